// Round 2
// baseline (870.141 us; speedup 1.0000x reference)
//
#include <hip/hip_runtime.h>
#include <hip/hip_bf16.h>

#define NP_TOT 128000
#define NV_TOT 12800
#define EP_EDGES 768000
#define EV_EDGES 51200
#define NB 256
#define MAXDEG 40

// ---------------- adjacency build ----------------
__global__ void adj_k(const int* __restrict__ ei, int* __restrict__ cnt,
                      int* __restrict__ adj, int NE) {
    int e = blockIdx.x * 256 + threadIdx.x;
    if (e >= NE) return;
    int dst = ei[NE + e];
    int slot = atomicAdd(&cnt[dst], 1);
    if (slot < MAXDEG) adj[dst * MAXDEG + slot] = ei[e];
}

__global__ void dinv_k(const int* __restrict__ cnt, float* __restrict__ dinv, int N) {
    int i = blockIdx.x * 256 + threadIdx.x;
    if (i < N) dinv[i] = rsqrtf(1.0f + (float)cnt[i]);
}

// ---------------- K=16 -> M=128 input GEMM (h0 = x@W0 + b0) ----------------
__global__ __launch_bounds__(256) void gemm16_k(const float* __restrict__ X,
                                                const float* __restrict__ W,
                                                const float* __restrict__ bias,
                                                float* __restrict__ out, int N) {
    __shared__ float sX[16][17];
    __shared__ float sW[16][128];
    int row0 = blockIdx.x * 16;
    int t = threadIdx.x;
    { int r = t >> 4, q = t & 15; sX[r][q] = X[(size_t)(row0 + r) * 16 + q]; }
    #pragma unroll
    for (int l = 0; l < 8; l++) {
        int lin = t + l * 256;
        sW[lin >> 7][lin & 127] = W[lin];
    }
    __syncthreads();
    int c = t & 127, rg = t >> 7;
    float acc[8];
    float b = bias[c];
    #pragma unroll
    for (int i = 0; i < 8; i++) acc[i] = b;
    #pragma unroll
    for (int k = 0; k < 16; k++) {
        float w = sW[k][c];
        #pragma unroll
        for (int i = 0; i < 8; i++) acc[i] += sX[rg * 8 + i][k] * w;
    }
    #pragma unroll
    for (int i = 0; i < 8; i++)
        out[(size_t)(row0 + rg * 8 + i) * 128 + c] = acc[i];
}

// ---------------- generic tiled fp32 GEMM ----------------
// out[N,M] = act( (A[N,K] @ W[K,M]) * rowscale[row] + bias[col] )
// K % 64 == 0, M % 128 == 0, N % 64 == 0. act: 0 none, 1 relu, 2 leaky_relu(0.01)
__global__ __launch_bounds__(256) void gemm_k(const float* __restrict__ A,
                                              const float* __restrict__ W,
                                              const float* __restrict__ bias,
                                              const float* __restrict__ rowscale,
                                              float* __restrict__ out,
                                              int N, int K, int M, int act) {
    __shared__ float sA[64][68];
    __shared__ float sW[64][132];
    int row0 = blockIdx.x * 64;
    int c0 = blockIdx.y * 128;
    int t = threadIdx.x;
    int tc = t & 31, tr = t >> 5;
    float acc[8][4];
    #pragma unroll
    for (int i = 0; i < 8; i++)
        #pragma unroll
        for (int j = 0; j < 4; j++) acc[i][j] = 0.f;

    for (int kk = 0; kk < K; kk += 64) {
        #pragma unroll
        for (int l = 0; l < 4; l++) {
            int lin = t + l * 256;
            int r = lin >> 4, q = lin & 15;
            *(float4*)&sA[r][q * 4] =
                *(const float4*)&A[(size_t)(row0 + r) * K + kk + q * 4];
        }
        #pragma unroll
        for (int l = 0; l < 8; l++) {
            int lin = t + l * 256;
            int r = lin >> 5, q = lin & 31;
            *(float4*)&sW[r][q * 4] =
                *(const float4*)&W[(size_t)(kk + r) * M + c0 + q * 4];
        }
        __syncthreads();
        #pragma unroll
        for (int k4 = 0; k4 < 64; k4 += 4) {
            float4 wv[4];
            #pragma unroll
            for (int q = 0; q < 4; q++) wv[q] = *(float4*)&sW[k4 + q][tc * 4];
            #pragma unroll
            for (int i = 0; i < 8; i++) {
                float4 a = *(float4*)&sA[tr * 8 + i][k4];
                acc[i][0] += a.x * wv[0].x + a.y * wv[1].x + a.z * wv[2].x + a.w * wv[3].x;
                acc[i][1] += a.x * wv[0].y + a.y * wv[1].y + a.z * wv[2].y + a.w * wv[3].y;
                acc[i][2] += a.x * wv[0].z + a.y * wv[1].z + a.z * wv[2].z + a.w * wv[3].z;
                acc[i][3] += a.x * wv[0].w + a.y * wv[1].w + a.z * wv[2].w + a.w * wv[3].w;
            }
        }
        __syncthreads();
    }
    float rs[8];
    #pragma unroll
    for (int i = 0; i < 8; i++)
        rs[i] = rowscale ? rowscale[row0 + tr * 8 + i] : 1.0f;
    float4 bv = make_float4(0.f, 0.f, 0.f, 0.f);
    if (bias) bv = *(const float4*)&bias[c0 + tc * 4];
    #pragma unroll
    for (int i = 0; i < 8; i++) {
        float v0 = acc[i][0] * rs[i] + bv.x;
        float v1 = acc[i][1] * rs[i] + bv.y;
        float v2 = acc[i][2] * rs[i] + bv.z;
        float v3 = acc[i][3] * rs[i] + bv.w;
        if (act == 1) {
            v0 = fmaxf(v0, 0.f); v1 = fmaxf(v1, 0.f);
            v2 = fmaxf(v2, 0.f); v3 = fmaxf(v3, 0.f);
        } else if (act == 2) {
            v0 = v0 > 0.f ? v0 : 0.01f * v0; v1 = v1 > 0.f ? v1 : 0.01f * v1;
            v2 = v2 > 0.f ? v2 : 0.01f * v2; v3 = v3 > 0.f ? v3 : 0.01f * v3;
        }
        *(float4*)&out[(size_t)(row0 + tr * 8 + i) * M + c0 + tc * 4] =
            make_float4(v0, v1, v2, v3);
    }
}

// ---------------- neighbor gather: out[i] = act(dinv[i]*(y[i]+sum y[nbr]) + b) ----------------
__global__ __launch_bounds__(256) void gather_k(const float* __restrict__ y,
                                                const int* __restrict__ adj,
                                                const int* __restrict__ cnt,
                                                const float* __restrict__ dinv,
                                                const float* __restrict__ bias,
                                                float* __restrict__ out,
                                                int N, int relu) {
    int node = blockIdx.x * 4 + (threadIdx.x >> 6);
    int lane = threadIdx.x & 63;
    const float2* y2 = (const float2*)y;
    float2 acc = y2[(size_t)node * 64 + lane];
    int d = cnt[node];
    if (d > MAXDEG) d = MAXDEG;
    const int* ap = &adj[(size_t)node * MAXDEG];
    for (int e = 0; e < d; e++) {
        int s = ap[e];
        float2 v = y2[(size_t)s * 64 + lane];
        acc.x += v.x; acc.y += v.y;
    }
    float di = dinv[node];
    float r0 = di * acc.x + bias[2 * lane];
    float r1 = di * acc.y + bias[2 * lane + 1];
    if (relu) { r0 = fmaxf(r0, 0.f); r1 = fmaxf(r1, 0.f); }
    ((float2*)out)[(size_t)node * 64 + lane] = make_float2(r0, r1);
}

// ---------------- mean pool over nodes of a graph ----------------
__global__ __launch_bounds__(256) void pool_k(const float* __restrict__ h,
                                              float* __restrict__ g, int npg) {
    __shared__ float s[128];
    int b = blockIdx.x;
    int f = threadIdx.x & 127, half = threadIdx.x >> 7;
    float sum = 0.f;
    for (int n = half; n < npg; n += 2)
        sum += h[((size_t)b * npg + n) * 128 + f];
    if (half) s[f] = sum;
    __syncthreads();
    if (!half) g[b * 128 + f] = (s[f] + sum) * (1.0f / npg);
}

// ---------------- build head input X = [vH2 | vH0 | v_graph | p_graph] ----------------
__global__ void xbuild_k(const float* __restrict__ vH2, const float* __restrict__ vH0,
                         const float* __restrict__ vg, const float* __restrict__ pg,
                         float* __restrict__ X) {
    int idx = blockIdx.x * 256 + threadIdx.x;
    int row = idx >> 9, c = idx & 511;
    int b = row / 50;
    float v;
    if (c < 128) v = vH2[row * 128 + c];
    else if (c < 256) v = vH0[row * 128 + (c - 128)];
    else if (c < 384) v = vg[b * 128 + (c - 256)];
    else v = pg[b * 128 + (c - 384)];
    X[idx] = v;
}

// ---------------- final K=128 -> 1 dot + bias, f32 store ----------------
__global__ __launch_bounds__(256) void head3_k(const float* __restrict__ T2,
                                               const float* __restrict__ w,
                                               const float* __restrict__ b,
                                               float* __restrict__ out) {
    int row = blockIdx.x * 4 + (threadIdx.x >> 6);
    int lane = threadIdx.x & 63;
    const float2* t2 = (const float2*)&T2[(size_t)row * 128];
    const float2* w2 = (const float2*)w;
    float2 tv = t2[lane], wv = w2[lane];
    float acc = tv.x * wv.x + tv.y * wv.y;
    #pragma unroll
    for (int off = 32; off; off >>= 1) acc += __shfl_xor(acc, off);
    if (lane == 0) out[row] = acc + b[0];
}

extern "C" void kernel_launch(void* const* d_in, const int* in_sizes, int n_in,
                              void* d_out, int out_size, void* d_ws, size_t ws_size,
                              hipStream_t stream) {
    const float* p_x = (const float*)d_in[0];
    const float* v_x = (const float*)d_in[1];
    const int* p_ei = (const int*)d_in[2];
    const int* v_ei = (const int*)d_in[3];
    const float* pW0 = (const float*)d_in[6];  const float* pb0 = (const float*)d_in[7];
    const float* pW1 = (const float*)d_in[8];  const float* pb1 = (const float*)d_in[9];
    const float* pW2 = (const float*)d_in[10]; const float* pb2 = (const float*)d_in[11];
    const float* vW0 = (const float*)d_in[12]; const float* vb0 = (const float*)d_in[13];
    const float* vW1 = (const float*)d_in[14]; const float* vb1 = (const float*)d_in[15];
    const float* vW2 = (const float*)d_in[16]; const float* vb2 = (const float*)d_in[17];
    const float* hW1 = (const float*)d_in[18]; const float* hb1 = (const float*)d_in[19];
    const float* hW2 = (const float*)d_in[20]; const float* hb2 = (const float*)d_in[21];
    const float* hW3 = (const float*)d_in[22]; const float* hb3 = (const float*)d_in[23];

    char* w = (char*)d_ws;
    size_t off = 0;
    auto alloc = [&](size_t bytes) { char* p = w + off; off += (bytes + 255) & ~size_t(255); return p; };
    float* bufA   = (float*)alloc((size_t)NP_TOT * 128 * 4);   // 65.5 MB ping
    float* bufB   = (float*)alloc((size_t)NP_TOT * 128 * 4);   // 65.5 MB pong
    float* vH0    = (float*)alloc((size_t)NV_TOT * 128 * 4);
    float* vH2    = (float*)alloc((size_t)NV_TOT * 128 * 4);
    float* p_g    = (float*)alloc((size_t)NB * 128 * 4);
    float* v_g    = (float*)alloc((size_t)NB * 128 * 4);
    int*   adj_p  = (int*)alloc((size_t)NP_TOT * MAXDEG * 4);
    int*   cnt_p  = (int*)alloc((size_t)NP_TOT * 4);
    float* dinv_p = (float*)alloc((size_t)NP_TOT * 4);
    int*   adj_v  = (int*)alloc((size_t)NV_TOT * MAXDEG * 4);
    int*   cnt_v  = (int*)alloc((size_t)NV_TOT * 4);
    float* dinv_v = (float*)alloc((size_t)NV_TOT * 4);
    // head buffers reuse big ping/pong
    float* X  = bufA;                              // [12800,512] 26.2 MB
    float* T1 = bufB;                              // [12800,256] 13.1 MB
    float* T2 = (float*)((char*)bufB + (16u << 20)); // [12800,128] 6.6 MB

    hipMemsetAsync(cnt_p, 0, (size_t)NP_TOT * 4, stream);
    hipMemsetAsync(cnt_v, 0, (size_t)NV_TOT * 4, stream);
    adj_k<<<(EP_EDGES + 255) / 256, 256, 0, stream>>>(p_ei, cnt_p, adj_p, EP_EDGES);
    adj_k<<<(EV_EDGES + 255) / 256, 256, 0, stream>>>(v_ei, cnt_v, adj_v, EV_EDGES);
    dinv_k<<<(NP_TOT + 255) / 256, 256, 0, stream>>>(cnt_p, dinv_p, NP_TOT);
    dinv_k<<<(NV_TOT + 255) / 256, 256, 0, stream>>>(cnt_v, dinv_v, NV_TOT);

    // ---- v encoder ----
    gemm16_k<<<NV_TOT / 16, 256, 0, stream>>>(v_x, vW0, vb0, vH0, NV_TOT);
    gemm_k<<<dim3(NV_TOT / 64, 1), 256, 0, stream>>>(vH0, vW1, nullptr, dinv_v, bufA, NV_TOT, 128, 128, 0);
    gather_k<<<NV_TOT / 4, 256, 0, stream>>>(bufA, adj_v, cnt_v, dinv_v, vb1, bufB, NV_TOT, 1);
    gemm_k<<<dim3(NV_TOT / 64, 1), 256, 0, stream>>>(bufB, vW2, nullptr, dinv_v, bufA, NV_TOT, 128, 128, 0);
    gather_k<<<NV_TOT / 4, 256, 0, stream>>>(bufA, adj_v, cnt_v, dinv_v, vb2, vH2, NV_TOT, 0);
    pool_k<<<NB, 256, 0, stream>>>(vH2, v_g, 50);

    // ---- p encoder ----
    gemm16_k<<<NP_TOT / 16, 256, 0, stream>>>(p_x, pW0, pb0, bufA, NP_TOT);
    gemm_k<<<dim3(NP_TOT / 64, 1), 256, 0, stream>>>(bufA, pW1, nullptr, dinv_p, bufB, NP_TOT, 128, 128, 0);
    gather_k<<<NP_TOT / 4, 256, 0, stream>>>(bufB, adj_p, cnt_p, dinv_p, pb1, bufA, NP_TOT, 1);
    gemm_k<<<dim3(NP_TOT / 64, 1), 256, 0, stream>>>(bufA, pW2, nullptr, dinv_p, bufB, NP_TOT, 128, 128, 0);
    gather_k<<<NP_TOT / 4, 256, 0, stream>>>(bufB, adj_p, cnt_p, dinv_p, pb2, bufA, NP_TOT, 0);
    pool_k<<<NB, 256, 0, stream>>>(bufA, p_g, 500);

    // ---- head ----
    xbuild_k<<<(NV_TOT * 512) / 256, 256, 0, stream>>>(vH2, vH0, v_g, p_g, X);
    gemm_k<<<dim3(NV_TOT / 64, 2), 256, 0, stream>>>(X, hW1, hb1, nullptr, T1, NV_TOT, 512, 256, 2);
    gemm_k<<<dim3(NV_TOT / 64, 1), 256, 0, stream>>>(T1, hW2, hb2, nullptr, T2, NV_TOT, 256, 128, 2);
    head3_k<<<NV_TOT / 4, 256, 0, stream>>>(T2, hW3, hb3, (float*)d_out);
}

// Round 3
// 624.581 us; speedup vs baseline: 1.3932x; 1.3932x over previous
//
#include <hip/hip_runtime.h>
#include <hip/hip_bf16.h>

#define NP_TOT 128000
#define NV_TOT 12800
#define EP_EDGES 768000
#define EV_EDGES 51200
#define NB 256
#define MAXDEG 40

typedef short bf16x8 __attribute__((ext_vector_type(8)));
typedef float f32x4 __attribute__((ext_vector_type(4)));

static __device__ __forceinline__ unsigned short f2bf(float f) {
    unsigned u = __builtin_bit_cast(unsigned, f);
    unsigned r = u + 0x7FFFu + ((u >> 16) & 1u);   // RNE
    return (unsigned short)(r >> 16);
}
static __device__ __forceinline__ float bf2f(unsigned short h) {
    return __builtin_bit_cast(float, (unsigned)h << 16);
}

// ---------------- adjacency build ----------------
__global__ void adj_k(const int* __restrict__ ei, int* __restrict__ cnt,
                      int* __restrict__ adj, int NE) {
    int e = blockIdx.x * 256 + threadIdx.x;
    if (e >= NE) return;
    int dst = ei[NE + e];
    int slot = atomicAdd(&cnt[dst], 1);
    if (slot < MAXDEG) adj[dst * MAXDEG + slot] = ei[e];
}

__global__ void dinv_k(const int* __restrict__ cnt, float* __restrict__ dinv, int N) {
    int i = blockIdx.x * 256 + threadIdx.x;
    if (i < N) dinv[i] = rsqrtf(1.0f + (float)cnt[i]);
}

// ---------------- K=16 -> M=128 input GEMM (h0 = x@W0 + b0) ----------------
__global__ __launch_bounds__(256) void gemm16_k(const float* __restrict__ X,
                                                const float* __restrict__ W,
                                                const float* __restrict__ bias,
                                                float* __restrict__ out, int N) {
    __shared__ float sX[16][17];
    __shared__ float sW[16][128];
    int row0 = blockIdx.x * 16;
    int t = threadIdx.x;
    { int r = t >> 4, q = t & 15; sX[r][q] = X[(size_t)(row0 + r) * 16 + q]; }
    #pragma unroll
    for (int l = 0; l < 8; l++) {
        int lin = t + l * 256;
        sW[lin >> 7][lin & 127] = W[lin];
    }
    __syncthreads();
    int c = t & 127, rg = t >> 7;
    float acc[8];
    float b = bias[c];
    #pragma unroll
    for (int i = 0; i < 8; i++) acc[i] = b;
    #pragma unroll
    for (int k = 0; k < 16; k++) {
        float w = sW[k][c];
        #pragma unroll
        for (int i = 0; i < 8; i++) acc[i] += sX[rg * 8 + i][k] * w;
    }
    #pragma unroll
    for (int i = 0; i < 8; i++)
        out[(size_t)(row0 + rg * 8 + i) * 128 + c] = acc[i];
}

// ---------------- split-bf16 3-pass MFMA GEMM ----------------
// out[N,M] = act( (A[N,K] @ W[K,M]) * rowscale[row] + bias[col] )
// N%128==0, K%64==0, M%128==0. act: 0 none, 1 relu, 2 leaky(0.01)
// Tile: 128 rows x 128 cols, KT=64. 4 waves; wave w owns cols [w*32, w*32+32).
__global__ __launch_bounds__(256) void gemm_mfma(const float* __restrict__ A,
                                                 const float* __restrict__ W,
                                                 const float* __restrict__ bias,
                                                 const float* __restrict__ rowscale,
                                                 float* __restrict__ out,
                                                 int N, int K, int M, int act) {
    __shared__ char lds[65536];
    char* sAh = lds;                 // [128 rows][64 k] bf16, swizzled
    char* sAl = lds + 16384;
    char* sWh = lds + 32768;         // [128 n][64 k] bf16 (W^T), swizzled
    char* sWl = lds + 49152;

    const int t = threadIdx.x;
    const int lane = t & 63;
    const int wv = t >> 6;           // wave 0..3
    const int row0 = blockIdx.x * 128;
    const int c0 = blockIdx.y * 128;
    const int fr = lane & 15;        // frag row/col index
    const int fq = lane >> 4;        // 0..3

    f32x4 acc[8][2];
    #pragma unroll
    for (int m = 0; m < 8; m++)
        #pragma unroll
        for (int n = 0; n < 2; n++) acc[m][n] = (f32x4){0.f, 0.f, 0.f, 0.f};

    for (int k0 = 0; k0 < K; k0 += 64) {
        __syncthreads();
        // ---- stage A: 128x64 fp32 -> split bf16 hi/lo ----
        #pragma unroll
        for (int i = 0; i < 8; i++) {
            int idx = t + i * 256;           // float4 index in 128x16 grid
            int r = idx >> 4, kq = idx & 15; // row, float4-within-row
            float4 a = *(const float4*)&A[(size_t)(row0 + r) * K + k0 + kq * 4];
            unsigned short h0 = f2bf(a.x), h1 = f2bf(a.y), h2 = f2bf(a.z), h3 = f2bf(a.w);
            unsigned short l0 = f2bf(a.x - bf2f(h0)), l1 = f2bf(a.y - bf2f(h1));
            unsigned short l2 = f2bf(a.z - bf2f(h2)), l3 = f2bf(a.w - bf2f(h3));
            int off = r * 128 + ((kq * 8) ^ ((r & 7) << 4));
            *(uint2*)(sAh + off) = make_uint2((unsigned)h0 | ((unsigned)h1 << 16),
                                              (unsigned)h2 | ((unsigned)h3 << 16));
            *(uint2*)(sAl + off) = make_uint2((unsigned)l0 | ((unsigned)l1 << 16),
                                              (unsigned)l2 | ((unsigned)l3 << 16));
        }
        // ---- stage W^T: 64k x 128n fp32 -> split bf16 hi/lo, transposed ----
        {
            int n = t & 127, kc = t >> 7;    // kc = 0 or 1
            #pragma unroll
            for (int r = 0; r < 4; r++) {
                int krel = r * 16 + kc * 8;
                unsigned short hh[8], ll[8];
                #pragma unroll
                for (int j = 0; j < 8; j++) {
                    float wv_ = W[(size_t)(k0 + krel + j) * M + c0 + n];
                    hh[j] = f2bf(wv_);
                    ll[j] = f2bf(wv_ - bf2f(hh[j]));
                }
                int off = n * 128 + ((krel * 2) ^ ((n & 7) << 4));
                uint4 ph, pl;
                ph.x = (unsigned)hh[0] | ((unsigned)hh[1] << 16);
                ph.y = (unsigned)hh[2] | ((unsigned)hh[3] << 16);
                ph.z = (unsigned)hh[4] | ((unsigned)hh[5] << 16);
                ph.w = (unsigned)hh[6] | ((unsigned)hh[7] << 16);
                pl.x = (unsigned)ll[0] | ((unsigned)ll[1] << 16);
                pl.y = (unsigned)ll[2] | ((unsigned)ll[3] << 16);
                pl.z = (unsigned)ll[4] | ((unsigned)ll[5] << 16);
                pl.w = (unsigned)ll[6] | ((unsigned)ll[7] << 16);
                *(uint4*)(sWh + off) = ph;
                *(uint4*)(sWl + off) = pl;
            }
        }
        __syncthreads();
        // ---- compute: 2 k-steps of K=32 ----
        #pragma unroll
        for (int ks = 0; ks < 2; ks++) {
            int kbyte = ks * 64 + fq * 16;
            bf16x8 wh[2], wl[2];
            #pragma unroll
            for (int nf = 0; nf < 2; nf++) {
                int n = wv * 32 + nf * 16 + fr;
                int off = n * 128 + (kbyte ^ ((n & 7) << 4));
                wh[nf] = *(bf16x8*)(sWh + off);
                wl[nf] = *(bf16x8*)(sWl + off);
            }
            #pragma unroll
            for (int m = 0; m < 8; m++) {
                int r = m * 16 + fr;
                int off = r * 128 + (kbyte ^ ((r & 7) << 4));
                bf16x8 ah = *(bf16x8*)(sAh + off);
                bf16x8 al = *(bf16x8*)(sAl + off);
                #pragma unroll
                for (int nf = 0; nf < 2; nf++) {
                    acc[m][nf] = __builtin_amdgcn_mfma_f32_16x16x32_bf16(ah, wh[nf], acc[m][nf], 0, 0, 0);
                    acc[m][nf] = __builtin_amdgcn_mfma_f32_16x16x32_bf16(ah, wl[nf], acc[m][nf], 0, 0, 0);
                    acc[m][nf] = __builtin_amdgcn_mfma_f32_16x16x32_bf16(al, wh[nf], acc[m][nf], 0, 0, 0);
                }
            }
        }
    }

    // ---- epilogue ----
    #pragma unroll
    for (int m = 0; m < 8; m++) {
        int rbase = row0 + m * 16 + fq * 4;
        float rs[4];
        #pragma unroll
        for (int j = 0; j < 4; j++)
            rs[j] = rowscale ? rowscale[rbase + j] : 1.0f;
        #pragma unroll
        for (int nf = 0; nf < 2; nf++) {
            int col = c0 + wv * 32 + nf * 16 + fr;
            float b = bias ? bias[col] : 0.0f;
            #pragma unroll
            for (int j = 0; j < 4; j++) {
                float v = acc[m][nf][j] * rs[j] + b;
                if (act == 1) v = fmaxf(v, 0.f);
                else if (act == 2) v = v > 0.f ? v : 0.01f * v;
                out[(size_t)(rbase + j) * M + col] = v;
            }
        }
    }
}

// ---------------- neighbor gather: out[i] = act(dinv[i]*(y[i]+sum y[nbr]) + b) ----------------
__global__ __launch_bounds__(256) void gather_k(const float* __restrict__ y,
                                                const int* __restrict__ adj,
                                                const int* __restrict__ cnt,
                                                const float* __restrict__ dinv,
                                                const float* __restrict__ bias,
                                                float* __restrict__ out,
                                                int N, int relu) {
    int node = blockIdx.x * 4 + (threadIdx.x >> 6);
    int lane = threadIdx.x & 63;
    const float2* y2 = (const float2*)y;
    float2 acc = y2[(size_t)node * 64 + lane];
    int d = cnt[node];
    if (d > MAXDEG) d = MAXDEG;
    const int* ap = &adj[(size_t)node * MAXDEG];
    for (int e = 0; e < d; e++) {
        int s = ap[e];
        float2 v = y2[(size_t)s * 64 + lane];
        acc.x += v.x; acc.y += v.y;
    }
    float di = dinv[node];
    float r0 = di * acc.x + bias[2 * lane];
    float r1 = di * acc.y + bias[2 * lane + 1];
    if (relu) { r0 = fmaxf(r0, 0.f); r1 = fmaxf(r1, 0.f); }
    ((float2*)out)[(size_t)node * 64 + lane] = make_float2(r0, r1);
}

// ---------------- mean pool over nodes of a graph ----------------
__global__ __launch_bounds__(256) void pool_k(const float* __restrict__ h,
                                              float* __restrict__ g, int npg) {
    __shared__ float s[128];
    int b = blockIdx.x;
    int f = threadIdx.x & 127, half = threadIdx.x >> 7;
    float sum = 0.f;
    for (int n = half; n < npg; n += 2)
        sum += h[((size_t)b * npg + n) * 128 + f];
    if (half) s[f] = sum;
    __syncthreads();
    if (!half) g[b * 128 + f] = (s[f] + sum) * (1.0f / npg);
}

// ---------------- build head input X = [vH2 | vH0 | v_graph | p_graph] ----------------
__global__ void xbuild_k(const float* __restrict__ vH2, const float* __restrict__ vH0,
                         const float* __restrict__ vg, const float* __restrict__ pg,
                         float* __restrict__ X) {
    int idx = blockIdx.x * 256 + threadIdx.x;
    int row = idx >> 9, c = idx & 511;
    int b = row / 50;
    float v;
    if (c < 128) v = vH2[row * 128 + c];
    else if (c < 256) v = vH0[row * 128 + (c - 128)];
    else if (c < 384) v = vg[b * 128 + (c - 256)];
    else v = pg[b * 128 + (c - 384)];
    X[idx] = v;
}

// ---------------- final K=128 -> 1 dot + bias, f32 store ----------------
__global__ __launch_bounds__(256) void head3_k(const float* __restrict__ T2,
                                               const float* __restrict__ w,
                                               const float* __restrict__ b,
                                               float* __restrict__ out) {
    int row = blockIdx.x * 4 + (threadIdx.x >> 6);
    int lane = threadIdx.x & 63;
    const float2* t2 = (const float2*)&T2[(size_t)row * 128];
    const float2* w2 = (const float2*)w;
    float2 tv = t2[lane], wv = w2[lane];
    float acc = tv.x * wv.x + tv.y * wv.y;
    #pragma unroll
    for (int off = 32; off; off >>= 1) acc += __shfl_xor(acc, off);
    if (lane == 0) out[row] = acc + b[0];
}

extern "C" void kernel_launch(void* const* d_in, const int* in_sizes, int n_in,
                              void* d_out, int out_size, void* d_ws, size_t ws_size,
                              hipStream_t stream) {
    const float* p_x = (const float*)d_in[0];
    const float* v_x = (const float*)d_in[1];
    const int* p_ei = (const int*)d_in[2];
    const int* v_ei = (const int*)d_in[3];
    const float* pW0 = (const float*)d_in[6];  const float* pb0 = (const float*)d_in[7];
    const float* pW1 = (const float*)d_in[8];  const float* pb1 = (const float*)d_in[9];
    const float* pW2 = (const float*)d_in[10]; const float* pb2 = (const float*)d_in[11];
    const float* vW0 = (const float*)d_in[12]; const float* vb0 = (const float*)d_in[13];
    const float* vW1 = (const float*)d_in[14]; const float* vb1 = (const float*)d_in[15];
    const float* vW2 = (const float*)d_in[16]; const float* vb2 = (const float*)d_in[17];
    const float* hW1 = (const float*)d_in[18]; const float* hb1 = (const float*)d_in[19];
    const float* hW2 = (const float*)d_in[20]; const float* hb2 = (const float*)d_in[21];
    const float* hW3 = (const float*)d_in[22]; const float* hb3 = (const float*)d_in[23];

    char* w = (char*)d_ws;
    size_t off = 0;
    auto alloc = [&](size_t bytes) { char* p = w + off; off += (bytes + 255) & ~size_t(255); return p; };
    float* bufA   = (float*)alloc((size_t)NP_TOT * 128 * 4);   // 65.5 MB ping
    float* bufB   = (float*)alloc((size_t)NP_TOT * 128 * 4);   // 65.5 MB pong
    float* vH0    = (float*)alloc((size_t)NV_TOT * 128 * 4);
    float* vH2    = (float*)alloc((size_t)NV_TOT * 128 * 4);
    float* p_g    = (float*)alloc((size_t)NB * 128 * 4);
    float* v_g    = (float*)alloc((size_t)NB * 128 * 4);
    int*   adj_p  = (int*)alloc((size_t)NP_TOT * MAXDEG * 4);
    int*   cnt_p  = (int*)alloc((size_t)NP_TOT * 4);
    float* dinv_p = (float*)alloc((size_t)NP_TOT * 4);
    int*   adj_v  = (int*)alloc((size_t)NV_TOT * MAXDEG * 4);
    int*   cnt_v  = (int*)alloc((size_t)NV_TOT * 4);
    float* dinv_v = (float*)alloc((size_t)NV_TOT * 4);
    // head buffers reuse big ping/pong
    float* X  = bufA;                              // [12800,512] 26.2 MB
    float* T1 = bufB;                              // [12800,256] 13.1 MB
    float* T2 = (float*)((char*)bufB + (16u << 20)); // [12800,128] 6.6 MB

    hipMemsetAsync(cnt_p, 0, (size_t)NP_TOT * 4, stream);
    hipMemsetAsync(cnt_v, 0, (size_t)NV_TOT * 4, stream);
    adj_k<<<(EP_EDGES + 255) / 256, 256, 0, stream>>>(p_ei, cnt_p, adj_p, EP_EDGES);
    adj_k<<<(EV_EDGES + 255) / 256, 256, 0, stream>>>(v_ei, cnt_v, adj_v, EV_EDGES);
    dinv_k<<<(NP_TOT + 255) / 256, 256, 0, stream>>>(cnt_p, dinv_p, NP_TOT);
    dinv_k<<<(NV_TOT + 255) / 256, 256, 0, stream>>>(cnt_v, dinv_v, NV_TOT);

    // ---- v encoder ----
    gemm16_k<<<NV_TOT / 16, 256, 0, stream>>>(v_x, vW0, vb0, vH0, NV_TOT);
    gemm_mfma<<<dim3(NV_TOT / 128, 1), 256, 0, stream>>>(vH0, vW1, nullptr, dinv_v, bufA, NV_TOT, 128, 128, 0);
    gather_k<<<NV_TOT / 4, 256, 0, stream>>>(bufA, adj_v, cnt_v, dinv_v, vb1, bufB, NV_TOT, 1);
    gemm_mfma<<<dim3(NV_TOT / 128, 1), 256, 0, stream>>>(bufB, vW2, nullptr, dinv_v, bufA, NV_TOT, 128, 128, 0);
    gather_k<<<NV_TOT / 4, 256, 0, stream>>>(bufA, adj_v, cnt_v, dinv_v, vb2, vH2, NV_TOT, 0);
    pool_k<<<NB, 256, 0, stream>>>(vH2, v_g, 50);

    // ---- p encoder ----
    gemm16_k<<<NP_TOT / 16, 256, 0, stream>>>(p_x, pW0, pb0, bufA, NP_TOT);
    gemm_mfma<<<dim3(NP_TOT / 128, 1), 256, 0, stream>>>(bufA, pW1, nullptr, dinv_p, bufB, NP_TOT, 128, 128, 0);
    gather_k<<<NP_TOT / 4, 256, 0, stream>>>(bufB, adj_p, cnt_p, dinv_p, pb1, bufA, NP_TOT, 1);
    gemm_mfma<<<dim3(NP_TOT / 128, 1), 256, 0, stream>>>(bufA, pW2, nullptr, dinv_p, bufB, NP_TOT, 128, 128, 0);
    gather_k<<<NP_TOT / 4, 256, 0, stream>>>(bufB, adj_p, cnt_p, dinv_p, pb2, bufA, NP_TOT, 0);
    pool_k<<<NB, 256, 0, stream>>>(bufA, p_g, 500);

    // ---- head ----
    xbuild_k<<<(NV_TOT * 512) / 256, 256, 0, stream>>>(vH2, vH0, v_g, p_g, X);
    gemm_mfma<<<dim3(NV_TOT / 128, 2), 256, 0, stream>>>(X, hW1, hb1, nullptr, T1, NV_TOT, 512, 256, 2);
    gemm_mfma<<<dim3(NV_TOT / 128, 1), 256, 0, stream>>>(T1, hW2, hb2, nullptr, T2, NV_TOT, 256, 128, 2);
    head3_k<<<NV_TOT / 4, 256, 0, stream>>>(T2, hW3, hb3, (float*)d_out);
}

// Round 4
// 523.231 us; speedup vs baseline: 1.6630x; 1.1937x over previous
//
#include <hip/hip_runtime.h>
#include <hip/hip_bf16.h>

#define NP_TOT 128000
#define NV_TOT 12800
#define EP_EDGES 768000
#define EV_EDGES 51200
#define NB 256
#define MAXDEG 40

typedef short bf16x8 __attribute__((ext_vector_type(8)));
typedef float f32x4 __attribute__((ext_vector_type(4)));

static __device__ __forceinline__ unsigned short f2bf(float f) {
    unsigned u = __builtin_bit_cast(unsigned, f);
    unsigned r = u + 0x7FFFu + ((u >> 16) & 1u);   // RNE
    return (unsigned short)(r >> 16);
}
static __device__ __forceinline__ float bf2f(unsigned short h) {
    return __builtin_bit_cast(float, (unsigned)h << 16);
}

// ---------------- adjacency build ----------------
__global__ void adj_k(const int* __restrict__ ei, int* __restrict__ cnt,
                      int* __restrict__ adj, int NE) {
    int e = blockIdx.x * 256 + threadIdx.x;
    if (e >= NE) return;
    int dst = ei[NE + e];
    int slot = atomicAdd(&cnt[dst], 1);
    if (slot < MAXDEG) adj[dst * MAXDEG + slot] = ei[e];
}

__global__ void dinv_k(const int* __restrict__ cnt, float* __restrict__ dinv, int N) {
    int i = blockIdx.x * 256 + threadIdx.x;
    if (i < N) dinv[i] = rsqrtf(1.0f + (float)cnt[i]);
}

// ---------------- K=16 -> M=128 input GEMM (h0 = x@W0 + b0) ----------------
__global__ __launch_bounds__(256) void gemm16_k(const float* __restrict__ X,
                                                const float* __restrict__ W,
                                                const float* __restrict__ bias,
                                                float* __restrict__ out, int N) {
    __shared__ float sX[16][17];
    __shared__ float sW[16][128];
    int row0 = blockIdx.x * 16;
    int t = threadIdx.x;
    { int r = t >> 4, q = t & 15; sX[r][q] = X[(size_t)(row0 + r) * 16 + q]; }
    #pragma unroll
    for (int l = 0; l < 8; l++) {
        int lin = t + l * 256;
        sW[lin >> 7][lin & 127] = W[lin];
    }
    __syncthreads();
    int c = t & 127, rg = t >> 7;
    float acc[8];
    float b = bias[c];
    #pragma unroll
    for (int i = 0; i < 8; i++) acc[i] = b;
    #pragma unroll
    for (int k = 0; k < 16; k++) {
        float w = sW[k][c];
        #pragma unroll
        for (int i = 0; i < 8; i++) acc[i] += sX[rg * 8 + i][k] * w;
    }
    #pragma unroll
    for (int i = 0; i < 8; i++)
        out[(size_t)(row0 + rg * 8 + i) * 128 + c] = acc[i];
}

// ---------------- split-bf16 3-pass MFMA GEMM ----------------
// out[N,M] = act( (A[N,K] @ W[K,M]) * rowscale[row] + bias[col] )
// N%128==0, K%64==0, M%128==0. act: 0 none, 1 relu, 2 leaky(0.01)
__global__ __launch_bounds__(256) void gemm_mfma(const float* __restrict__ A,
                                                 const float* __restrict__ W,
                                                 const float* __restrict__ bias,
                                                 const float* __restrict__ rowscale,
                                                 float* __restrict__ out,
                                                 int N, int K, int M, int act) {
    __shared__ char lds[65536];
    char* sAh = lds;                 // [128 rows][64 k] bf16, swizzled
    char* sAl = lds + 16384;
    char* sWh = lds + 32768;         // [128 n][64 k] bf16 (W^T), swizzled
    char* sWl = lds + 49152;

    const int t = threadIdx.x;
    const int lane = t & 63;
    const int wv = t >> 6;           // wave 0..3
    const int row0 = blockIdx.x * 128;
    const int c0 = blockIdx.y * 128;
    const int fr = lane & 15;        // frag row/col index
    const int fq = lane >> 4;        // 0..3

    f32x4 acc[8][2];
    #pragma unroll
    for (int m = 0; m < 8; m++)
        #pragma unroll
        for (int n = 0; n < 2; n++) acc[m][n] = (f32x4){0.f, 0.f, 0.f, 0.f};

    for (int k0 = 0; k0 < K; k0 += 64) {
        __syncthreads();
        // ---- stage A: 128x64 fp32 -> split bf16 hi/lo ----
        #pragma unroll
        for (int i = 0; i < 8; i++) {
            int idx = t + i * 256;           // float4 index in 128x16 grid
            int r = idx >> 4, kq = idx & 15; // row, float4-within-row
            float4 a = *(const float4*)&A[(size_t)(row0 + r) * K + k0 + kq * 4];
            unsigned short h0 = f2bf(a.x), h1 = f2bf(a.y), h2 = f2bf(a.z), h3 = f2bf(a.w);
            unsigned short l0 = f2bf(a.x - bf2f(h0)), l1 = f2bf(a.y - bf2f(h1));
            unsigned short l2 = f2bf(a.z - bf2f(h2)), l3 = f2bf(a.w - bf2f(h3));
            int off = r * 128 + ((kq * 8) ^ ((r & 7) << 4));
            *(uint2*)(sAh + off) = make_uint2((unsigned)h0 | ((unsigned)h1 << 16),
                                              (unsigned)h2 | ((unsigned)h3 << 16));
            *(uint2*)(sAl + off) = make_uint2((unsigned)l0 | ((unsigned)l1 << 16),
                                              (unsigned)l2 | ((unsigned)l3 << 16));
        }
        // ---- stage W^T: 64k x 128n fp32 -> split bf16 hi/lo, transposed ----
        {
            int n = t & 127, kc = t >> 7;    // kc = 0 or 1
            #pragma unroll
            for (int r = 0; r < 4; r++) {
                int krel = r * 16 + kc * 8;
                unsigned short hh[8], ll[8];
                #pragma unroll
                for (int j = 0; j < 8; j++) {
                    float wv_ = W[(size_t)(k0 + krel + j) * M + c0 + n];
                    hh[j] = f2bf(wv_);
                    ll[j] = f2bf(wv_ - bf2f(hh[j]));
                }
                int off = n * 128 + ((krel * 2) ^ ((n & 7) << 4));
                uint4 ph, pl;
                ph.x = (unsigned)hh[0] | ((unsigned)hh[1] << 16);
                ph.y = (unsigned)hh[2] | ((unsigned)hh[3] << 16);
                ph.z = (unsigned)hh[4] | ((unsigned)hh[5] << 16);
                ph.w = (unsigned)hh[6] | ((unsigned)hh[7] << 16);
                pl.x = (unsigned)ll[0] | ((unsigned)ll[1] << 16);
                pl.y = (unsigned)ll[2] | ((unsigned)ll[3] << 16);
                pl.z = (unsigned)ll[4] | ((unsigned)ll[5] << 16);
                pl.w = (unsigned)ll[6] | ((unsigned)ll[7] << 16);
                *(uint4*)(sWh + off) = ph;
                *(uint4*)(sWl + off) = pl;
            }
        }
        __syncthreads();
        // ---- compute: 2 k-steps of K=32 ----
        #pragma unroll
        for (int ks = 0; ks < 2; ks++) {
            int kbyte = ks * 64 + fq * 16;
            bf16x8 wh[2], wl[2];
            #pragma unroll
            for (int nf = 0; nf < 2; nf++) {
                int n = wv * 32 + nf * 16 + fr;
                int off = n * 128 + (kbyte ^ ((n & 7) << 4));
                wh[nf] = *(bf16x8*)(sWh + off);
                wl[nf] = *(bf16x8*)(sWl + off);
            }
            #pragma unroll
            for (int m = 0; m < 8; m++) {
                int r = m * 16 + fr;
                int off = r * 128 + (kbyte ^ ((r & 7) << 4));
                bf16x8 ah = *(bf16x8*)(sAh + off);
                bf16x8 al = *(bf16x8*)(sAl + off);
                #pragma unroll
                for (int nf = 0; nf < 2; nf++) {
                    acc[m][nf] = __builtin_amdgcn_mfma_f32_16x16x32_bf16(ah, wh[nf], acc[m][nf], 0, 0, 0);
                    acc[m][nf] = __builtin_amdgcn_mfma_f32_16x16x32_bf16(ah, wl[nf], acc[m][nf], 0, 0, 0);
                    acc[m][nf] = __builtin_amdgcn_mfma_f32_16x16x32_bf16(al, wh[nf], acc[m][nf], 0, 0, 0);
                }
            }
        }
    }

    // ---- epilogue ----
    #pragma unroll
    for (int m = 0; m < 8; m++) {
        int rbase = row0 + m * 16 + fq * 4;
        float rs[4];
        #pragma unroll
        for (int j = 0; j < 4; j++)
            rs[j] = rowscale ? rowscale[rbase + j] : 1.0f;
        #pragma unroll
        for (int nf = 0; nf < 2; nf++) {
            int col = c0 + wv * 32 + nf * 16 + fr;
            float b = bias ? bias[col] : 0.0f;
            #pragma unroll
            for (int j = 0; j < 4; j++) {
                float v = acc[m][nf][j] * rs[j] + b;
                if (act == 1) v = fmaxf(v, 0.f);
                else if (act == 2) v = v > 0.f ? v : 0.01f * v;
                out[(size_t)(rbase + j) * M + col] = v;
            }
        }
    }
}

// ---------------- neighbor gather: out[i] = act(dinv[i]*(y[i]+sum y[nbr]) + b) ----------------
// ILP-grouped predicated loads + XCD-chunked swizzle. grid.x % 8 == 0 required.
__global__ __launch_bounds__(256) void gather_k(const float* __restrict__ y,
                                                const int* __restrict__ adj,
                                                const int* __restrict__ cnt,
                                                const float* __restrict__ dinv,
                                                const float* __restrict__ bias,
                                                float* __restrict__ out,
                                                int N, int relu) {
    int nb = gridDim.x;
    int q = nb >> 3;
    int bid = blockIdx.x;
    int swz = (bid & 7) * q + (bid >> 3);          // contiguous chunk per XCD
    int node = swz * 4 + (threadIdx.x >> 6);
    int lane = threadIdx.x & 63;

    int d = cnt[node];
    if (d > MAXDEG) d = MAXDEG;
    const int* ap = &adj[(size_t)node * MAXDEG];
    int4 i0 = *(const int4*)ap;                    // slots 0-3 (always in-bounds)
    int4 i1 = *(const int4*)(ap + 4);
    int4 i2 = *(const int4*)(ap + 8);

    const float2* y2 = (const float2*)y;
    float2 acc = y2[(size_t)node * 64 + lane];     // own row (self loop)
    int idx[12] = {i0.x, i0.y, i0.z, i0.w, i1.x, i1.y, i1.z, i1.w, i2.x, i2.y, i2.z, i2.w};
    #pragma unroll
    for (int e = 0; e < 12; e++) {
        bool valid = e < d;
        int s = valid ? idx[e] : node;             // safe addr, L1-hot
        float2 v = y2[(size_t)s * 64 + lane];
        float m = valid ? 1.0f : 0.0f;
        acc.x += m * v.x; acc.y += m * v.y;
    }
    for (int e = 12; e < d; e++) {                 // rare tail (deg > 12)
        int s = ap[e];
        float2 v = y2[(size_t)s * 64 + lane];
        acc.x += v.x; acc.y += v.y;
    }
    float di = dinv[node];
    float r0 = di * acc.x + bias[2 * lane];
    float r1 = di * acc.y + bias[2 * lane + 1];
    if (relu) { r0 = fmaxf(r0, 0.f); r1 = fmaxf(r1, 0.f); }
    ((float2*)out)[(size_t)node * 64 + lane] = make_float2(r0, r1);
}

// ---------------- mean pool over nodes of a graph (float4, 8-way row parallel) ----------------
__global__ __launch_bounds__(256) void pool_k(const float* __restrict__ h,
                                              float* __restrict__ g, int npg) {
    int b = blockIdx.x;
    int t = threadIdx.x;
    int rg = t >> 5;       // row group 0..7
    int c4 = t & 31;       // float4 column
    const float4* h4 = (const float4*)(h + (size_t)b * npg * 128);
    float4 acc = make_float4(0.f, 0.f, 0.f, 0.f);
    for (int r = rg; r < npg; r += 8) {
        float4 v = h4[r * 32 + c4];
        acc.x += v.x; acc.y += v.y; acc.z += v.z; acc.w += v.w;
    }
    __shared__ float4 sp[8][32];
    sp[rg][c4] = acc;
    __syncthreads();
    if (rg == 0) {
        float4 s = sp[0][c4];
        #pragma unroll
        for (int i = 1; i < 8; i++) {
            float4 v = sp[i][c4];
            s.x += v.x; s.y += v.y; s.z += v.z; s.w += v.w;
        }
        float inv = 1.0f / npg;
        ((float4*)(g + b * 128))[c4] = make_float4(s.x * inv, s.y * inv, s.z * inv, s.w * inv);
    }
}

// ---------------- build head input X = [vH2 | vH0 | v_graph | p_graph] ----------------
__global__ void xbuild_k(const float* __restrict__ vH2, const float* __restrict__ vH0,
                         const float* __restrict__ vg, const float* __restrict__ pg,
                         float* __restrict__ X) {
    int idx = blockIdx.x * 256 + threadIdx.x;
    int row = idx >> 9, c = idx & 511;
    int b = row / 50;
    float v;
    if (c < 128) v = vH2[row * 128 + c];
    else if (c < 256) v = vH0[row * 128 + (c - 128)];
    else if (c < 384) v = vg[b * 128 + (c - 256)];
    else v = pg[b * 128 + (c - 384)];
    X[idx] = v;
}

// ---------------- final K=128 -> 1 dot + bias, f32 store ----------------
__global__ __launch_bounds__(256) void head3_k(const float* __restrict__ T2,
                                               const float* __restrict__ w,
                                               const float* __restrict__ b,
                                               float* __restrict__ out) {
    int row = blockIdx.x * 4 + (threadIdx.x >> 6);
    int lane = threadIdx.x & 63;
    const float2* t2 = (const float2*)&T2[(size_t)row * 128];
    const float2* w2 = (const float2*)w;
    float2 tv = t2[lane], wv = w2[lane];
    float acc = tv.x * wv.x + tv.y * wv.y;
    #pragma unroll
    for (int off = 32; off; off >>= 1) acc += __shfl_xor(acc, off);
    if (lane == 0) out[row] = acc + b[0];
}

extern "C" void kernel_launch(void* const* d_in, const int* in_sizes, int n_in,
                              void* d_out, int out_size, void* d_ws, size_t ws_size,
                              hipStream_t stream) {
    const float* p_x = (const float*)d_in[0];
    const float* v_x = (const float*)d_in[1];
    const int* p_ei = (const int*)d_in[2];
    const int* v_ei = (const int*)d_in[3];
    const float* pW0 = (const float*)d_in[6];  const float* pb0 = (const float*)d_in[7];
    const float* pW1 = (const float*)d_in[8];  const float* pb1 = (const float*)d_in[9];
    const float* pW2 = (const float*)d_in[10]; const float* pb2 = (const float*)d_in[11];
    const float* vW0 = (const float*)d_in[12]; const float* vb0 = (const float*)d_in[13];
    const float* vW1 = (const float*)d_in[14]; const float* vb1 = (const float*)d_in[15];
    const float* vW2 = (const float*)d_in[16]; const float* vb2 = (const float*)d_in[17];
    const float* hW1 = (const float*)d_in[18]; const float* hb1 = (const float*)d_in[19];
    const float* hW2 = (const float*)d_in[20]; const float* hb2 = (const float*)d_in[21];
    const float* hW3 = (const float*)d_in[22]; const float* hb3 = (const float*)d_in[23];

    char* w = (char*)d_ws;
    size_t off = 0;
    auto alloc = [&](size_t bytes) { char* p = w + off; off += (bytes + 255) & ~size_t(255); return p; };
    float* bufA   = (float*)alloc((size_t)NP_TOT * 128 * 4);   // 65.5 MB ping
    float* bufB   = (float*)alloc((size_t)NP_TOT * 128 * 4);   // 65.5 MB pong
    float* vH0    = (float*)alloc((size_t)NV_TOT * 128 * 4);
    float* vH2    = (float*)alloc((size_t)NV_TOT * 128 * 4);
    float* p_g    = (float*)alloc((size_t)NB * 128 * 4);
    float* v_g    = (float*)alloc((size_t)NB * 128 * 4);
    int*   adj_p  = (int*)alloc((size_t)NP_TOT * MAXDEG * 4);
    int*   cnt_p  = (int*)alloc((size_t)NP_TOT * 4);
    float* dinv_p = (float*)alloc((size_t)NP_TOT * 4);
    int*   adj_v  = (int*)alloc((size_t)NV_TOT * MAXDEG * 4);
    int*   cnt_v  = (int*)alloc((size_t)NV_TOT * 4);
    float* dinv_v = (float*)alloc((size_t)NV_TOT * 4);
    // head buffers reuse big ping/pong
    float* X  = bufA;                              // [12800,512] 26.2 MB
    float* T1 = bufB;                              // [12800,256] 13.1 MB
    float* T2 = (float*)((char*)bufB + (16u << 20)); // [12800,128] 6.6 MB

    hipMemsetAsync(cnt_p, 0, (size_t)NP_TOT * 4, stream);
    hipMemsetAsync(cnt_v, 0, (size_t)NV_TOT * 4, stream);
    adj_k<<<(EP_EDGES + 255) / 256, 256, 0, stream>>>(p_ei, cnt_p, adj_p, EP_EDGES);
    adj_k<<<(EV_EDGES + 255) / 256, 256, 0, stream>>>(v_ei, cnt_v, adj_v, EV_EDGES);
    dinv_k<<<(NP_TOT + 255) / 256, 256, 0, stream>>>(cnt_p, dinv_p, NP_TOT);
    dinv_k<<<(NV_TOT + 255) / 256, 256, 0, stream>>>(cnt_v, dinv_v, NV_TOT);

    // ---- v encoder ----
    gemm16_k<<<NV_TOT / 16, 256, 0, stream>>>(v_x, vW0, vb0, vH0, NV_TOT);
    gemm_mfma<<<dim3(NV_TOT / 128, 1), 256, 0, stream>>>(vH0, vW1, nullptr, dinv_v, bufA, NV_TOT, 128, 128, 0);
    gather_k<<<NV_TOT / 4, 256, 0, stream>>>(bufA, adj_v, cnt_v, dinv_v, vb1, bufB, NV_TOT, 1);
    gemm_mfma<<<dim3(NV_TOT / 128, 1), 256, 0, stream>>>(bufB, vW2, nullptr, dinv_v, bufA, NV_TOT, 128, 128, 0);
    gather_k<<<NV_TOT / 4, 256, 0, stream>>>(bufA, adj_v, cnt_v, dinv_v, vb2, vH2, NV_TOT, 0);
    pool_k<<<NB, 256, 0, stream>>>(vH2, v_g, 50);

    // ---- p encoder ----
    gemm16_k<<<NP_TOT / 16, 256, 0, stream>>>(p_x, pW0, pb0, bufA, NP_TOT);
    gemm_mfma<<<dim3(NP_TOT / 128, 1), 256, 0, stream>>>(bufA, pW1, nullptr, dinv_p, bufB, NP_TOT, 128, 128, 0);
    gather_k<<<NP_TOT / 4, 256, 0, stream>>>(bufB, adj_p, cnt_p, dinv_p, pb1, bufA, NP_TOT, 1);
    gemm_mfma<<<dim3(NP_TOT / 128, 1), 256, 0, stream>>>(bufA, pW2, nullptr, dinv_p, bufB, NP_TOT, 128, 128, 0);
    gather_k<<<NP_TOT / 4, 256, 0, stream>>>(bufB, adj_p, cnt_p, dinv_p, pb2, bufA, NP_TOT, 0);
    pool_k<<<NB, 256, 0, stream>>>(bufA, p_g, 500);

    // ---- head ----
    xbuild_k<<<(NV_TOT * 512) / 256, 256, 0, stream>>>(vH2, vH0, v_g, p_g, X);
    gemm_mfma<<<dim3(NV_TOT / 128, 2), 256, 0, stream>>>(X, hW1, hb1, nullptr, T1, NV_TOT, 512, 256, 2);
    gemm_mfma<<<dim3(NV_TOT / 128, 1), 256, 0, stream>>>(T1, hW2, hb2, nullptr, T2, NV_TOT, 256, 128, 2);
    head3_k<<<NV_TOT / 4, 256, 0, stream>>>(T2, hW3, hb3, (float*)d_out);
}

// Round 5
// 453.449 us; speedup vs baseline: 1.9189x; 1.1539x over previous
//
#include <hip/hip_runtime.h>
#include <hip/hip_bf16.h>

#define NP_TOT 128000
#define NV_TOT 12800
#define EP_EDGES 768000
#define EV_EDGES 51200
#define NB 256
#define MAXDEG 40

typedef short bf16x8 __attribute__((ext_vector_type(8)));
typedef float f32x4 __attribute__((ext_vector_type(4)));

static __device__ __forceinline__ unsigned short f2bf(float f) {
    unsigned u = __builtin_bit_cast(unsigned, f);
    unsigned r = u + 0x7FFFu + ((u >> 16) & 1u);   // RNE
    return (unsigned short)(r >> 16);
}
static __device__ __forceinline__ float bf2f(unsigned short h) {
    return __builtin_bit_cast(float, (unsigned)h << 16);
}

// ---------------- adjacency build ----------------
__global__ void adj_k(const int* __restrict__ ei, int* __restrict__ cnt,
                      int* __restrict__ adj, int NE) {
    int e = blockIdx.x * 256 + threadIdx.x;
    if (e >= NE) return;
    int dst = ei[NE + e];
    int slot = atomicAdd(&cnt[dst], 1);
    if (slot < MAXDEG) adj[dst * MAXDEG + slot] = ei[e];
}

__global__ void dinv_k(const int* __restrict__ cnt, float* __restrict__ dinv, int N) {
    int i = blockIdx.x * 256 + threadIdx.x;
    if (i < N) dinv[i] = rsqrtf(1.0f + (float)cnt[i]);
}

// ---------------- K=16 -> M=128 input GEMM: h0 = x@W0 + b0 ----------------
// writes outS = h0 * dinv[row]  (pre-scaled for aggregate-first GCN)
// optionally outP = h0 (unscaled, needed by v-encoder concat)
__global__ __launch_bounds__(256) void gemm16_k(const float* __restrict__ X,
                                                const float* __restrict__ W,
                                                const float* __restrict__ bias,
                                                const float* __restrict__ rs,
                                                float* __restrict__ outS,
                                                float* __restrict__ outP, int N) {
    __shared__ float sX[16][17];
    __shared__ float sW[16][128];
    int row0 = blockIdx.x * 16;
    int t = threadIdx.x;
    { int r = t >> 4, q = t & 15; sX[r][q] = X[(size_t)(row0 + r) * 16 + q]; }
    #pragma unroll
    for (int l = 0; l < 8; l++) {
        int lin = t + l * 256;
        sW[lin >> 7][lin & 127] = W[lin];
    }
    __syncthreads();
    int c = t & 127, rg = t >> 7;
    float acc[8];
    float b = bias[c];
    #pragma unroll
    for (int i = 0; i < 8; i++) acc[i] = b;
    #pragma unroll
    for (int k = 0; k < 16; k++) {
        float w = sW[k][c];
        #pragma unroll
        for (int i = 0; i < 8; i++) acc[i] += sX[rg * 8 + i][k] * w;
    }
    #pragma unroll
    for (int i = 0; i < 8; i++) {
        int row = row0 + rg * 8 + i;
        if (outP) outP[(size_t)row * 128 + c] = acc[i];
        outS[(size_t)row * 128 + c] = acc[i] * rs[row];
    }
}

// ---------------- fused GCN layer (aggregate-first) ----------------
// z[i] = dinv[i]*(g[i] + sum_{j in N(i)} g[j]);  h = z@W + bias
// mode bits: 1=relu, 2=scale output by dinv, 4=write out, 8=pool (mean into pool[batch])
// 512 threads = 8 waves; tile = 128 rows; W[128,128] held in registers (split bf16).
__global__ __launch_bounds__(512) void gcn_fused(const float* __restrict__ g,
                                                 const int* __restrict__ adj,
                                                 const int* __restrict__ cnt,
                                                 const float* __restrict__ dinv,
                                                 const float* __restrict__ W,
                                                 const float* __restrict__ bias,
                                                 float* __restrict__ out,
                                                 float* __restrict__ pool,
                                                 int npg, int mode) {
    __shared__ char lds[65536];
    char* zh = lds;            // [128 rows][128 k] bf16 hi, swizzled
    char* zl = lds + 32768;    // lo

    const int t = threadIdx.x;
    const int lane = t & 63;
    const int wvi = t >> 6;          // wave 0..7
    const int fr = lane & 15;
    const int fq = lane >> 4;

    int nb = gridDim.x;
    int bid = blockIdx.x;
    int swz = (nb & 7) ? bid : ((bid & 7) * (nb >> 3) + (bid >> 3));  // XCD chunking
    int row0 = swz * 128;

    // ---- W fragments into registers: col = wvi*16+fr, k = ks*32+fq*8+j ----
    const int colW = wvi * 16 + fr;
    bf16x8 wh[4], wl[4];
    #pragma unroll
    for (int ks = 0; ks < 4; ks++) {
        short hh[8], ll[8];
        #pragma unroll
        for (int j = 0; j < 8; j++) {
            float x = W[(size_t)(ks * 32 + fq * 8 + j) * 128 + colW];
            unsigned short h = f2bf(x);
            hh[j] = (short)h;
            ll[j] = (short)f2bf(x - bf2f(h));
        }
        wh[ks] = (bf16x8){hh[0],hh[1],hh[2],hh[3],hh[4],hh[5],hh[6],hh[7]};
        wl[ks] = (bf16x8){ll[0],ll[1],ll[2],ll[3],ll[4],ll[5],ll[6],ll[7]};
    }

    // ---- gather phase: wave handles rows wvi, wvi+8, ... ----
    const float2* g2 = (const float2*)g;
    for (int gi = 0; gi < 16; gi++) {
        int r = gi * 8 + wvi;
        int node = row0 + r;
        int d = cnt[node];
        if (d > MAXDEG) d = MAXDEG;
        const int* ap = adj + (size_t)node * MAXDEG;
        int4 i0 = *(const int4*)ap;
        int4 i1 = *(const int4*)(ap + 4);
        int4 i2 = *(const int4*)(ap + 8);
        float2 acc = g2[(size_t)node * 64 + lane];
        int idx[12] = {i0.x,i0.y,i0.z,i0.w,i1.x,i1.y,i1.z,i1.w,i2.x,i2.y,i2.z,i2.w};
        #pragma unroll
        for (int e = 0; e < 12; e++) {
            bool valid = e < d;
            int s = valid ? idx[e] : node;
            float2 v = g2[(size_t)s * 64 + lane];
            float m = valid ? 1.0f : 0.0f;
            acc.x += m * v.x; acc.y += m * v.y;
        }
        for (int e = 12; e < d; e++) {
            int s = ap[e];
            float2 v = g2[(size_t)s * 64 + lane];
            acc.x += v.x; acc.y += v.y;
        }
        float di = dinv[node];
        float zx = di * acc.x, zy = di * acc.y;
        unsigned short hx = f2bf(zx), hy = f2bf(zy);
        unsigned short lx = f2bf(zx - bf2f(hx)), ly = f2bf(zy - bf2f(hy));
        int off = r * 256 + ((lane * 4) ^ ((r & 7) << 4));
        *(unsigned*)(zh + off) = (unsigned)hx | ((unsigned)hy << 16);
        *(unsigned*)(zl + off) = (unsigned)lx | ((unsigned)ly << 16);
    }
    __syncthreads();

    // ---- MFMA phase: 3-pass split-bf16 ----
    f32x4 acc[8];
    #pragma unroll
    for (int m = 0; m < 8; m++) acc[m] = (f32x4){0.f, 0.f, 0.f, 0.f};
    #pragma unroll
    for (int ks = 0; ks < 4; ks++) {
        int kbyte = ks * 64 + fq * 16;
        #pragma unroll
        for (int m = 0; m < 8; m++) {
            int r = m * 16 + fr;
            int off = r * 256 + (kbyte ^ ((r & 7) << 4));
            bf16x8 ah = *(bf16x8*)(zh + off);
            bf16x8 al = *(bf16x8*)(zl + off);
            acc[m] = __builtin_amdgcn_mfma_f32_16x16x32_bf16(ah, wh[ks], acc[m], 0, 0, 0);
            acc[m] = __builtin_amdgcn_mfma_f32_16x16x32_bf16(ah, wl[ks], acc[m], 0, 0, 0);
            acc[m] = __builtin_amdgcn_mfma_f32_16x16x32_bf16(al, wh[ks], acc[m], 0, 0, 0);
        }
    }

    // ---- epilogue ----
    const int col = wvi * 16 + fr;
    const float bcol = bias[col];
    const float invn = 1.0f / npg;
    #pragma unroll
    for (int m = 0; m < 8; m++) {
        int R = row0 + m * 16;                   // chunk of 16 rows
        float vj[4];
        #pragma unroll
        for (int j = 0; j < 4; j++) {
            int row = R + fq * 4 + j;
            float v = acc[m][j] + bcol;
            if (mode & 1) v = fmaxf(v, 0.f);
            vj[j] = v;
            if (mode & 4) {
                float wv_ = (mode & 2) ? v * dinv[row] : v;
                out[(size_t)row * 128 + col] = wv_;
            }
        }
        if (mode & 8) {
            int b0 = R / npg;
            int bound = (b0 + 1) * npg;
            float s0 = 0.f, s1 = 0.f;
            #pragma unroll
            for (int j = 0; j < 4; j++) {
                int row = R + fq * 4 + j;
                if (row < bound) s0 += vj[j]; else s1 += vj[j];
            }
            s0 += __shfl_xor(s0, 16); s0 += __shfl_xor(s0, 32);
            s1 += __shfl_xor(s1, 16); s1 += __shfl_xor(s1, 32);
            if (fq == 0) {
                atomicAdd(&pool[b0 * 128 + col], s0 * invn);
                if (R + 16 > bound) atomicAdd(&pool[(b0 + 1) * 128 + col], s1 * invn);
            }
        }
    }
}

// ---------------- split-bf16 3-pass MFMA GEMM (head layers) ----------------
// out[N,M] = act( A_cat[N,K] @ W[K,M] + bias[col] + addrow[(row/50)*M+col] )
// A_cat: k<128 from A, k>=128 from A2 (if A2 != null); row stride = astride.
__global__ __launch_bounds__(256) void gemm_mfma(const float* __restrict__ A,
                                                 const float* __restrict__ A2,
                                                 const float* __restrict__ W,
                                                 const float* __restrict__ bias,
                                                 const float* __restrict__ addrow,
                                                 float* __restrict__ out,
                                                 int N, int K, int M, int act,
                                                 int astride) {
    __shared__ char lds[65536];
    char* sAh = lds;
    char* sAl = lds + 16384;
    char* sWh = lds + 32768;
    char* sWl = lds + 49152;

    const int t = threadIdx.x;
    const int lane = t & 63;
    const int wv = t >> 6;
    const int row0 = blockIdx.x * 128;
    const int c0 = blockIdx.y * 128;
    const int fr = lane & 15;
    const int fq = lane >> 4;

    f32x4 acc[8][2];
    #pragma unroll
    for (int m = 0; m < 8; m++)
        #pragma unroll
        for (int n = 0; n < 2; n++) acc[m][n] = (f32x4){0.f, 0.f, 0.f, 0.f};

    for (int k0 = 0; k0 < K; k0 += 64) {
        const float* src = A;
        int kk = k0;
        if (A2 && k0 >= 128) { src = A2; kk = k0 - 128; }
        __syncthreads();
        #pragma unroll
        for (int i = 0; i < 8; i++) {
            int idx = t + i * 256;
            int r = idx >> 4, kq = idx & 15;
            float4 a = *(const float4*)&src[(size_t)(row0 + r) * astride + kk + kq * 4];
            unsigned short h0 = f2bf(a.x), h1 = f2bf(a.y), h2 = f2bf(a.z), h3 = f2bf(a.w);
            unsigned short l0 = f2bf(a.x - bf2f(h0)), l1 = f2bf(a.y - bf2f(h1));
            unsigned short l2 = f2bf(a.z - bf2f(h2)), l3 = f2bf(a.w - bf2f(h3));
            int off = r * 128 + ((kq * 8) ^ ((r & 7) << 4));
            *(uint2*)(sAh + off) = make_uint2((unsigned)h0 | ((unsigned)h1 << 16),
                                              (unsigned)h2 | ((unsigned)h3 << 16));
            *(uint2*)(sAl + off) = make_uint2((unsigned)l0 | ((unsigned)l1 << 16),
                                              (unsigned)l2 | ((unsigned)l3 << 16));
        }
        {
            int n = t & 127, kc = t >> 7;
            #pragma unroll
            for (int r = 0; r < 4; r++) {
                int krel = r * 16 + kc * 8;
                unsigned short hh[8], ll[8];
                #pragma unroll
                for (int j = 0; j < 8; j++) {
                    float wv_ = W[(size_t)(k0 + krel + j) * M + c0 + n];
                    hh[j] = f2bf(wv_);
                    ll[j] = f2bf(wv_ - bf2f(hh[j]));
                }
                int off = n * 128 + ((krel * 2) ^ ((n & 7) << 4));
                uint4 ph, pl;
                ph.x = (unsigned)hh[0] | ((unsigned)hh[1] << 16);
                ph.y = (unsigned)hh[2] | ((unsigned)hh[3] << 16);
                ph.z = (unsigned)hh[4] | ((unsigned)hh[5] << 16);
                ph.w = (unsigned)hh[6] | ((unsigned)hh[7] << 16);
                pl.x = (unsigned)ll[0] | ((unsigned)ll[1] << 16);
                pl.y = (unsigned)ll[2] | ((unsigned)ll[3] << 16);
                pl.z = (unsigned)ll[4] | ((unsigned)ll[5] << 16);
                pl.w = (unsigned)ll[6] | ((unsigned)ll[7] << 16);
                *(uint4*)(sWh + off) = ph;
                *(uint4*)(sWl + off) = pl;
            }
        }
        __syncthreads();
        #pragma unroll
        for (int ks = 0; ks < 2; ks++) {
            int kbyte = ks * 64 + fq * 16;
            bf16x8 bh[2], bl[2];
            #pragma unroll
            for (int nf = 0; nf < 2; nf++) {
                int n = wv * 32 + nf * 16 + fr;
                int off = n * 128 + (kbyte ^ ((n & 7) << 4));
                bh[nf] = *(bf16x8*)(sWh + off);
                bl[nf] = *(bf16x8*)(sWl + off);
            }
            #pragma unroll
            for (int m = 0; m < 8; m++) {
                int r = m * 16 + fr;
                int off = r * 128 + (kbyte ^ ((r & 7) << 4));
                bf16x8 ah = *(bf16x8*)(sAh + off);
                bf16x8 al = *(bf16x8*)(sAl + off);
                #pragma unroll
                for (int nf = 0; nf < 2; nf++) {
                    acc[m][nf] = __builtin_amdgcn_mfma_f32_16x16x32_bf16(ah, bh[nf], acc[m][nf], 0, 0, 0);
                    acc[m][nf] = __builtin_amdgcn_mfma_f32_16x16x32_bf16(ah, bl[nf], acc[m][nf], 0, 0, 0);
                    acc[m][nf] = __builtin_amdgcn_mfma_f32_16x16x32_bf16(al, bh[nf], acc[m][nf], 0, 0, 0);
                }
            }
        }
    }

    #pragma unroll
    for (int m = 0; m < 8; m++) {
        int rbase = row0 + m * 16 + fq * 4;
        #pragma unroll
        for (int nf = 0; nf < 2; nf++) {
            int col = c0 + wv * 32 + nf * 16 + fr;
            float b = bias ? bias[col] : 0.0f;
            #pragma unroll
            for (int j = 0; j < 4; j++) {
                int row = rbase + j;
                float ar = addrow ? addrow[(size_t)(row / 50) * M + col] : 0.0f;
                float v = acc[m][nf][j] + b + ar;
                if (act == 1) v = fmaxf(v, 0.f);
                else if (act == 2) v = v > 0.f ? v : 0.01f * v;
                out[(size_t)row * M + col] = v;
            }
        }
    }
}

// ---------------- final K=128 -> 1 dot + bias, f32 store ----------------
__global__ __launch_bounds__(256) void head3_k(const float* __restrict__ T2,
                                               const float* __restrict__ w,
                                               const float* __restrict__ b,
                                               float* __restrict__ out) {
    int row = blockIdx.x * 4 + (threadIdx.x >> 6);
    int lane = threadIdx.x & 63;
    const float2* t2 = (const float2*)&T2[(size_t)row * 128];
    const float2* w2 = (const float2*)w;
    float2 tv = t2[lane], wv = w2[lane];
    float acc = tv.x * wv.x + tv.y * wv.y;
    #pragma unroll
    for (int off = 32; off; off >>= 1) acc += __shfl_xor(acc, off);
    if (lane == 0) out[row] = acc + b[0];
}

extern "C" void kernel_launch(void* const* d_in, const int* in_sizes, int n_in,
                              void* d_out, int out_size, void* d_ws, size_t ws_size,
                              hipStream_t stream) {
    const float* p_x = (const float*)d_in[0];
    const float* v_x = (const float*)d_in[1];
    const int* p_ei = (const int*)d_in[2];
    const int* v_ei = (const int*)d_in[3];
    const float* pW0 = (const float*)d_in[6];  const float* pb0 = (const float*)d_in[7];
    const float* pW1 = (const float*)d_in[8];  const float* pb1 = (const float*)d_in[9];
    const float* pW2 = (const float*)d_in[10]; const float* pb2 = (const float*)d_in[11];
    const float* vW0 = (const float*)d_in[12]; const float* vb0 = (const float*)d_in[13];
    const float* vW1 = (const float*)d_in[14]; const float* vb1 = (const float*)d_in[15];
    const float* vW2 = (const float*)d_in[16]; const float* vb2 = (const float*)d_in[17];
    const float* hW1 = (const float*)d_in[18]; const float* hb1 = (const float*)d_in[19];
    const float* hW2 = (const float*)d_in[20]; const float* hb2 = (const float*)d_in[21];
    const float* hW3 = (const float*)d_in[22]; const float* hb3 = (const float*)d_in[23];

    char* w = (char*)d_ws;
    size_t off = 0;
    auto alloc = [&](size_t bytes) { char* p = w + off; off += (bytes + 255) & ~size_t(255); return p; };
    float* bufA   = (float*)alloc((size_t)NP_TOT * 128 * 4);   // g0p, later T1
    float* bufB   = (float*)alloc((size_t)NP_TOT * 128 * 4);   // g1p, later T2
    float* g0v    = (float*)alloc((size_t)NV_TOT * 128 * 4);
    float* g1v    = (float*)alloc((size_t)NV_TOT * 128 * 4);
    float* vH0    = (float*)alloc((size_t)NV_TOT * 128 * 4);
    float* vH2    = (float*)alloc((size_t)NV_TOT * 128 * 4);
    float* p_g    = (float*)alloc((size_t)NB * 128 * 4);       // contiguous with v_g
    float* v_g    = (float*)alloc((size_t)NB * 128 * 4);
    float* Gmix   = (float*)alloc((size_t)NB * 256 * 4);
    int*   adj_p  = (int*)alloc((size_t)NP_TOT * MAXDEG * 4);
    int*   cnt_p  = (int*)alloc((size_t)NP_TOT * 4);           // contiguous with cnt_v
    int*   cnt_v  = (int*)alloc((size_t)NV_TOT * 4);
    float* dinv_p = (float*)alloc((size_t)NP_TOT * 4);
    int*   adj_v  = (int*)alloc((size_t)NV_TOT * MAXDEG * 4);
    float* dinv_v = (float*)alloc((size_t)NV_TOT * 4);
    float* T1 = bufA;   // [12800,256]
    float* T2 = bufB;   // [12800,128]

    hipMemsetAsync(cnt_p, 0, (size_t)(NP_TOT + NV_TOT) * 4, stream);
    hipMemsetAsync(p_g, 0, (size_t)2 * NB * 128 * 4, stream);
    adj_k<<<(EP_EDGES + 255) / 256, 256, 0, stream>>>(p_ei, cnt_p, adj_p, EP_EDGES);
    adj_k<<<(EV_EDGES + 255) / 256, 256, 0, stream>>>(v_ei, cnt_v, adj_v, EV_EDGES);
    dinv_k<<<(NP_TOT + 255) / 256, 256, 0, stream>>>(cnt_p, dinv_p, NP_TOT);
    dinv_k<<<(NV_TOT + 255) / 256, 256, 0, stream>>>(cnt_v, dinv_v, NV_TOT);

    // ---- v encoder ----
    gemm16_k<<<NV_TOT / 16, 256, 0, stream>>>(v_x, vW0, vb0, dinv_v, g0v, vH0, NV_TOT);
    gcn_fused<<<NV_TOT / 128, 512, 0, stream>>>(g0v, adj_v, cnt_v, dinv_v, vW1, vb1,
                                                g1v, nullptr, 50, 1 | 2 | 4);
    gcn_fused<<<NV_TOT / 128, 512, 0, stream>>>(g1v, adj_v, cnt_v, dinv_v, vW2, vb2,
                                                vH2, v_g, 50, 4 | 8);

    // ---- p encoder ----
    gemm16_k<<<NP_TOT / 16, 256, 0, stream>>>(p_x, pW0, pb0, dinv_p, bufA, nullptr, NP_TOT);
    gcn_fused<<<NP_TOT / 128, 512, 0, stream>>>(bufA, adj_p, cnt_p, dinv_p, pW1, pb1,
                                                bufB, nullptr, 500, 1 | 2 | 4);
    gcn_fused<<<NP_TOT / 128, 512, 0, stream>>>(bufB, adj_p, cnt_p, dinv_p, pW2, pb2,
                                                nullptr, p_g, 500, 8);

    // ---- head ----
    // Gmix[b,:] = [v_g|p_g][b,:] @ hW1[256:512,:] + hb1
    gemm_mfma<<<dim3(2, 2), 256, 0, stream>>>(v_g, p_g, hW1 + (size_t)256 * 256, hb1,
                                              nullptr, Gmix, NB, 256, 256, 0, 128);
    // T1 = leaky( [vH2|vH0] @ hW1[0:256,:] + Gmix[row/50] )
    gemm_mfma<<<dim3(NV_TOT / 128, 2), 256, 0, stream>>>(vH2, vH0, hW1, nullptr,
                                                         Gmix, T1, NV_TOT, 256, 256, 2, 128);
    // T2 = leaky( T1 @ hW2 + hb2 )
    gemm_mfma<<<dim3(NV_TOT / 128, 1), 256, 0, stream>>>(T1, nullptr, hW2, hb2,
                                                         nullptr, T2, NV_TOT, 256, 128, 2, 256);
    head3_k<<<NV_TOT / 4, 256, 0, stream>>>(T2, hW3, hb3, (float*)d_out);
}

// Round 6
// 335.245 us; speedup vs baseline: 2.5955x; 1.3526x over previous
//
#include <hip/hip_runtime.h>
#include <hip/hip_bf16.h>

#define NP_TOT 128000
#define NV_TOT 12800
#define EP_EDGES 768000
#define EV_EDGES 51200
#define NB 256
#define MAXDEG 40

typedef short bf16x8 __attribute__((ext_vector_type(8)));
typedef float f32x4 __attribute__((ext_vector_type(4)));

static __device__ __forceinline__ unsigned short f2bf(float f) {
    unsigned u = __builtin_bit_cast(unsigned, f);
    unsigned r = u + 0x7FFFu + ((u >> 16) & 1u);   // RNE
    return (unsigned short)(r >> 16);
}
static __device__ __forceinline__ float bf2f(unsigned short h) {
    return __builtin_bit_cast(float, (unsigned)h << 16);
}

// ---------------- adjacency build ----------------
__global__ void adj_k(const int* __restrict__ ei, int* __restrict__ cnt,
                      int* __restrict__ adj, int NE) {
    int e = blockIdx.x * 256 + threadIdx.x;
    if (e >= NE) return;
    int dst = ei[NE + e];
    int slot = atomicAdd(&cnt[dst], 1);
    if (slot < MAXDEG) adj[dst * MAXDEG + slot] = ei[e];
}

__global__ void dinv_k(const int* __restrict__ cnt, float* __restrict__ dinv, int N) {
    int i = blockIdx.x * 256 + threadIdx.x;
    if (i < N) dinv[i] = rsqrtf(1.0f + (float)cnt[i]);
}

// c[src] += dinv[dst] over edges  (for pool-first layer-2 trick)
__global__ void c_k(const int* __restrict__ ei, const float* __restrict__ dinv,
                    float* __restrict__ c, int NE) {
    int e = blockIdx.x * 256 + threadIdx.x;
    if (e >= NE) return;
    atomicAdd(&c[ei[e]], dinv[ei[NE + e]]);
}

// W01 = W0[16,128] @ W1[128,128], b01 = b0 @ W1   (one block, 128 threads)
__global__ __launch_bounds__(128) void w01_k(const float* __restrict__ W0,
                                             const float* __restrict__ b0,
                                             const float* __restrict__ W1,
                                             float* __restrict__ W01,
                                             float* __restrict__ b01) {
    int col = threadIdx.x;
    float acc[17];
    #pragma unroll
    for (int r = 0; r < 17; r++) acc[r] = 0.f;
    for (int i = 0; i < 128; i++) {
        float w1 = W1[i * 128 + col];
        #pragma unroll
        for (int r = 0; r < 16; r++) acc[r] += W0[r * 128 + i] * w1;
        acc[16] += b0[i] * w1;
    }
    #pragma unroll
    for (int r = 0; r < 16; r++) W01[r * 128 + col] = acc[r];
    b01[col] = acc[16];
}

// ---------------- K=16 -> M=128 input GEMM: h0 = x@W0 + b0 (v only) ----------------
__global__ __launch_bounds__(256) void gemm16_k(const float* __restrict__ X,
                                                const float* __restrict__ W,
                                                const float* __restrict__ bias,
                                                const float* __restrict__ rs,
                                                float* __restrict__ outS,
                                                float* __restrict__ outP, int N) {
    __shared__ float sX[16][17];
    __shared__ float sW[16][128];
    int row0 = blockIdx.x * 16;
    int t = threadIdx.x;
    { int r = t >> 4, q = t & 15; sX[r][q] = X[(size_t)(row0 + r) * 16 + q]; }
    #pragma unroll
    for (int l = 0; l < 8; l++) {
        int lin = t + l * 256;
        sW[lin >> 7][lin & 127] = W[lin];
    }
    __syncthreads();
    int c = t & 127, rg = t >> 7;
    float acc[8];
    float b = bias[c];
    #pragma unroll
    for (int i = 0; i < 8; i++) acc[i] = b;
    #pragma unroll
    for (int k = 0; k < 16; k++) {
        float w = sW[k][c];
        #pragma unroll
        for (int i = 0; i < 8; i++) acc[i] += sX[rg * 8 + i][k] * w;
    }
    #pragma unroll
    for (int i = 0; i < 8; i++) {
        int row = row0 + rg * 8 + i;
        if (outP) outP[(size_t)row * 128 + c] = acc[i];
        outS[(size_t)row * 128 + c] = acc[i] * rs[row];
    }
}

// ---------------- fused GCN layer (v encoder; aggregate-first, 128-dim gather) -----
// mode bits: 1=relu, 2=scale out by dinv, 4=write out, 8=pool mean into pool[batch]
__global__ __launch_bounds__(512) void gcn_fused(const float* __restrict__ g,
                                                 const int* __restrict__ adj,
                                                 const int* __restrict__ cnt,
                                                 const float* __restrict__ dinv,
                                                 const float* __restrict__ W,
                                                 const float* __restrict__ bias,
                                                 float* __restrict__ out,
                                                 float* __restrict__ pool,
                                                 int npg, int mode) {
    __shared__ char lds[65536];
    char* zh = lds;
    char* zl = lds + 32768;

    const int t = threadIdx.x;
    const int lane = t & 63;
    const int wvi = t >> 6;
    const int fr = lane & 15;
    const int fq = lane >> 4;

    int nb = gridDim.x;
    int bid = blockIdx.x;
    int swz = (nb & 7) ? bid : ((bid & 7) * (nb >> 3) + (bid >> 3));
    int row0 = swz * 128;

    const int colW = wvi * 16 + fr;
    bf16x8 wh[4], wl[4];
    #pragma unroll
    for (int ks = 0; ks < 4; ks++) {
        short hh[8], ll[8];
        #pragma unroll
        for (int j = 0; j < 8; j++) {
            float x = W[(size_t)(ks * 32 + fq * 8 + j) * 128 + colW];
            unsigned short h = f2bf(x);
            hh[j] = (short)h;
            ll[j] = (short)f2bf(x - bf2f(h));
        }
        wh[ks] = (bf16x8){hh[0],hh[1],hh[2],hh[3],hh[4],hh[5],hh[6],hh[7]};
        wl[ks] = (bf16x8){ll[0],ll[1],ll[2],ll[3],ll[4],ll[5],ll[6],ll[7]};
    }

    const float2* g2 = (const float2*)g;
    for (int gi = 0; gi < 16; gi++) {
        int r = gi * 8 + wvi;
        int node = row0 + r;
        int d = cnt[node];
        if (d > MAXDEG) d = MAXDEG;
        const int* ap = adj + (size_t)node * MAXDEG;
        int4 i0 = *(const int4*)ap;
        int4 i1 = *(const int4*)(ap + 4);
        int4 i2 = *(const int4*)(ap + 8);
        float2 acc = g2[(size_t)node * 64 + lane];
        int idx[12] = {i0.x,i0.y,i0.z,i0.w,i1.x,i1.y,i1.z,i1.w,i2.x,i2.y,i2.z,i2.w};
        #pragma unroll
        for (int e = 0; e < 12; e++) {
            bool valid = e < d;
            int s = valid ? idx[e] : node;
            float2 v = g2[(size_t)s * 64 + lane];
            float m = valid ? 1.0f : 0.0f;
            acc.x += m * v.x; acc.y += m * v.y;
        }
        for (int e = 12; e < d; e++) {
            int s = ap[e];
            float2 v = g2[(size_t)s * 64 + lane];
            acc.x += v.x; acc.y += v.y;
        }
        float di = dinv[node];
        float zx = di * acc.x, zy = di * acc.y;
        unsigned short hx = f2bf(zx), hy = f2bf(zy);
        unsigned short lx = f2bf(zx - bf2f(hx)), ly = f2bf(zy - bf2f(hy));
        int off = r * 256 + ((lane * 4) ^ ((r & 7) << 4));
        *(unsigned*)(zh + off) = (unsigned)hx | ((unsigned)hy << 16);
        *(unsigned*)(zl + off) = (unsigned)lx | ((unsigned)ly << 16);
    }
    __syncthreads();

    f32x4 acc[8];
    #pragma unroll
    for (int m = 0; m < 8; m++) acc[m] = (f32x4){0.f, 0.f, 0.f, 0.f};
    #pragma unroll
    for (int ks = 0; ks < 4; ks++) {
        int kbyte = ks * 64 + fq * 16;
        #pragma unroll
        for (int m = 0; m < 8; m++) {
            int r = m * 16 + fr;
            int off = r * 256 + (kbyte ^ ((r & 7) << 4));
            bf16x8 ah = *(bf16x8*)(zh + off);
            bf16x8 al = *(bf16x8*)(zl + off);
            acc[m] = __builtin_amdgcn_mfma_f32_16x16x32_bf16(ah, wh[ks], acc[m], 0, 0, 0);
            acc[m] = __builtin_amdgcn_mfma_f32_16x16x32_bf16(ah, wl[ks], acc[m], 0, 0, 0);
            acc[m] = __builtin_amdgcn_mfma_f32_16x16x32_bf16(al, wh[ks], acc[m], 0, 0, 0);
        }
    }

    const int col = wvi * 16 + fr;
    const float bcol = bias[col];
    const float invn = 1.0f / npg;
    #pragma unroll
    for (int m = 0; m < 8; m++) {
        int R = row0 + m * 16;
        float vj[4];
        #pragma unroll
        for (int j = 0; j < 4; j++) {
            int row = R + fq * 4 + j;
            float v = acc[m][j] + bcol;
            if (mode & 1) v = fmaxf(v, 0.f);
            vj[j] = v;
            if (mode & 4) {
                float wv_ = (mode & 2) ? v * dinv[row] : v;
                out[(size_t)row * 128 + col] = wv_;
            }
        }
        if (mode & 8) {
            int b0 = R / npg;
            int bound = (b0 + 1) * npg;
            float s0 = 0.f, s1 = 0.f;
            #pragma unroll
            for (int j = 0; j < 4; j++) {
                int row = R + fq * 4 + j;
                if (row < bound) s0 += vj[j]; else s1 += vj[j];
            }
            s0 += __shfl_xor(s0, 16); s0 += __shfl_xor(s0, 32);
            s1 += __shfl_xor(s1, 16); s1 += __shfl_xor(s1, 32);
            if (fq == 0) {
                atomicAdd(&pool[b0 * 128 + col], s0 * invn);
                if (R + 16 > bound) atomicAdd(&pool[(b0 + 1) * 128 + col], s1 * invn);
            }
        }
    }
}

// ---------------- fully-fused p encoder ----------------
// agg_i = dinv_i*(dinv_i*x_i + sum_j dinv_j*x_j)  (16-dim gather)
// h1_i  = relu(agg_i@W01 + beta_i*b01 + b1),  beta_i = dinv_i*(dinv_i + sum_j dinv_j)
// pool[b] += sum_{i in b} pw_i * h1_i,  pw_i = dinv_i*(dinv_i + c_i)/npg
// Block: 512 threads, 128 nodes. LDS: zA [128][pitch 80B] (k0..15=hi, 16..31=lo) + beta + pw.
__global__ __launch_bounds__(512) void pfused(const float* __restrict__ x,
                                              const int* __restrict__ adj,
                                              const int* __restrict__ cnt,
                                              const float* __restrict__ dinv,
                                              const float* __restrict__ cw,
                                              const float* __restrict__ W01,
                                              const float* __restrict__ b01,
                                              const float* __restrict__ b1,
                                              float* __restrict__ pool, int npg) {
    __shared__ char lds[80 * 128 + 1024];
    float* sbeta = (float*)(lds + 80 * 128);
    float* spw   = sbeta + 128;

    const int t = threadIdx.x;
    int nb = gridDim.x;
    int bid = blockIdx.x;
    int swz = (nb & 7) ? bid : ((bid & 7) * (nb >> 3) + (bid >> 3));
    int row0 = swz * 128;

    // ---- phase A: 16-dim gather; 4 threads per node (one float4 each) ----
    {
        int ns = t >> 2, q = t & 3;
        int node = row0 + ns;
        float di = dinv[node];
        int d = cnt[node];
        if (d > MAXDEG) d = MAXDEG;
        const int* ap = adj + (size_t)node * MAXDEG;
        int4 i0 = *(const int4*)ap;
        int4 i1 = *(const int4*)(ap + 4);
        int4 i2 = *(const int4*)(ap + 8);
        const float4* x4 = (const float4*)x;
        float4 xo = x4[(size_t)node * 4 + q];
        float ax = di * xo.x, ay = di * xo.y, az = di * xo.z, aw = di * xo.w;
        float tsum = 0.f;
        int idx[12] = {i0.x,i0.y,i0.z,i0.w,i1.x,i1.y,i1.z,i1.w,i2.x,i2.y,i2.z,i2.w};
        #pragma unroll
        for (int e = 0; e < 12; e++) {
            bool valid = e < d;
            int s = valid ? idx[e] : node;
            float dj = valid ? dinv[s] : 0.f;
            float4 v = x4[(size_t)s * 4 + q];
            ax += dj * v.x; ay += dj * v.y; az += dj * v.z; aw += dj * v.w;
            tsum += dj;
        }
        for (int e = 12; e < d; e++) {
            int s = ap[e];
            float dj = dinv[s];
            float4 v = x4[(size_t)s * 4 + q];
            ax += dj * v.x; ay += dj * v.y; az += dj * v.z; aw += dj * v.w;
            tsum += dj;
        }
        ax *= di; ay *= di; az *= di; aw *= di;
        unsigned short h0 = f2bf(ax), h1 = f2bf(ay), h2 = f2bf(az), h3 = f2bf(aw);
        unsigned short l0 = f2bf(ax - bf2f(h0)), l1 = f2bf(ay - bf2f(h1));
        unsigned short l2 = f2bf(az - bf2f(h2)), l3 = f2bf(aw - bf2f(h3));
        char* base = lds + ns * 80;
        *(unsigned*)(base + q * 8)     = (unsigned)h0 | ((unsigned)h1 << 16);
        *(unsigned*)(base + q * 8 + 4) = (unsigned)h2 | ((unsigned)h3 << 16);
        *(unsigned*)(base + 32 + q * 8)     = (unsigned)l0 | ((unsigned)l1 << 16);
        *(unsigned*)(base + 32 + q * 8 + 4) = (unsigned)l2 | ((unsigned)l3 << 16);
        if (q == 0) {
            sbeta[ns] = di * (di + tsum);
            spw[ns]   = di * (di + cw[node]) * (1.0f / npg);
        }
    }
    __syncthreads();

    // ---- phase B: MFMA (K=32: hi|lo packed), 2 MFMAs per m-tile ----
    const int lane = t & 63;
    const int wvi = t >> 6;
    const int fr = lane & 15;
    const int fq = lane >> 4;
    const int col = wvi * 16 + fr;

    bf16x8 B1, B2;
    {
        short b1a[8], b2a[8];
        #pragma unroll
        for (int j = 0; j < 8; j++) {
            int kk = fq * 8 + j;
            float wf = W01[(size_t)(kk & 15) * 128 + col];
            unsigned short h = f2bf(wf);
            b1a[j] = (short)h;
            b2a[j] = (kk < 16) ? (short)f2bf(wf - bf2f(h)) : (short)0;
        }
        B1 = (bf16x8){b1a[0],b1a[1],b1a[2],b1a[3],b1a[4],b1a[5],b1a[6],b1a[7]};
        B2 = (bf16x8){b2a[0],b2a[1],b2a[2],b2a[3],b2a[4],b2a[5],b2a[6],b2a[7]};
    }

    f32x4 acc[8];
    #pragma unroll
    for (int m = 0; m < 8; m++) acc[m] = (f32x4){0.f, 0.f, 0.f, 0.f};
    #pragma unroll
    for (int m = 0; m < 8; m++) {
        int r = m * 16 + fr;
        bf16x8 a = *(bf16x8*)(lds + r * 80 + fq * 16);
        acc[m] = __builtin_amdgcn_mfma_f32_16x16x32_bf16(a, B1, acc[m], 0, 0, 0);
        acc[m] = __builtin_amdgcn_mfma_f32_16x16x32_bf16(a, B2, acc[m], 0, 0, 0);
    }

    // ---- epilogue: bias, relu, weighted pool ----
    float b01c = b01[col];
    float b1c = b1[col];
    int b0 = row0 / npg;
    int bound = (b0 + 1) * npg;
    float sA = 0.f, sB = 0.f;
    #pragma unroll
    for (int m = 0; m < 8; m++) {
        #pragma unroll
        for (int j = 0; j < 4; j++) {
            int rl = m * 16 + fq * 4 + j;
            float v = acc[m][j] + sbeta[rl] * b01c + b1c;
            v = fmaxf(v, 0.f);
            float pv = spw[rl] * v;
            if (row0 + rl < bound) sA += pv; else sB += pv;
        }
    }
    sA += __shfl_xor(sA, 16); sA += __shfl_xor(sA, 32);
    sB += __shfl_xor(sB, 16); sB += __shfl_xor(sB, 32);
    if (fq == 0) {
        atomicAdd(&pool[b0 * 128 + col], sA);
        if (row0 + 127 >= bound) atomicAdd(&pool[(b0 + 1) * 128 + col], sB);
    }
}

// ---------------- split-bf16 3-pass MFMA GEMM (head + p_g) ----------------
__global__ __launch_bounds__(256) void gemm_mfma(const float* __restrict__ A,
                                                 const float* __restrict__ A2,
                                                 const float* __restrict__ W,
                                                 const float* __restrict__ bias,
                                                 const float* __restrict__ addrow,
                                                 float* __restrict__ out,
                                                 int N, int K, int M, int act,
                                                 int astride) {
    __shared__ char lds[65536];
    char* sAh = lds;
    char* sAl = lds + 16384;
    char* sWh = lds + 32768;
    char* sWl = lds + 49152;

    const int t = threadIdx.x;
    const int lane = t & 63;
    const int wv = t >> 6;
    const int row0 = blockIdx.x * 128;
    const int c0 = blockIdx.y * 128;
    const int fr = lane & 15;
    const int fq = lane >> 4;

    f32x4 acc[8][2];
    #pragma unroll
    for (int m = 0; m < 8; m++)
        #pragma unroll
        for (int n = 0; n < 2; n++) acc[m][n] = (f32x4){0.f, 0.f, 0.f, 0.f};

    for (int k0 = 0; k0 < K; k0 += 64) {
        const float* src = A;
        int kk = k0;
        if (A2 && k0 >= 128) { src = A2; kk = k0 - 128; }
        __syncthreads();
        #pragma unroll
        for (int i = 0; i < 8; i++) {
            int idx = t + i * 256;
            int r = idx >> 4, kq = idx & 15;
            float4 a = *(const float4*)&src[(size_t)(row0 + r) * astride + kk + kq * 4];
            unsigned short h0 = f2bf(a.x), h1 = f2bf(a.y), h2 = f2bf(a.z), h3 = f2bf(a.w);
            unsigned short l0 = f2bf(a.x - bf2f(h0)), l1 = f2bf(a.y - bf2f(h1));
            unsigned short l2 = f2bf(a.z - bf2f(h2)), l3 = f2bf(a.w - bf2f(h3));
            int off = r * 128 + ((kq * 8) ^ ((r & 7) << 4));
            *(uint2*)(sAh + off) = make_uint2((unsigned)h0 | ((unsigned)h1 << 16),
                                              (unsigned)h2 | ((unsigned)h3 << 16));
            *(uint2*)(sAl + off) = make_uint2((unsigned)l0 | ((unsigned)l1 << 16),
                                              (unsigned)l2 | ((unsigned)l3 << 16));
        }
        {
            int n = t & 127, kc = t >> 7;
            #pragma unroll
            for (int r = 0; r < 4; r++) {
                int krel = r * 16 + kc * 8;
                unsigned short hh[8], ll[8];
                #pragma unroll
                for (int j = 0; j < 8; j++) {
                    float wv_ = W[(size_t)(k0 + krel + j) * M + c0 + n];
                    hh[j] = f2bf(wv_);
                    ll[j] = f2bf(wv_ - bf2f(hh[j]));
                }
                int off = n * 128 + ((krel * 2) ^ ((n & 7) << 4));
                uint4 ph, pl;
                ph.x = (unsigned)hh[0] | ((unsigned)hh[1] << 16);
                ph.y = (unsigned)hh[2] | ((unsigned)hh[3] << 16);
                ph.z = (unsigned)hh[4] | ((unsigned)hh[5] << 16);
                ph.w = (unsigned)hh[6] | ((unsigned)hh[7] << 16);
                pl.x = (unsigned)ll[0] | ((unsigned)ll[1] << 16);
                pl.y = (unsigned)ll[2] | ((unsigned)ll[3] << 16);
                pl.z = (unsigned)ll[4] | ((unsigned)ll[5] << 16);
                pl.w = (unsigned)ll[6] | ((unsigned)ll[7] << 16);
                *(uint4*)(sWh + off) = ph;
                *(uint4*)(sWl + off) = pl;
            }
        }
        __syncthreads();
        #pragma unroll
        for (int ks = 0; ks < 2; ks++) {
            int kbyte = ks * 64 + fq * 16;
            bf16x8 bh[2], bl[2];
            #pragma unroll
            for (int nf = 0; nf < 2; nf++) {
                int n = wv * 32 + nf * 16 + fr;
                int off = n * 128 + (kbyte ^ ((n & 7) << 4));
                bh[nf] = *(bf16x8*)(sWh + off);
                bl[nf] = *(bf16x8*)(sWl + off);
            }
            #pragma unroll
            for (int m = 0; m < 8; m++) {
                int r = m * 16 + fr;
                int off = r * 128 + (kbyte ^ ((r & 7) << 4));
                bf16x8 ah = *(bf16x8*)(sAh + off);
                bf16x8 al = *(bf16x8*)(sAl + off);
                #pragma unroll
                for (int nf = 0; nf < 2; nf++) {
                    acc[m][nf] = __builtin_amdgcn_mfma_f32_16x16x32_bf16(ah, bh[nf], acc[m][nf], 0, 0, 0);
                    acc[m][nf] = __builtin_amdgcn_mfma_f32_16x16x32_bf16(ah, bl[nf], acc[m][nf], 0, 0, 0);
                    acc[m][nf] = __builtin_amdgcn_mfma_f32_16x16x32_bf16(al, bh[nf], acc[m][nf], 0, 0, 0);
                }
            }
        }
    }

    #pragma unroll
    for (int m = 0; m < 8; m++) {
        int rbase = row0 + m * 16 + fq * 4;
        #pragma unroll
        for (int nf = 0; nf < 2; nf++) {
            int col = c0 + wv * 32 + nf * 16 + fr;
            float b = bias ? bias[col] : 0.0f;
            #pragma unroll
            for (int j = 0; j < 4; j++) {
                int row = rbase + j;
                float ar = addrow ? addrow[(size_t)(row / 50) * M + col] : 0.0f;
                float v = acc[m][nf][j] + b + ar;
                if (act == 1) v = fmaxf(v, 0.f);
                else if (act == 2) v = v > 0.f ? v : 0.01f * v;
                out[(size_t)row * M + col] = v;
            }
        }
    }
}

// ---------------- final K=128 -> 1 dot + bias, f32 store ----------------
__global__ __launch_bounds__(256) void head3_k(const float* __restrict__ T2,
                                               const float* __restrict__ w,
                                               const float* __restrict__ b,
                                               float* __restrict__ out) {
    int row = blockIdx.x * 4 + (threadIdx.x >> 6);
    int lane = threadIdx.x & 63;
    const float2* t2 = (const float2*)&T2[(size_t)row * 128];
    const float2* w2 = (const float2*)w;
    float2 tv = t2[lane], wv = w2[lane];
    float acc = tv.x * wv.x + tv.y * wv.y;
    #pragma unroll
    for (int off = 32; off; off >>= 1) acc += __shfl_xor(acc, off);
    if (lane == 0) out[row] = acc + b[0];
}

extern "C" void kernel_launch(void* const* d_in, const int* in_sizes, int n_in,
                              void* d_out, int out_size, void* d_ws, size_t ws_size,
                              hipStream_t stream) {
    const float* p_x = (const float*)d_in[0];
    const float* v_x = (const float*)d_in[1];
    const int* p_ei = (const int*)d_in[2];
    const int* v_ei = (const int*)d_in[3];
    const float* pW0 = (const float*)d_in[6];  const float* pb0 = (const float*)d_in[7];
    const float* pW1 = (const float*)d_in[8];  const float* pb1 = (const float*)d_in[9];
    const float* pW2 = (const float*)d_in[10]; const float* pb2 = (const float*)d_in[11];
    const float* vW0 = (const float*)d_in[12]; const float* vb0 = (const float*)d_in[13];
    const float* vW1 = (const float*)d_in[14]; const float* vb1 = (const float*)d_in[15];
    const float* vW2 = (const float*)d_in[16]; const float* vb2 = (const float*)d_in[17];
    const float* hW1 = (const float*)d_in[18]; const float* hb1 = (const float*)d_in[19];
    const float* hW2 = (const float*)d_in[20]; const float* hb2 = (const float*)d_in[21];
    const float* hW3 = (const float*)d_in[22]; const float* hb3 = (const float*)d_in[23];

    char* w = (char*)d_ws;
    size_t off = 0;
    auto alloc = [&](size_t bytes) { char* p = w + off; off += (bytes + 255) & ~size_t(255); return p; };
    float* bufA   = (float*)alloc((size_t)NV_TOT * 256 * 4);   // T1 [12800,256]
    float* bufB   = (float*)alloc((size_t)NV_TOT * 128 * 4);   // T2 [12800,128]
    float* g0v    = (float*)alloc((size_t)NV_TOT * 128 * 4);
    float* g1v    = (float*)alloc((size_t)NV_TOT * 128 * 4);
    float* vH0    = (float*)alloc((size_t)NV_TOT * 128 * 4);
    float* vH2    = (float*)alloc((size_t)NV_TOT * 128 * 4);
    float* p_g    = (float*)alloc((size_t)NB * 128 * 4);
    float* v_g    = (float*)alloc((size_t)NB * 128 * 4);       // atomic pool (zeroed)
    float* p_gz   = (float*)alloc((size_t)NB * 128 * 4);       // atomic pool (zeroed)
    float* Gmix   = (float*)alloc((size_t)NB * 256 * 4);
    float* W01    = (float*)alloc((size_t)16 * 128 * 4);
    float* b01    = (float*)alloc((size_t)128 * 4);
    int*   adj_p  = (int*)alloc((size_t)NP_TOT * MAXDEG * 4);
    int*   cnt_p  = (int*)alloc((size_t)NP_TOT * 4);           // contiguous with cnt_v
    int*   cnt_v  = (int*)alloc((size_t)NV_TOT * 4);
    float* dinv_p = (float*)alloc((size_t)NP_TOT * 4);
    float* c_p    = (float*)alloc((size_t)NP_TOT * 4);         // atomic (zeroed)
    int*   adj_v  = (int*)alloc((size_t)NV_TOT * MAXDEG * 4);
    float* dinv_v = (float*)alloc((size_t)NV_TOT * 4);
    float* T1 = bufA;
    float* T2 = bufB;

    hipMemsetAsync(cnt_p, 0, (size_t)(NP_TOT + NV_TOT) * 4, stream);
    hipMemsetAsync(c_p, 0, (size_t)NP_TOT * 4, stream);
    hipMemsetAsync(v_g, 0, (size_t)NB * 128 * 4, stream);
    hipMemsetAsync(p_gz, 0, (size_t)NB * 128 * 4, stream);

    adj_k<<<(EP_EDGES + 255) / 256, 256, 0, stream>>>(p_ei, cnt_p, adj_p, EP_EDGES);
    adj_k<<<(EV_EDGES + 255) / 256, 256, 0, stream>>>(v_ei, cnt_v, adj_v, EV_EDGES);
    dinv_k<<<(NP_TOT + 255) / 256, 256, 0, stream>>>(cnt_p, dinv_p, NP_TOT);
    dinv_k<<<(NV_TOT + 255) / 256, 256, 0, stream>>>(cnt_v, dinv_v, NV_TOT);
    c_k<<<(EP_EDGES + 255) / 256, 256, 0, stream>>>(p_ei, dinv_p, c_p, EP_EDGES);
    w01_k<<<1, 128, 0, stream>>>(pW0, pb0, pW1, W01, b01);

    // ---- v encoder (unchanged structure) ----
    gemm16_k<<<NV_TOT / 16, 256, 0, stream>>>(v_x, vW0, vb0, dinv_v, g0v, vH0, NV_TOT);
    gcn_fused<<<NV_TOT / 128, 512, 0, stream>>>(g0v, adj_v, cnt_v, dinv_v, vW1, vb1,
                                                g1v, nullptr, 50, 1 | 2 | 4);
    gcn_fused<<<NV_TOT / 128, 512, 0, stream>>>(g1v, adj_v, cnt_v, dinv_v, vW2, vb2,
                                                vH2, v_g, 50, 4 | 8);

    // ---- p encoder: one fused kernel + tiny GEMM ----
    pfused<<<NP_TOT / 128, 512, 0, stream>>>(p_x, adj_p, cnt_p, dinv_p, c_p,
                                             W01, b01, pb1, p_gz, 500);
    // p_g = p_gz @ pW2 + pb2   (p_gz already mean-weighted)
    gemm_mfma<<<dim3(2, 1), 256, 0, stream>>>(p_gz, nullptr, pW2, pb2, nullptr,
                                              p_g, NB, 128, 128, 0, 128);

    // ---- head ----
    gemm_mfma<<<dim3(2, 2), 256, 0, stream>>>(v_g, p_g, hW1 + (size_t)256 * 256, hb1,
                                              nullptr, Gmix, NB, 256, 256, 0, 128);
    gemm_mfma<<<dim3(NV_TOT / 128, 2), 256, 0, stream>>>(vH2, vH0, hW1, nullptr,
                                                         Gmix, T1, NV_TOT, 256, 256, 2, 128);
    gemm_mfma<<<dim3(NV_TOT / 128, 1), 256, 0, stream>>>(T1, nullptr, hW2, hb2,
                                                         nullptr, T2, NV_TOT, 256, 128, 2, 256);
    head3_k<<<NV_TOT / 4, 256, 0, stream>>>(T2, hW3, hb3, (float*)d_out);
}

// Round 7
// 253.298 us; speedup vs baseline: 3.4353x; 1.3235x over previous
//
#include <hip/hip_runtime.h>
#include <hip/hip_bf16.h>

#define NP_TOT 128000
#define NV_TOT 12800
#define EP_EDGES 768000
#define EV_EDGES 51200
#define NB 256
#define MAXDEG 40

typedef short bf16x8 __attribute__((ext_vector_type(8)));
typedef float f32x4 __attribute__((ext_vector_type(4)));

static __device__ __forceinline__ unsigned short f2bf(float f) {
    unsigned u = __builtin_bit_cast(unsigned, f);
    unsigned r = u + 0x7FFFu + ((u >> 16) & 1u);   // RNE
    return (unsigned short)(r >> 16);
}
static __device__ __forceinline__ float bf2f(unsigned short h) {
    return __builtin_bit_cast(float, (unsigned)h << 16);
}

// ---------------- adjacency build ----------------
__global__ void adj_k(const int* __restrict__ ei, int* __restrict__ cnt,
                      int* __restrict__ adj, int NE) {
    int e = blockIdx.x * 256 + threadIdx.x;
    if (e >= NE) return;
    int dst = ei[NE + e];
    int slot = atomicAdd(&cnt[dst], 1);
    if (slot < MAXDEG) adj[dst * MAXDEG + slot] = ei[e];
}

__global__ void dinv_k(const int* __restrict__ cnt, float* __restrict__ dinv, int N) {
    int i = blockIdx.x * 256 + threadIdx.x;
    if (i < N) dinv[i] = rsqrtf(1.0f + (float)cnt[i]);
}

// c[src] += dinv[dst] over edges  (for pool-first layer-2 trick)
__global__ void c_k(const int* __restrict__ ei, const float* __restrict__ dinv,
                    float* __restrict__ c, int NE) {
    int e = blockIdx.x * 256 + threadIdx.x;
    if (e >= NE) return;
    atomicAdd(&c[ei[e]], dinv[ei[NE + e]]);
}

// W01 = W0[16,128] @ W1[128,128], b01 = b0 @ W1
__global__ __launch_bounds__(128) void w01_k(const float* __restrict__ W0,
                                             const float* __restrict__ b0,
                                             const float* __restrict__ W1,
                                             float* __restrict__ W01,
                                             float* __restrict__ b01) {
    int col = threadIdx.x;
    float acc[17];
    #pragma unroll
    for (int r = 0; r < 17; r++) acc[r] = 0.f;
    for (int i = 0; i < 128; i++) {
        float w1 = W1[i * 128 + col];
        #pragma unroll
        for (int r = 0; r < 16; r++) acc[r] += W0[r * 128 + i] * w1;
        acc[16] += b0[i] * w1;
    }
    #pragma unroll
    for (int r = 0; r < 16; r++) W01[r * 128 + col] = acc[r];
    b01[col] = acc[16];
}

// ---------------- convert W[K,M] -> split-bf16 MFMA B-fragment layout ----------------
// dst index: ((col*(K/32) + ks)*4 + fq)*8 + j   where k = ks*32 + fq*8 + j
__global__ void w_frag(const float* __restrict__ W, short* __restrict__ Fh,
                       short* __restrict__ Fl, int K, int M) {
    int e = blockIdx.x * 256 + threadIdx.x;
    if (e >= K * M) return;
    int col = e % M, kk = e / M;
    int ks = kk >> 5, rem = kk & 31, fq = rem >> 3, j = rem & 7;
    float v = W[(size_t)kk * M + col];
    unsigned short h = f2bf(v);
    size_t dst = (((size_t)col * (K >> 5) + ks) * 4 + fq) * 8 + j;
    Fh[dst] = (short)h;
    Fl[dst] = (short)f2bf(v - bf2f(h));
}

// ---------------- K=16 -> M=128 input GEMM: h0 = x@W0 + b0 (v only) ----------------
__global__ __launch_bounds__(256) void gemm16_k(const float* __restrict__ X,
                                                const float* __restrict__ W,
                                                const float* __restrict__ bias,
                                                const float* __restrict__ rs,
                                                float* __restrict__ outS,
                                                float* __restrict__ outP, int N) {
    __shared__ float sX[16][17];
    __shared__ float sW[16][128];
    int row0 = blockIdx.x * 16;
    int t = threadIdx.x;
    { int r = t >> 4, q = t & 15; sX[r][q] = X[(size_t)(row0 + r) * 16 + q]; }
    #pragma unroll
    for (int l = 0; l < 8; l++) {
        int lin = t + l * 256;
        sW[lin >> 7][lin & 127] = W[lin];
    }
    __syncthreads();
    int c = t & 127, rg = t >> 7;
    float acc[8];
    float b = bias[c];
    #pragma unroll
    for (int i = 0; i < 8; i++) acc[i] = b;
    #pragma unroll
    for (int k = 0; k < 16; k++) {
        float w = sW[k][c];
        #pragma unroll
        for (int i = 0; i < 8; i++) acc[i] += sX[rg * 8 + i][k] * w;
    }
    #pragma unroll
    for (int i = 0; i < 8; i++) {
        int row = row0 + rg * 8 + i;
        if (outP) outP[(size_t)row * 128 + c] = acc[i];
        outS[(size_t)row * 128 + c] = acc[i] * rs[row];
    }
}

// ---------------- fused GCN layer (v encoder) ----------------
// mode bits: 1=relu, 2=scale out by dinv, 4=write out, 8=pool mean into pool[batch]
__global__ __launch_bounds__(512) void gcn_fused(const float* __restrict__ g,
                                                 const int* __restrict__ adj,
                                                 const int* __restrict__ cnt,
                                                 const float* __restrict__ dinv,
                                                 const float* __restrict__ W,
                                                 const float* __restrict__ bias,
                                                 float* __restrict__ out,
                                                 float* __restrict__ pool,
                                                 int npg, int mode) {
    __shared__ char lds[65536];
    char* zh = lds;
    char* zl = lds + 32768;

    const int t = threadIdx.x;
    const int lane = t & 63;
    const int wvi = t >> 6;
    const int fr = lane & 15;
    const int fq = lane >> 4;

    int nb = gridDim.x;
    int bid = blockIdx.x;
    int swz = (nb & 7) ? bid : ((bid & 7) * (nb >> 3) + (bid >> 3));
    int row0 = swz * 128;

    // W fragments -> registers (batched loads, then convert)
    const int colW = wvi * 16 + fr;
    float wtmp[32];
    #pragma unroll
    for (int kk = 0; kk < 32; kk++)
        wtmp[kk] = W[(size_t)((kk >> 3) * 32 + fq * 8 + (kk & 7)) * 128 + colW];
    bf16x8 wh[4], wl[4];
    #pragma unroll
    for (int ks = 0; ks < 4; ks++) {
        short hh[8], ll[8];
        #pragma unroll
        for (int j = 0; j < 8; j++) {
            float x = wtmp[ks * 8 + j];
            unsigned short h = f2bf(x);
            hh[j] = (short)h;
            ll[j] = (short)f2bf(x - bf2f(h));
        }
        wh[ks] = (bf16x8){hh[0],hh[1],hh[2],hh[3],hh[4],hh[5],hh[6],hh[7]};
        wl[ks] = (bf16x8){ll[0],ll[1],ll[2],ll[3],ll[4],ll[5],ll[6],ll[7]};
    }

    const float2* g2 = (const float2*)g;
    for (int gi = 0; gi < 16; gi++) {
        int r = gi * 8 + wvi;
        int node = row0 + r;
        int d = cnt[node];
        if (d > MAXDEG) d = MAXDEG;
        const int* ap = adj + (size_t)node * MAXDEG;
        int4 i0 = *(const int4*)ap;
        int4 i1 = *(const int4*)(ap + 4);
        int4 i2 = *(const int4*)(ap + 8);
        float2 acc = g2[(size_t)node * 64 + lane];
        int idx[12] = {i0.x,i0.y,i0.z,i0.w,i1.x,i1.y,i1.z,i1.w,i2.x,i2.y,i2.z,i2.w};
        #pragma unroll
        for (int e = 0; e < 12; e++) {
            bool valid = e < d;
            int s = valid ? idx[e] : node;
            float2 v = g2[(size_t)s * 64 + lane];
            float m = valid ? 1.0f : 0.0f;
            acc.x += m * v.x; acc.y += m * v.y;
        }
        for (int e = 12; e < d; e++) {
            int s = ap[e];
            float2 v = g2[(size_t)s * 64 + lane];
            acc.x += v.x; acc.y += v.y;
        }
        float di = dinv[node];
        float zx = di * acc.x, zy = di * acc.y;
        unsigned short hx = f2bf(zx), hy = f2bf(zy);
        unsigned short lx = f2bf(zx - bf2f(hx)), ly = f2bf(zy - bf2f(hy));
        int off = r * 256 + ((lane * 4) ^ ((r & 7) << 4));
        *(unsigned*)(zh + off) = (unsigned)hx | ((unsigned)hy << 16);
        *(unsigned*)(zl + off) = (unsigned)lx | ((unsigned)ly << 16);
    }
    __syncthreads();

    f32x4 acc[8];
    #pragma unroll
    for (int m = 0; m < 8; m++) acc[m] = (f32x4){0.f, 0.f, 0.f, 0.f};
    #pragma unroll
    for (int ks = 0; ks < 4; ks++) {
        int kbyte = ks * 64 + fq * 16;
        #pragma unroll
        for (int m = 0; m < 8; m++) {
            int r = m * 16 + fr;
            int off = r * 256 + (kbyte ^ ((r & 7) << 4));
            bf16x8 ah = *(bf16x8*)(zh + off);
            bf16x8 al = *(bf16x8*)(zl + off);
            acc[m] = __builtin_amdgcn_mfma_f32_16x16x32_bf16(ah, wh[ks], acc[m], 0, 0, 0);
            acc[m] = __builtin_amdgcn_mfma_f32_16x16x32_bf16(ah, wl[ks], acc[m], 0, 0, 0);
            acc[m] = __builtin_amdgcn_mfma_f32_16x16x32_bf16(al, wh[ks], acc[m], 0, 0, 0);
        }
    }

    const int col = wvi * 16 + fr;
    const float bcol = bias[col];
    const float invn = 1.0f / npg;
    #pragma unroll
    for (int m = 0; m < 8; m++) {
        int R = row0 + m * 16;
        float vj[4];
        #pragma unroll
        for (int j = 0; j < 4; j++) {
            int row = R + fq * 4 + j;
            float v = acc[m][j] + bcol;
            if (mode & 1) v = fmaxf(v, 0.f);
            vj[j] = v;
            if (mode & 4) {
                float wv_ = (mode & 2) ? v * dinv[row] : v;
                out[(size_t)row * 128 + col] = wv_;
            }
        }
        if (mode & 8) {
            int b0 = R / npg;
            int bound = (b0 + 1) * npg;
            float s0 = 0.f, s1 = 0.f;
            #pragma unroll
            for (int j = 0; j < 4; j++) {
                int row = R + fq * 4 + j;
                if (row < bound) s0 += vj[j]; else s1 += vj[j];
            }
            s0 += __shfl_xor(s0, 16); s0 += __shfl_xor(s0, 32);
            s1 += __shfl_xor(s1, 16); s1 += __shfl_xor(s1, 32);
            if (fq == 0) {
                atomicAdd(&pool[b0 * 128 + col], s0 * invn);
                if (R + 16 > bound) atomicAdd(&pool[(b0 + 1) * 128 + col], s1 * invn);
            }
        }
    }
}

// ---------------- fully-fused p encoder ----------------
__global__ __launch_bounds__(512) void pfused(const float* __restrict__ x,
                                              const int* __restrict__ adj,
                                              const int* __restrict__ cnt,
                                              const float* __restrict__ dinv,
                                              const float* __restrict__ cw,
                                              const float* __restrict__ W01,
                                              const float* __restrict__ b01,
                                              const float* __restrict__ b1,
                                              float* __restrict__ pool, int npg) {
    __shared__ char lds[80 * 128 + 1024];
    float* sbeta = (float*)(lds + 80 * 128);
    float* spw   = sbeta + 128;

    const int t = threadIdx.x;
    int nb = gridDim.x;
    int bid = blockIdx.x;
    int swz = (nb & 7) ? bid : ((bid & 7) * (nb >> 3) + (bid >> 3));
    int row0 = swz * 128;

    {
        int ns = t >> 2, q = t & 3;
        int node = row0 + ns;
        float di = dinv[node];
        int d = cnt[node];
        if (d > MAXDEG) d = MAXDEG;
        const int* ap = adj + (size_t)node * MAXDEG;
        int4 i0 = *(const int4*)ap;
        int4 i1 = *(const int4*)(ap + 4);
        int4 i2 = *(const int4*)(ap + 8);
        const float4* x4 = (const float4*)x;
        float4 xo = x4[(size_t)node * 4 + q];
        float ax = di * xo.x, ay = di * xo.y, az = di * xo.z, aw = di * xo.w;
        float tsum = 0.f;
        int idx[12] = {i0.x,i0.y,i0.z,i0.w,i1.x,i1.y,i1.z,i1.w,i2.x,i2.y,i2.z,i2.w};
        #pragma unroll
        for (int e = 0; e < 12; e++) {
            bool valid = e < d;
            int s = valid ? idx[e] : node;
            float dj = valid ? dinv[s] : 0.f;
            float4 v = x4[(size_t)s * 4 + q];
            ax += dj * v.x; ay += dj * v.y; az += dj * v.z; aw += dj * v.w;
            tsum += dj;
        }
        for (int e = 12; e < d; e++) {
            int s = ap[e];
            float dj = dinv[s];
            float4 v = x4[(size_t)s * 4 + q];
            ax += dj * v.x; ay += dj * v.y; az += dj * v.z; aw += dj * v.w;
            tsum += dj;
        }
        ax *= di; ay *= di; az *= di; aw *= di;
        unsigned short h0 = f2bf(ax), h1 = f2bf(ay), h2 = f2bf(az), h3 = f2bf(aw);
        unsigned short l0 = f2bf(ax - bf2f(h0)), l1 = f2bf(ay - bf2f(h1));
        unsigned short l2 = f2bf(az - bf2f(h2)), l3 = f2bf(aw - bf2f(h3));
        char* base = lds + ns * 80;
        *(unsigned*)(base + q * 8)     = (unsigned)h0 | ((unsigned)h1 << 16);
        *(unsigned*)(base + q * 8 + 4) = (unsigned)h2 | ((unsigned)h3 << 16);
        *(unsigned*)(base + 32 + q * 8)     = (unsigned)l0 | ((unsigned)l1 << 16);
        *(unsigned*)(base + 32 + q * 8 + 4) = (unsigned)l2 | ((unsigned)l3 << 16);
        if (q == 0) {
            sbeta[ns] = di * (di + tsum);
            spw[ns]   = di * (di + cw[node]) * (1.0f / npg);
        }
    }
    __syncthreads();

    const int lane = t & 63;
    const int wvi = t >> 6;
    const int fr = lane & 15;
    const int fq = lane >> 4;
    const int col = wvi * 16 + fr;

    bf16x8 B1, B2;
    {
        float wt[8];
        #pragma unroll
        for (int j = 0; j < 8; j++)
            wt[j] = W01[(size_t)((fq * 8 + j) & 15) * 128 + col];
        short b1a[8], b2a[8];
        #pragma unroll
        for (int j = 0; j < 8; j++) {
            int kk = fq * 8 + j;
            unsigned short h = f2bf(wt[j]);
            b1a[j] = (short)h;
            b2a[j] = (kk < 16) ? (short)f2bf(wt[j] - bf2f(h)) : (short)0;
        }
        B1 = (bf16x8){b1a[0],b1a[1],b1a[2],b1a[3],b1a[4],b1a[5],b1a[6],b1a[7]};
        B2 = (bf16x8){b2a[0],b2a[1],b2a[2],b2a[3],b2a[4],b2a[5],b2a[6],b2a[7]};
    }

    f32x4 acc[8];
    #pragma unroll
    for (int m = 0; m < 8; m++) acc[m] = (f32x4){0.f, 0.f, 0.f, 0.f};
    #pragma unroll
    for (int m = 0; m < 8; m++) {
        int r = m * 16 + fr;
        bf16x8 a = *(bf16x8*)(lds + r * 80 + fq * 16);
        acc[m] = __builtin_amdgcn_mfma_f32_16x16x32_bf16(a, B1, acc[m], 0, 0, 0);
        acc[m] = __builtin_amdgcn_mfma_f32_16x16x32_bf16(a, B2, acc[m], 0, 0, 0);
    }

    float b01c = b01[col];
    float b1c = b1[col];
    int b0 = row0 / npg;
    int bound = (b0 + 1) * npg;
    float sA = 0.f, sB = 0.f;
    #pragma unroll
    for (int m = 0; m < 8; m++) {
        #pragma unroll
        for (int j = 0; j < 4; j++) {
            int rl = m * 16 + fq * 4 + j;
            float v = acc[m][j] + sbeta[rl] * b01c + b1c;
            v = fmaxf(v, 0.f);
            float pv = spw[rl] * v;
            if (row0 + rl < bound) sA += pv; else sB += pv;
        }
    }
    sA += __shfl_xor(sA, 16); sA += __shfl_xor(sA, 32);
    sB += __shfl_xor(sB, 16); sB += __shfl_xor(sB, 32);
    if (fq == 0) {
        atomicAdd(&pool[b0 * 128 + col], sA);
        if (row0 + 127 >= bound) atomicAdd(&pool[(b0 + 1) * 128 + col], sB);
    }
}

// ---------------- small fp32 GEMM for [256,*] matrices ----------------
// out[r,c] = sum_k Acat[r,k] * W[k,c] + bias[c];  Acat = A (k<128) | A2 (k>=128)
// grid (N/16, M/128), 256 threads. A/A2 row stride = 128.
__global__ __launch_bounds__(256) void small_gemm(const float* __restrict__ A,
                                                  const float* __restrict__ A2,
                                                  const float* __restrict__ W,
                                                  const float* __restrict__ bias,
                                                  float* __restrict__ out,
                                                  int K, int M) {
    __shared__ float sA[16 * 256];
    int t = threadIdx.x;
    int r0 = blockIdx.x * 16;
    int c0 = blockIdx.y * 128;
    for (int i = t * 4; i < 16 * K; i += 1024) {
        int r = i / K, k = i % K;
        const float* src = (A2 && k >= 128) ? &A2[(size_t)(r0 + r) * 128 + k - 128]
                                            : &A[(size_t)(r0 + r) * 128 + k];
        *(float4*)&sA[r * K + k] = *(const float4*)src;
    }
    __syncthreads();
    int col = c0 + (t & 127);
    int rg = (t >> 7) * 8;
    float acc[8] = {0.f,0.f,0.f,0.f,0.f,0.f,0.f,0.f};
    for (int k = 0; k < K; k += 4) {
        float w0 = W[(size_t)k * M + col];
        float w1 = W[(size_t)(k + 1) * M + col];
        float w2 = W[(size_t)(k + 2) * M + col];
        float w3 = W[(size_t)(k + 3) * M + col];
        #pragma unroll
        for (int r = 0; r < 8; r++) {
            float4 a = *(float4*)&sA[(rg + r) * K + k];
            acc[r] += a.x * w0 + a.y * w1 + a.z * w2 + a.w * w3;
        }
    }
    float b = bias[col];
    #pragma unroll
    for (int r = 0; r < 8; r++)
        out[(size_t)(r0 + rg + r) * M + col] = acc[r] + b;
}

// ---------------- fused head: T1 -> T2 -> logits, one kernel per 64 rows ----------------
__global__ __launch_bounds__(256) void headk(const float* __restrict__ vH2,
                                             const float* __restrict__ vH0,
                                             const float* __restrict__ Gmix,
                                             const short* __restrict__ W1fh,
                                             const short* __restrict__ W1fl,
                                             const short* __restrict__ W2fh,
                                             const short* __restrict__ W2fl,
                                             const float* __restrict__ hb2,
                                             const float* __restrict__ w3,
                                             const float* __restrict__ b3,
                                             float* __restrict__ out) {
    __shared__ char lds[65536];
    const int t = threadIdx.x;
    const int lane = t & 63;
    const int wv = t >> 6;
    const int fr = lane & 15;
    const int fq = lane >> 4;
    const int r0 = blockIdx.x * 64;
    const int b0 = r0 / 50;

    // Gmix (bias-included) rows for up to 3 batches -> registers
    float gm[3][4];
    #pragma unroll
    for (int s = 0; s < 3; s++) {
        int b = b0 + s; if (b > NB - 1) b = NB - 1;
        #pragma unroll
        for (int nf = 0; nf < 4; nf++)
            gm[s][nf] = Gmix[(size_t)b * 256 + wv * 64 + nf * 16 + fr];
    }

    // ---- step1: T1[64,256] = leaky([vH2|vH0]@W1a + Gmix) ----
    f32x4 acc[4][4];
    #pragma unroll
    for (int m = 0; m < 4; m++)
        #pragma unroll
        for (int nf = 0; nf < 4; nf++) acc[m][nf] = (f32x4){0.f,0.f,0.f,0.f};

    for (int k0 = 0; k0 < 256; k0 += 64) {
        const float* src = (k0 < 128) ? vH2 : vH0;
        int kk = (k0 < 128) ? k0 : k0 - 128;
        __syncthreads();
        float4 tmp[4];
        #pragma unroll
        for (int i = 0; i < 4; i++) {
            int idx = t + i * 256;
            int r = idx >> 4, kq = idx & 15;
            tmp[i] = *(const float4*)&src[(size_t)(r0 + r) * 128 + kk + kq * 4];
        }
        #pragma unroll
        for (int i = 0; i < 4; i++) {
            int idx = t + i * 256;
            int r = idx >> 4, kq = idx & 15;
            float4 a = tmp[i];
            unsigned short h0 = f2bf(a.x), h1 = f2bf(a.y), h2 = f2bf(a.z), h3 = f2bf(a.w);
            unsigned short l0 = f2bf(a.x - bf2f(h0)), l1 = f2bf(a.y - bf2f(h1));
            unsigned short l2 = f2bf(a.z - bf2f(h2)), l3 = f2bf(a.w - bf2f(h3));
            int off = r * 128 + ((kq * 8) ^ ((r & 7) << 4));
            *(uint2*)(lds + off) = make_uint2((unsigned)h0 | ((unsigned)h1 << 16),
                                              (unsigned)h2 | ((unsigned)h3 << 16));
            *(uint2*)(lds + 8192 + off) = make_uint2((unsigned)l0 | ((unsigned)l1 << 16),
                                                     (unsigned)l2 | ((unsigned)l3 << 16));
        }
        __syncthreads();
        #pragma unroll
        for (int ksl = 0; ksl < 2; ksl++) {
            int ks = (k0 >> 5) + ksl;
            bf16x8 bh[4], bl[4];
            #pragma unroll
            for (int nf = 0; nf < 4; nf++) {
                int col = wv * 64 + nf * 16 + fr;
                size_t base = (((size_t)col * 8 + ks) * 4 + fq) * 8;
                bh[nf] = *(const bf16x8*)&W1fh[base];
                bl[nf] = *(const bf16x8*)&W1fl[base];
            }
            int kbyte = ksl * 64 + fq * 16;
            #pragma unroll
            for (int m = 0; m < 4; m++) {
                int r = m * 16 + fr;
                int off = r * 128 + (kbyte ^ ((r & 7) << 4));
                bf16x8 ah = *(bf16x8*)(lds + off);
                bf16x8 al = *(bf16x8*)(lds + 8192 + off);
                #pragma unroll
                for (int nf = 0; nf < 4; nf++) {
                    acc[m][nf] = __builtin_amdgcn_mfma_f32_16x16x32_bf16(ah, bh[nf], acc[m][nf], 0, 0, 0);
                    acc[m][nf] = __builtin_amdgcn_mfma_f32_16x16x32_bf16(ah, bl[nf], acc[m][nf], 0, 0, 0);
                    acc[m][nf] = __builtin_amdgcn_mfma_f32_16x16x32_bf16(al, bh[nf], acc[m][nf], 0, 0, 0);
                }
            }
        }
    }
    __syncthreads();

    // ---- epilogue1: leaky + Gmix, write T1 split planes (hi@0, lo@32K, pitch 512B) ----
    #pragma unroll
    for (int m = 0; m < 4; m++) {
        #pragma unroll
        for (int j = 0; j < 4; j++) {
            int row = m * 16 + fq * 4 + j;
            int s = (r0 + row) / 50 - b0;
            #pragma unroll
            for (int nf = 0; nf < 4; nf++) {
                float v = acc[m][nf][j] + gm[s][nf];
                v = v > 0.f ? v : 0.01f * v;
                unsigned short h = f2bf(v);
                unsigned short l = f2bf(v - bf2f(h));
                int col = wv * 64 + nf * 16 + fr;
                int byt = (col * 2) ^ ((row & 7) << 4);
                *(short*)(lds + row * 512 + byt) = (short)h;
                *(short*)(lds + 32768 + row * 512 + byt) = (short)l;
            }
        }
    }
    __syncthreads();

    // ---- step2: T2[64,128] = leaky(T1@W2 + hb2) ----
    f32x4 acc2[4][2];
    #pragma unroll
    for (int m = 0; m < 4; m++)
        #pragma unroll
        for (int nf = 0; nf < 2; nf++) acc2[m][nf] = (f32x4){0.f,0.f,0.f,0.f};
    #pragma unroll
    for (int ks = 0; ks < 8; ks++) {
        bf16x8 bh[2], bl[2];
        #pragma unroll
        for (int nf = 0; nf < 2; nf++) {
            int col = wv * 32 + nf * 16 + fr;
            size_t base = (((size_t)col * 8 + ks) * 4 + fq) * 8;
            bh[nf] = *(const bf16x8*)&W2fh[base];
            bl[nf] = *(const bf16x8*)&W2fl[base];
        }
        int kbyte = ks * 64 + fq * 16;
        #pragma unroll
        for (int m = 0; m < 4; m++) {
            int row = m * 16 + fr;
            int off = row * 512 + (kbyte ^ ((row & 7) << 4));
            bf16x8 ah = *(bf16x8*)(lds + off);
            bf16x8 al = *(bf16x8*)(lds + 32768 + off);
            #pragma unroll
            for (int nf = 0; nf < 2; nf++) {
                acc2[m][nf] = __builtin_amdgcn_mfma_f32_16x16x32_bf16(ah, bh[nf], acc2[m][nf], 0, 0, 0);
                acc2[m][nf] = __builtin_amdgcn_mfma_f32_16x16x32_bf16(ah, bl[nf], acc2[m][nf], 0, 0, 0);
                acc2[m][nf] = __builtin_amdgcn_mfma_f32_16x16x32_bf16(al, bh[nf], acc2[m][nf], 0, 0, 0);
            }
        }
    }

    // ---- step3: logits = T2 @ w3 + b3 ----
    float hb2c[2], w3f[2];
    #pragma unroll
    for (int nf = 0; nf < 2; nf++) {
        int col = wv * 32 + nf * 16 + fr;
        hb2c[nf] = hb2[col];
        w3f[nf] = w3[col];
    }
    float p[4][4];
    #pragma unroll
    for (int m = 0; m < 4; m++)
        #pragma unroll
        for (int j = 0; j < 4; j++) {
            float s = 0.f;
            #pragma unroll
            for (int nf = 0; nf < 2; nf++) {
                float v = acc2[m][nf][j] + hb2c[nf];
                v = v > 0.f ? v : 0.01f * v;
                s += v * w3f[nf];
            }
            p[m][j] = s;
        }
    #pragma unroll
    for (int m = 0; m < 4; m++)
        #pragma unroll
        for (int j = 0; j < 4; j++) {
            p[m][j] += __shfl_xor(p[m][j], 1);
            p[m][j] += __shfl_xor(p[m][j], 2);
            p[m][j] += __shfl_xor(p[m][j], 4);
            p[m][j] += __shfl_xor(p[m][j], 8);
        }
    __syncthreads();           // T1 planes dead; reuse LDS for wave sums
    float* wsum = (float*)lds; // [4][64]
    if (fr == 0) {
        #pragma unroll
        for (int m = 0; m < 4; m++)
            #pragma unroll
            for (int j = 0; j < 4; j++)
                wsum[wv * 64 + m * 16 + fq * 4 + j] = p[m][j];
    }
    __syncthreads();
    if (t < 64) {
        float s = wsum[t] + wsum[64 + t] + wsum[128 + t] + wsum[192 + t];
        out[r0 + t] = s + b3[0];
    }
}

extern "C" void kernel_launch(void* const* d_in, const int* in_sizes, int n_in,
                              void* d_out, int out_size, void* d_ws, size_t ws_size,
                              hipStream_t stream) {
    const float* p_x = (const float*)d_in[0];
    const float* v_x = (const float*)d_in[1];
    const int* p_ei = (const int*)d_in[2];
    const int* v_ei = (const int*)d_in[3];
    const float* pW0 = (const float*)d_in[6];  const float* pb0 = (const float*)d_in[7];
    const float* pW1 = (const float*)d_in[8];  const float* pb1 = (const float*)d_in[9];
    const float* pW2 = (const float*)d_in[10]; const float* pb2 = (const float*)d_in[11];
    const float* vW0 = (const float*)d_in[12]; const float* vb0 = (const float*)d_in[13];
    const float* vW1 = (const float*)d_in[14]; const float* vb1 = (const float*)d_in[15];
    const float* vW2 = (const float*)d_in[16]; const float* vb2 = (const float*)d_in[17];
    const float* hW1 = (const float*)d_in[18]; const float* hb1 = (const float*)d_in[19];
    const float* hW2 = (const float*)d_in[20]; const float* hb2 = (const float*)d_in[21];
    const float* hW3 = (const float*)d_in[22]; const float* hb3 = (const float*)d_in[23];

    char* w = (char*)d_ws;
    size_t off = 0;
    auto alloc = [&](size_t bytes) { char* p = w + off; off += (bytes + 255) & ~size_t(255); return p; };
    float* g0v    = (float*)alloc((size_t)NV_TOT * 128 * 4);
    float* g1v    = (float*)alloc((size_t)NV_TOT * 128 * 4);
    float* vH0    = (float*)alloc((size_t)NV_TOT * 128 * 4);
    float* vH2    = (float*)alloc((size_t)NV_TOT * 128 * 4);
    float* p_g    = (float*)alloc((size_t)NB * 128 * 4);
    float* v_g    = (float*)alloc((size_t)NB * 128 * 4);       // atomic pool (zeroed)
    float* p_gz   = (float*)alloc((size_t)NB * 128 * 4);       // atomic pool (zeroed)
    float* Gmix   = (float*)alloc((size_t)NB * 256 * 4);
    float* W01    = (float*)alloc((size_t)16 * 128 * 4);
    float* b01    = (float*)alloc((size_t)128 * 4);
    short* W1fh   = (short*)alloc((size_t)256 * 256 * 2);
    short* W1fl   = (short*)alloc((size_t)256 * 256 * 2);
    short* W2fh   = (short*)alloc((size_t)256 * 128 * 2);
    short* W2fl   = (short*)alloc((size_t)256 * 128 * 2);
    int*   adj_p  = (int*)alloc((size_t)NP_TOT * MAXDEG * 4);
    int*   cnt_p  = (int*)alloc((size_t)NP_TOT * 4);           // contiguous with cnt_v
    int*   cnt_v  = (int*)alloc((size_t)NV_TOT * 4);
    float* dinv_p = (float*)alloc((size_t)NP_TOT * 4);
    float* c_p    = (float*)alloc((size_t)NP_TOT * 4);         // atomic (zeroed)
    int*   adj_v  = (int*)alloc((size_t)NV_TOT * MAXDEG * 4);
    float* dinv_v = (float*)alloc((size_t)NV_TOT * 4);

    hipMemsetAsync(cnt_p, 0, (size_t)(NP_TOT + NV_TOT) * 4, stream);
    hipMemsetAsync(c_p, 0, (size_t)NP_TOT * 4, stream);
    hipMemsetAsync(v_g, 0, (size_t)NB * 128 * 4, stream);
    hipMemsetAsync(p_gz, 0, (size_t)NB * 128 * 4, stream);

    adj_k<<<(EP_EDGES + 255) / 256, 256, 0, stream>>>(p_ei, cnt_p, adj_p, EP_EDGES);
    adj_k<<<(EV_EDGES + 255) / 256, 256, 0, stream>>>(v_ei, cnt_v, adj_v, EV_EDGES);
    dinv_k<<<(NP_TOT + 255) / 256, 256, 0, stream>>>(cnt_p, dinv_p, NP_TOT);
    dinv_k<<<(NV_TOT + 255) / 256, 256, 0, stream>>>(cnt_v, dinv_v, NV_TOT);
    c_k<<<(EP_EDGES + 255) / 256, 256, 0, stream>>>(p_ei, dinv_p, c_p, EP_EDGES);
    w01_k<<<1, 128, 0, stream>>>(pW0, pb0, pW1, W01, b01);
    w_frag<<<(256 * 256 + 255) / 256, 256, 0, stream>>>(hW1, W1fh, W1fl, 256, 256);
    w_frag<<<(256 * 128 + 255) / 256, 256, 0, stream>>>(hW2, W2fh, W2fl, 256, 128);

    // ---- v encoder ----
    gemm16_k<<<NV_TOT / 16, 256, 0, stream>>>(v_x, vW0, vb0, dinv_v, g0v, vH0, NV_TOT);
    gcn_fused<<<NV_TOT / 128, 512, 0, stream>>>(g0v, adj_v, cnt_v, dinv_v, vW1, vb1,
                                                g1v, nullptr, 50, 1 | 2 | 4);
    gcn_fused<<<NV_TOT / 128, 512, 0, stream>>>(g1v, adj_v, cnt_v, dinv_v, vW2, vb2,
                                                vH2, v_g, 50, 4 | 8);

    // ---- p encoder ----
    pfused<<<NP_TOT / 128, 512, 0, stream>>>(p_x, adj_p, cnt_p, dinv_p, c_p,
                                             W01, b01, pb1, p_gz, 500);
    small_gemm<<<dim3(16, 1), 256, 0, stream>>>(p_gz, nullptr, pW2, pb2, p_g, 128, 128);

    // ---- head ----
    small_gemm<<<dim3(16, 2), 256, 0, stream>>>(v_g, p_g, hW1 + (size_t)256 * 256, hb1,
                                                Gmix, 256, 256);
    headk<<<NV_TOT / 64, 256, 0, stream>>>(vH2, vH0, Gmix, W1fh, W1fl, W2fh, W2fl,
                                           hb2, hW3, hb3, (float*)d_out);
}

// Round 8
// 170.514 us; speedup vs baseline: 5.1030x; 1.4855x over previous
//
#include <hip/hip_runtime.h>
#include <hip/hip_bf16.h>

#define NP_TOT 128000
#define NV_TOT 12800
#define EP_EDGES 768000
#define EV_EDGES 51200
#define NB 256
#define MAXDEG 40

typedef short bf16x8 __attribute__((ext_vector_type(8)));
typedef float f32x4 __attribute__((ext_vector_type(4)));

static __device__ __forceinline__ unsigned short f2bf(float f) {
    unsigned u = __builtin_bit_cast(unsigned, f);
    unsigned r = u + 0x7FFFu + ((u >> 16) & 1u);   // RNE
    return (unsigned short)(r >> 16);
}
static __device__ __forceinline__ float bf2f(unsigned short h) {
    return __builtin_bit_cast(float, (unsigned)h << 16);
}

// ---------------- adjacency build ----------------
__global__ void adj_k(const int* __restrict__ ei, int* __restrict__ cnt,
                      int* __restrict__ adj, int NE) {
    int e = blockIdx.x * 256 + threadIdx.x;
    if (e >= NE) return;
    int dst = ei[NE + e];
    int slot = atomicAdd(&cnt[dst], 1);
    if (slot < MAXDEG) adj[dst * MAXDEG + slot] = ei[e];
}

__global__ void dinv_k(const int* __restrict__ cnt, float* __restrict__ dinv, int N) {
    int i = blockIdx.x * 256 + threadIdx.x;
    if (i < N) dinv[i] = rsqrtf(1.0f + (float)cnt[i]);
}

// c[src] += dinv[dst] over edges  (pool-first layer-2 trick, p encoder)
__global__ void c_k(const int* __restrict__ ei, const float* __restrict__ dinv,
                    float* __restrict__ c, int NE) {
    int e = blockIdx.x * 256 + threadIdx.x;
    if (e >= NE) return;
    atomicAdd(&c[ei[e]], dinv[ei[NE + e]]);
}

// W01 = W0[16,128] @ W1[128,128], b01 = b0 @ W1
__global__ __launch_bounds__(128) void w01_k(const float* __restrict__ W0,
                                             const float* __restrict__ b0,
                                             const float* __restrict__ W1,
                                             float* __restrict__ W01,
                                             float* __restrict__ b01) {
    int col = threadIdx.x;
    float acc[17];
    #pragma unroll
    for (int r = 0; r < 17; r++) acc[r] = 0.f;
    for (int i = 0; i < 128; i++) {
        float w1 = W1[i * 128 + col];
        #pragma unroll
        for (int r = 0; r < 16; r++) acc[r] += W0[r * 128 + i] * w1;
        acc[16] += b0[i] * w1;
    }
    #pragma unroll
    for (int r = 0; r < 16; r++) W01[r * 128 + col] = acc[r];
    b01[col] = acc[16];
}

// ---------------- convert W[K,M] -> split-bf16 MFMA B-fragment layout ----------------
// dst index: ((col*(K/32) + ks)*4 + fq)*8 + j   where k = ks*32 + fq*8 + j
__global__ void w_frag(const float* __restrict__ W, short* __restrict__ Fh,
                       short* __restrict__ Fl, int K, int M) {
    int e = blockIdx.x * 256 + threadIdx.x;
    if (e >= K * M) return;
    int col = e % M, kk = e / M;
    int ks = kk >> 5, rem = kk & 31, fq = rem >> 3, j = rem & 7;
    float v = W[(size_t)kk * M + col];
    unsigned short h = f2bf(v);
    size_t dst = (((size_t)col * (K >> 5) + ks) * 4 + fq) * 8 + j;
    Fh[dst] = (short)h;
    Fl[dst] = (short)f2bf(v - bf2f(h));
}

// ---------------- fully-fused p encoder (verified R6/R7) ----------------
__global__ __launch_bounds__(512) void pfused(const float* __restrict__ x,
                                              const int* __restrict__ adj,
                                              const int* __restrict__ cnt,
                                              const float* __restrict__ dinv,
                                              const float* __restrict__ cw,
                                              const float* __restrict__ W01,
                                              const float* __restrict__ b01,
                                              const float* __restrict__ b1,
                                              float* __restrict__ pool, int npg) {
    __shared__ char lds[80 * 128 + 1024];
    float* sbeta = (float*)(lds + 80 * 128);
    float* spw   = sbeta + 128;

    const int t = threadIdx.x;
    int nb = gridDim.x;
    int bid = blockIdx.x;
    int swz = (nb & 7) ? bid : ((bid & 7) * (nb >> 3) + (bid >> 3));
    int row0 = swz * 128;

    {
        int ns = t >> 2, q = t & 3;
        int node = row0 + ns;
        float di = dinv[node];
        int d = cnt[node];
        if (d > MAXDEG) d = MAXDEG;
        const int* ap = adj + (size_t)node * MAXDEG;
        int4 i0 = *(const int4*)ap;
        int4 i1 = *(const int4*)(ap + 4);
        int4 i2 = *(const int4*)(ap + 8);
        const float4* x4 = (const float4*)x;
        float4 xo = x4[(size_t)node * 4 + q];
        float ax = di * xo.x, ay = di * xo.y, az = di * xo.z, aw = di * xo.w;
        float tsum = 0.f;
        int idx[12] = {i0.x,i0.y,i0.z,i0.w,i1.x,i1.y,i1.z,i1.w,i2.x,i2.y,i2.z,i2.w};
        #pragma unroll
        for (int e = 0; e < 12; e++) {
            bool valid = e < d;
            int s = valid ? idx[e] : node;
            float dj = valid ? dinv[s] : 0.f;
            float4 v = x4[(size_t)s * 4 + q];
            ax += dj * v.x; ay += dj * v.y; az += dj * v.z; aw += dj * v.w;
            tsum += dj;
        }
        for (int e = 12; e < d; e++) {
            int s = ap[e];
            float dj = dinv[s];
            float4 v = x4[(size_t)s * 4 + q];
            ax += dj * v.x; ay += dj * v.y; az += dj * v.z; aw += dj * v.w;
            tsum += dj;
        }
        ax *= di; ay *= di; az *= di; aw *= di;
        unsigned short h0 = f2bf(ax), h1 = f2bf(ay), h2 = f2bf(az), h3 = f2bf(aw);
        unsigned short l0 = f2bf(ax - bf2f(h0)), l1 = f2bf(ay - bf2f(h1));
        unsigned short l2 = f2bf(az - bf2f(h2)), l3 = f2bf(aw - bf2f(h3));
        char* base = lds + ns * 80;
        *(unsigned*)(base + q * 8)     = (unsigned)h0 | ((unsigned)h1 << 16);
        *(unsigned*)(base + q * 8 + 4) = (unsigned)h2 | ((unsigned)h3 << 16);
        *(unsigned*)(base + 32 + q * 8)     = (unsigned)l0 | ((unsigned)l1 << 16);
        *(unsigned*)(base + 32 + q * 8 + 4) = (unsigned)l2 | ((unsigned)l3 << 16);
        if (q == 0) {
            sbeta[ns] = di * (di + tsum);
            spw[ns]   = di * (di + cw[node]) * (1.0f / npg);
        }
    }
    __syncthreads();

    const int lane = t & 63;
    const int wvi = t >> 6;
    const int fr = lane & 15;
    const int fq = lane >> 4;
    const int col = wvi * 16 + fr;

    bf16x8 B1, B2;
    {
        float wt[8];
        #pragma unroll
        for (int j = 0; j < 8; j++)
            wt[j] = W01[(size_t)((fq * 8 + j) & 15) * 128 + col];
        short b1a[8], b2a[8];
        #pragma unroll
        for (int j = 0; j < 8; j++) {
            int kk = fq * 8 + j;
            unsigned short h = f2bf(wt[j]);
            b1a[j] = (short)h;
            b2a[j] = (kk < 16) ? (short)f2bf(wt[j] - bf2f(h)) : (short)0;
        }
        B1 = (bf16x8){b1a[0],b1a[1],b1a[2],b1a[3],b1a[4],b1a[5],b1a[6],b1a[7]};
        B2 = (bf16x8){b2a[0],b2a[1],b2a[2],b2a[3],b2a[4],b2a[5],b2a[6],b2a[7]};
    }

    f32x4 acc[8];
    #pragma unroll
    for (int m = 0; m < 8; m++) acc[m] = (f32x4){0.f, 0.f, 0.f, 0.f};
    #pragma unroll
    for (int m = 0; m < 8; m++) {
        int r = m * 16 + fr;
        bf16x8 a = *(bf16x8*)(lds + r * 80 + fq * 16);
        acc[m] = __builtin_amdgcn_mfma_f32_16x16x32_bf16(a, B1, acc[m], 0, 0, 0);
        acc[m] = __builtin_amdgcn_mfma_f32_16x16x32_bf16(a, B2, acc[m], 0, 0, 0);
    }

    float b01c = b01[col];
    float b1c = b1[col];
    int b0 = row0 / npg;
    int bound = (b0 + 1) * npg;
    float sA = 0.f, sB = 0.f;
    #pragma unroll
    for (int m = 0; m < 8; m++) {
        #pragma unroll
        for (int j = 0; j < 4; j++) {
            int rl = m * 16 + fq * 4 + j;
            float v = acc[m][j] + sbeta[rl] * b01c + b1c;
            v = fmaxf(v, 0.f);
            float pv = spw[rl] * v;
            if (row0 + rl < bound) sA += pv; else sB += pv;
        }
    }
    sA += __shfl_xor(sA, 16); sA += __shfl_xor(sA, 32);
    sB += __shfl_xor(sB, 16); sB += __shfl_xor(sB, 32);
    if (fq == 0) {
        atomicAdd(&pool[b0 * 128 + col], sA);
        if (row0 + 127 >= bound) atomicAdd(&pool[(b0 + 1) * 128 + col], sB);
    }
}

// ---------------- small fp32 GEMM for [256,*] (p_g) ----------------
__global__ __launch_bounds__(256) void small_gemm(const float* __restrict__ A,
                                                  const float* __restrict__ A2,
                                                  const float* __restrict__ W,
                                                  const float* __restrict__ bias,
                                                  float* __restrict__ out,
                                                  int K, int M) {
    __shared__ float sA[16 * 256];
    int t = threadIdx.x;
    int r0 = blockIdx.x * 16;
    int c0 = blockIdx.y * 128;
    for (int i = t * 4; i < 16 * K; i += 1024) {
        int r = i / K, k = i % K;
        const float* src = (A2 && k >= 128) ? &A2[(size_t)(r0 + r) * 128 + k - 128]
                                            : &A[(size_t)(r0 + r) * 128 + k];
        *(float4*)&sA[r * K + k] = *(const float4*)src;
    }
    __syncthreads();
    int col = c0 + (t & 127);
    int rg = (t >> 7) * 8;
    float acc[8] = {0.f,0.f,0.f,0.f,0.f,0.f,0.f,0.f};
    for (int k = 0; k < K; k += 4) {
        float w0 = W[(size_t)k * M + col];
        float w1 = W[(size_t)(k + 1) * M + col];
        float w2 = W[(size_t)(k + 2) * M + col];
        float w3 = W[(size_t)(k + 3) * M + col];
        #pragma unroll
        for (int r = 0; r < 8; r++) {
            float4 a = *(float4*)&sA[(rg + r) * K + k];
            acc[r] += a.x * w0 + a.y * w1 + a.z * w2 + a.w * w3;
        }
    }
    float b = bias[col];
    #pragma unroll
    for (int r = 0; r < 8; r++)
        out[(size_t)(r0 + rg + r) * M + col] = acc[r] + b;
}

// ---------------- mega-fused v encoder + head: one block per batch ----------------
// LDS map (bytes):
#define LB 0            // fp32 work [64][136] pitch 544 (W0 staged in LC first)
#define LC 34816        // bf16 hi plane [64] pitch 512 (k0-255)
#define LD 67584        // bf16 lo plane
#define LE 100352       // small: sdinv(256) scnt(256) sadj(3072) svg(512) vgh(256) vgl(256) pgh(256) pgl(256) wsum(2048)
#define E_SDINV (LE)
#define E_SCNT  (LE + 256)
#define E_SADJ  (LE + 512)
#define E_SVG   (LE + 3584)
#define E_VGH   (LE + 4096)
#define E_VGL   (LE + 4352)
#define E_PGH   (LE + 4608)
#define E_PGL   (LE + 4864)
#define E_WSUM  (LE + 5120)
__global__ __launch_bounds__(512) void vhead_k(
    const float* __restrict__ v_x,
    const int* __restrict__ adj, const int* __restrict__ cnt,
    const float* __restrict__ dinv,
    const float* __restrict__ W0, const float* __restrict__ b0,
    const short* __restrict__ W1h, const short* __restrict__ W1l,
    const float* __restrict__ b1,
    const short* __restrict__ W2h, const short* __restrict__ W2l,
    const float* __restrict__ b2,
    const float* __restrict__ p_g,
    const short* __restrict__ H1h, const short* __restrict__ H1l,
    const float* __restrict__ hb1,
    const short* __restrict__ H2h, const short* __restrict__ H2l,
    const float* __restrict__ hb2,
    const float* __restrict__ w3, const float* __restrict__ b3,
    float* __restrict__ out) {
    __shared__ char lds[107520];
    const int t = threadIdx.x;
    const int b = blockIdx.x;
    const int lane = t & 63;
    const int wv = t >> 6;
    const int fr = lane & 15;
    const int fq = lane >> 4;
    float* Bf = (float*)(lds + LB);               // pitch 136 floats
    float* sdinv = (float*)(lds + E_SDINV);
    int*   scnt  = (int*)(lds + E_SCNT);
    int*   sadj  = (int*)(lds + E_SADJ);

    // ---- P0: stage W0 -> LC; node meta; p_g row -> frags ----
    *(float4*)(lds + LC + t * 16) = *((const float4*)W0 + t);   // 512 x 16B = 8KB
    if (t < 64) {
        bool ok = t < 50;
        scnt[t]  = ok ? cnt[b * 50 + t] : 0;
        sdinv[t] = ok ? dinv[b * 50 + t] : 0.f;
    }
    if (t < 150) {
        int node = t / 3, chunk = t % 3;
        int4 v = *(const int4*)&adj[((size_t)(b * 50 + node)) * MAXDEG + chunk * 4];
        int* d = &sadj[node * 12 + chunk * 4];
        d[0] = v.x - b * 50; d[1] = v.y - b * 50; d[2] = v.z - b * 50; d[3] = v.w - b * 50;
    }
    if (t < 128) {
        float pv = p_g[(size_t)b * 128 + t];
        unsigned short h = f2bf(pv);
        ((short*)(lds + E_PGH))[t] = (short)h;
        ((short*)(lds + E_PGL))[t] = (short)f2bf(pv - bf2f(h));
    }
    __syncthreads();

    // ---- P1: h0 = x@W0 + b0 -> Bf fp32 ----
    {
        int n = t >> 3, cg = t & 7;
        if (n < 50) {
            const float* sW0 = (const float*)(lds + LC);
            const float4* xr = (const float4*)(v_x + (size_t)(b * 50 + n) * 16);
            float4 x0 = xr[0], x1 = xr[1], x2 = xr[2], x3 = xr[3];
            float xv[16] = {x0.x,x0.y,x0.z,x0.w, x1.x,x1.y,x1.z,x1.w,
                            x2.x,x2.y,x2.z,x2.w, x3.x,x3.y,x3.z,x3.w};
            #pragma unroll
            for (int cc = 0; cc < 16; cc++) {
                int c = cg * 16 + cc;
                float a = b0[c];
                #pragma unroll
                for (int k = 0; k < 16; k++) a += xv[k] * sW0[k * 128 + c];
                Bf[n * 136 + c] = a;
            }
        }
    }
    __syncthreads();

    // ---- P2: (a) h0 -> split bf16 at k128..255 of LC/LD; (b) gather1 -> z1 at k0..127 ----
    {
        int r = t >> 3, f0 = (t & 7) * 16;
        #pragma unroll
        for (int w8 = 0; w8 < 8; w8++) {
            int f = f0 + 2 * w8;
            float v0 = Bf[r * 136 + f], v1 = Bf[r * 136 + f + 1];
            unsigned short h0 = f2bf(v0), h1 = f2bf(v1);
            unsigned short l0 = f2bf(v0 - bf2f(h0)), l1 = f2bf(v1 - bf2f(h1));
            int q = (256 + 2 * f) ^ ((r & 7) << 4);
            *(unsigned*)(lds + LC + r * 512 + q) = (unsigned)h0 | ((unsigned)h1 << 16);
            *(unsigned*)(lds + LD + r * 512 + q) = (unsigned)l0 | ((unsigned)l1 << 16);
        }
        int n = r;
        if (n < 50) {
            float di = sdinv[n];
            int d = scnt[n]; if (d > MAXDEG) d = MAXDEG;
            float acc[16];
            #pragma unroll
            for (int cc = 0; cc < 16; cc++) acc[cc] = di * Bf[n * 136 + f0 + cc];
            #pragma unroll
            for (int e = 0; e < 12; e++) {
                bool valid = e < d;
                int jl = valid ? sadj[n * 12 + e] : n;
                float dj = valid ? sdinv[jl] : 0.f;
                #pragma unroll
                for (int cc = 0; cc < 16; cc++) acc[cc] += dj * Bf[jl * 136 + f0 + cc];
            }
            for (int e = 12; e < d; e++) {
                int jl = adj[((size_t)(b * 50 + n)) * MAXDEG + e] - b * 50;
                float dj = sdinv[jl];
                #pragma unroll
                for (int cc = 0; cc < 16; cc++) acc[cc] += dj * Bf[jl * 136 + f0 + cc];
            }
            #pragma unroll
            for (int w8 = 0; w8 < 8; w8++) {
                float z0 = di * acc[2 * w8], z1 = di * acc[2 * w8 + 1];
                unsigned short h0 = f2bf(z0), h1 = f2bf(z1);
                unsigned short l0 = f2bf(z0 - bf2f(h0)), l1 = f2bf(z1 - bf2f(h1));
                int q = (2 * (f0 + 2 * w8)) ^ ((n & 7) << 4);
                *(unsigned*)(lds + LC + n * 512 + q) = (unsigned)h0 | ((unsigned)h1 << 16);
                *(unsigned*)(lds + LD + n * 512 + q) = (unsigned)l0 | ((unsigned)l1 << 16);
            }
        }
    }
    __syncthreads();

    // ---- P3: L1 MFMA: h1 = relu(z1@W1 + b1) -> Bf ----
    {
        const int col = wv * 16 + fr;
        bf16x8 bh[4], bl[4];
        #pragma unroll
        for (int ks = 0; ks < 4; ks++) {
            int base = ((col * 4 + ks) * 4 + fq) * 8;
            bh[ks] = *(const bf16x8*)&W1h[base];
            bl[ks] = *(const bf16x8*)&W1l[base];
        }
        f32x4 acc[4];
        #pragma unroll
        for (int m = 0; m < 4; m++) acc[m] = (f32x4){0.f,0.f,0.f,0.f};
        #pragma unroll
        for (int ks = 0; ks < 4; ks++) {
            int kb = ks * 64 + fq * 16;
            #pragma unroll
            for (int m = 0; m < 4; m++) {
                int r = m * 16 + fr;
                int off = r * 512 + (kb ^ ((r & 7) << 4));
                bf16x8 ah = *(bf16x8*)(lds + LC + off);
                bf16x8 al = *(bf16x8*)(lds + LD + off);
                acc[m] = __builtin_amdgcn_mfma_f32_16x16x32_bf16(ah, bh[ks], acc[m], 0, 0, 0);
                acc[m] = __builtin_amdgcn_mfma_f32_16x16x32_bf16(ah, bl[ks], acc[m], 0, 0, 0);
                acc[m] = __builtin_amdgcn_mfma_f32_16x16x32_bf16(al, bh[ks], acc[m], 0, 0, 0);
            }
        }
        float b1c = b1[col];
        #pragma unroll
        for (int m = 0; m < 4; m++)
            #pragma unroll
            for (int j = 0; j < 4; j++) {
                int row = m * 16 + fq * 4 + j;
                Bf[row * 136 + col] = fmaxf(acc[m][j] + b1c, 0.f);
            }
    }
    __syncthreads();

    // ---- P4: gather2 on h1 -> z2 at k0..127 ----
    {
        int n = t >> 3, f0 = (t & 7) * 16;
        if (n < 50) {
            float di = sdinv[n];
            int d = scnt[n]; if (d > MAXDEG) d = MAXDEG;
            float acc[16];
            #pragma unroll
            for (int cc = 0; cc < 16; cc++) acc[cc] = di * Bf[n * 136 + f0 + cc];
            #pragma unroll
            for (int e = 0; e < 12; e++) {
                bool valid = e < d;
                int jl = valid ? sadj[n * 12 + e] : n;
                float dj = valid ? sdinv[jl] : 0.f;
                #pragma unroll
                for (int cc = 0; cc < 16; cc++) acc[cc] += dj * Bf[jl * 136 + f0 + cc];
            }
            for (int e = 12; e < d; e++) {
                int jl = adj[((size_t)(b * 50 + n)) * MAXDEG + e] - b * 50;
                float dj = sdinv[jl];
                #pragma unroll
                for (int cc = 0; cc < 16; cc++) acc[cc] += dj * Bf[jl * 136 + f0 + cc];
            }
            #pragma unroll
            for (int w8 = 0; w8 < 8; w8++) {
                float z0 = di * acc[2 * w8], z1 = di * acc[2 * w8 + 1];
                unsigned short h0 = f2bf(z0), h1 = f2bf(z1);
                unsigned short l0 = f2bf(z0 - bf2f(h0)), l1 = f2bf(z1 - bf2f(h1));
                int q = (2 * (f0 + 2 * w8)) ^ ((n & 7) << 4);
                *(unsigned*)(lds + LC + n * 512 + q) = (unsigned)h0 | ((unsigned)h1 << 16);
                *(unsigned*)(lds + LD + n * 512 + q) = (unsigned)l0 | ((unsigned)l1 << 16);
            }
        }
    }
    __syncthreads();

    // ---- P5: L2 MFMA: h2 = z2@W2 + b2 (keep in regs) ----
    float h2v[4][4];
    {
        const int col = wv * 16 + fr;
        bf16x8 bh[4], bl[4];
        #pragma unroll
        for (int ks = 0; ks < 4; ks++) {
            int base = ((col * 4 + ks) * 4 + fq) * 8;
            bh[ks] = *(const bf16x8*)&W2h[base];
            bl[ks] = *(const bf16x8*)&W2l[base];
        }
        f32x4 acc[4];
        #pragma unroll
        for (int m = 0; m < 4; m++) acc[m] = (f32x4){0.f,0.f,0.f,0.f};
        #pragma unroll
        for (int ks = 0; ks < 4; ks++) {
            int kb = ks * 64 + fq * 16;
            #pragma unroll
            for (int m = 0; m < 4; m++) {
                int r = m * 16 + fr;
                int off = r * 512 + (kb ^ ((r & 7) << 4));
                bf16x8 ah = *(bf16x8*)(lds + LC + off);
                bf16x8 al = *(bf16x8*)(lds + LD + off);
                acc[m] = __builtin_amdgcn_mfma_f32_16x16x32_bf16(ah, bh[ks], acc[m], 0, 0, 0);
                acc[m] = __builtin_amdgcn_mfma_f32_16x16x32_bf16(ah, bl[ks], acc[m], 0, 0, 0);
                acc[m] = __builtin_amdgcn_mfma_f32_16x16x32_bf16(al, bh[ks], acc[m], 0, 0, 0);
            }
        }
        float b2c = b2[col];
        #pragma unroll
        for (int m = 0; m < 4; m++)
            #pragma unroll
            for (int j = 0; j < 4; j++) h2v[m][j] = acc[m][j] + b2c;
    }
    __syncthreads();   // all z2 reads done before overwriting k0..127

    // ---- P6: h2 -> split k0..127; pool -> svg ----
    {
        const int col = wv * 16 + fr;
        float s = 0.f;
        #pragma unroll
        for (int m = 0; m < 4; m++)
            #pragma unroll
            for (int j = 0; j < 4; j++) {
                int row = m * 16 + fq * 4 + j;
                float v = h2v[m][j];
                unsigned short h = f2bf(v);
                unsigned short l = f2bf(v - bf2f(h));
                int q = (2 * col) ^ ((row & 7) << 4);
                *(short*)(lds + LC + row * 512 + q) = (short)h;
                *(short*)(lds + LD + row * 512 + q) = (short)l;
                if (row < 50) s += v;
            }
        s += __shfl_xor(s, 16); s += __shfl_xor(s, 32);
        if (fq == 0) ((float*)(lds + E_SVG))[col] = s * (1.0f / 50.0f);
    }
    __syncthreads();

    // ---- P7: vg -> frags ----
    if (t < 128) {
        float v = ((float*)(lds + E_SVG))[t];
        unsigned short h = f2bf(v);
        ((short*)(lds + E_VGH))[t] = (short)h;
        ((short*)(lds + E_VGL))[t] = (short)f2bf(v - bf2f(h));
    }
    __syncthreads();

    // ---- P8: T1 = leaky([h2|h0|vg|pg]@hW1 + hb1) ----
    f32x4 accT[4][2];
    #pragma unroll
    for (int m = 0; m < 4; m++)
        #pragma unroll
        for (int nf = 0; nf < 2; nf++) accT[m][nf] = (f32x4){0.f,0.f,0.f,0.f};
    {
        #pragma unroll
        for (int ks = 0; ks < 16; ks++) {
            bf16x8 bh[2], bl[2];
            #pragma unroll
            for (int nf = 0; nf < 2; nf++) {
                int col2 = wv * 32 + nf * 16 + fr;
                int base = ((col2 * 16 + ks) * 4 + fq) * 8;
                bh[nf] = *(const bf16x8*)&H1h[base];
                bl[nf] = *(const bf16x8*)&H1l[base];
            }
            if (ks < 8) {
                int kb = ks * 64 + fq * 16;
                #pragma unroll
                for (int m = 0; m < 4; m++) {
                    int r = m * 16 + fr;
                    int off = r * 512 + (kb ^ ((r & 7) << 4));
                    bf16x8 ah = *(bf16x8*)(lds + LC + off);
                    bf16x8 al = *(bf16x8*)(lds + LD + off);
                    #pragma unroll
                    for (int nf = 0; nf < 2; nf++) {
                        accT[m][nf] = __builtin_amdgcn_mfma_f32_16x16x32_bf16(ah, bh[nf], accT[m][nf], 0, 0, 0);
                        accT[m][nf] = __builtin_amdgcn_mfma_f32_16x16x32_bf16(ah, bl[nf], accT[m][nf], 0, 0, 0);
                        accT[m][nf] = __builtin_amdgcn_mfma_f32_16x16x32_bf16(al, bh[nf], accT[m][nf], 0, 0, 0);
                    }
                }
            } else {
                int boff = (ks < 12) ? (E_VGH + (ks - 8) * 64 + fq * 16)
                                     : (E_PGH + (ks - 12) * 64 + fq * 16);
                int loff = boff + 256;   // VGL/PGL follow hi by 256 bytes
                bf16x8 ah = *(bf16x8*)(lds + boff);
                bf16x8 al = *(bf16x8*)(lds + loff);
                #pragma unroll
                for (int m = 0; m < 4; m++)
                    #pragma unroll
                    for (int nf = 0; nf < 2; nf++) {
                        accT[m][nf] = __builtin_amdgcn_mfma_f32_16x16x32_bf16(ah, bh[nf], accT[m][nf], 0, 0, 0);
                        accT[m][nf] = __builtin_amdgcn_mfma_f32_16x16x32_bf16(ah, bl[nf], accT[m][nf], 0, 0, 0);
                        accT[m][nf] = __builtin_amdgcn_mfma_f32_16x16x32_bf16(al, bh[nf], accT[m][nf], 0, 0, 0);
                    }
            }
        }
    }
    __syncthreads();   // all T1 A-reads done before overwriting LC/LD
    {
        #pragma unroll
        for (int nf = 0; nf < 2; nf++) {
            int col2 = wv * 32 + nf * 16 + fr;
            float hc = hb1[col2];
            #pragma unroll
            for (int m = 0; m < 4; m++)
                #pragma unroll
                for (int j = 0; j < 4; j++) {
                    int row = m * 16 + fq * 4 + j;
                    float v = accT[m][nf][j] + hc;
                    v = v > 0.f ? v : 0.01f * v;
                    unsigned short h = f2bf(v);
                    unsigned short l = f2bf(v - bf2f(h));
                    int q = (2 * col2) ^ ((row & 7) << 4);
                    *(short*)(lds + LC + row * 512 + q) = (short)h;
                    *(short*)(lds + LD + row * 512 + q) = (short)l;
                }
        }
    }
    __syncthreads();

    // ---- P9: T2 = leaky(T1@hW2 + hb2); logits partial ----
    {
        const int col3 = wv * 16 + fr;
        f32x4 acc[4];
        #pragma unroll
        for (int m = 0; m < 4; m++) acc[m] = (f32x4){0.f,0.f,0.f,0.f};
        #pragma unroll
        for (int ks = 0; ks < 8; ks++) {
            int base = ((col3 * 8 + ks) * 4 + fq) * 8;
            bf16x8 bh = *(const bf16x8*)&H2h[base];
            bf16x8 bl = *(const bf16x8*)&H2l[base];
            int kb = ks * 64 + fq * 16;
            #pragma unroll
            for (int m = 0; m < 4; m++) {
                int r = m * 16 + fr;
                int off = r * 512 + (kb ^ ((r & 7) << 4));
                bf16x8 ah = *(bf16x8*)(lds + LC + off);
                bf16x8 al = *(bf16x8*)(lds + LD + off);
                acc[m] = __builtin_amdgcn_mfma_f32_16x16x32_bf16(ah, bh, acc[m], 0, 0, 0);
                acc[m] = __builtin_amdgcn_mfma_f32_16x16x32_bf16(ah, bl, acc[m], 0, 0, 0);
                acc[m] = __builtin_amdgcn_mfma_f32_16x16x32_bf16(al, bh, acc[m], 0, 0, 0);
            }
        }
        float hc = hb2[col3], wc = w3[col3];
        float p[4][4];
        #pragma unroll
        for (int m = 0; m < 4; m++)
            #pragma unroll
            for (int j = 0; j < 4; j++) {
                float v = acc[m][j] + hc;
                v = v > 0.f ? v : 0.01f * v;
                p[m][j] = v * wc;
            }
        #pragma unroll
        for (int m = 0; m < 4; m++)
            #pragma unroll
            for (int j = 0; j < 4; j++) {
                p[m][j] += __shfl_xor(p[m][j], 1);
                p[m][j] += __shfl_xor(p[m][j], 2);
                p[m][j] += __shfl_xor(p[m][j], 4);
                p[m][j] += __shfl_xor(p[m][j], 8);
            }
        if (fr == 0) {
            float* wsum = (float*)(lds + E_WSUM);
            #pragma unroll
            for (int m = 0; m < 4; m++)
                #pragma unroll
                for (int j = 0; j < 4; j++)
                    wsum[wv * 64 + m * 16 + fq * 4 + j] = p[m][j];
        }
    }
    __syncthreads();
    if (t < 50) {
        float* wsum = (float*)(lds + E_WSUM);
        float s = 0.f;
        #pragma unroll
        for (int w8 = 0; w8 < 8; w8++) s += wsum[w8 * 64 + t];
        out[b * 50 + t] = s + b3[0];
    }
}

extern "C" void kernel_launch(void* const* d_in, const int* in_sizes, int n_in,
                              void* d_out, int out_size, void* d_ws, size_t ws_size,
                              hipStream_t stream) {
    const float* p_x = (const float*)d_in[0];
    const float* v_x = (const float*)d_in[1];
    const int* p_ei = (const int*)d_in[2];
    const int* v_ei = (const int*)d_in[3];
    const float* pW0 = (const float*)d_in[6];  const float* pb0 = (const float*)d_in[7];
    const float* pW1 = (const float*)d_in[8];  const float* pb1 = (const float*)d_in[9];
    const float* pW2 = (const float*)d_in[10]; const float* pb2 = (const float*)d_in[11];
    const float* vW0 = (const float*)d_in[12]; const float* vb0 = (const float*)d_in[13];
    const float* vW1 = (const float*)d_in[14]; const float* vb1 = (const float*)d_in[15];
    const float* vW2 = (const float*)d_in[16]; const float* vb2 = (const float*)d_in[17];
    const float* hW1 = (const float*)d_in[18]; const float* hb1 = (const float*)d_in[19];
    const float* hW2 = (const float*)d_in[20]; const float* hb2 = (const float*)d_in[21];
    const float* hW3 = (const float*)d_in[22]; const float* hb3 = (const float*)d_in[23];

    char* w = (char*)d_ws;
    size_t off = 0;
    auto alloc = [&](size_t bytes) { char* p = w + off; off += (bytes + 255) & ~size_t(255); return p; };
    float* p_g    = (float*)alloc((size_t)NB * 128 * 4);
    float* p_gz   = (float*)alloc((size_t)NB * 128 * 4);       // atomic pool (zeroed)
    float* W01    = (float*)alloc((size_t)16 * 128 * 4);
    float* b01    = (float*)alloc((size_t)128 * 4);
    short* W1vh   = (short*)alloc((size_t)128 * 128 * 2);
    short* W1vl   = (short*)alloc((size_t)128 * 128 * 2);
    short* W2vh   = (short*)alloc((size_t)128 * 128 * 2);
    short* W2vl   = (short*)alloc((size_t)128 * 128 * 2);
    short* H1h    = (short*)alloc((size_t)512 * 256 * 2);
    short* H1l    = (short*)alloc((size_t)512 * 256 * 2);
    short* H2h    = (short*)alloc((size_t)256 * 128 * 2);
    short* H2l    = (short*)alloc((size_t)256 * 128 * 2);
    int*   adj_p  = (int*)alloc((size_t)NP_TOT * MAXDEG * 4);
    int*   cnt_p  = (int*)alloc((size_t)NP_TOT * 4);           // contiguous with cnt_v
    int*   cnt_v  = (int*)alloc((size_t)NV_TOT * 4);
    float* dinv_p = (float*)alloc((size_t)NP_TOT * 4);
    float* c_p    = (float*)alloc((size_t)NP_TOT * 4);         // atomic (zeroed)
    int*   adj_v  = (int*)alloc((size_t)NV_TOT * MAXDEG * 4);
    float* dinv_v = (float*)alloc((size_t)NV_TOT * 4);

    hipMemsetAsync(cnt_p, 0, (size_t)(NP_TOT + NV_TOT) * 4, stream);
    hipMemsetAsync(c_p, 0, (size_t)NP_TOT * 4, stream);
    hipMemsetAsync(p_gz, 0, (size_t)NB * 128 * 4, stream);

    adj_k<<<(EP_EDGES + 255) / 256, 256, 0, stream>>>(p_ei, cnt_p, adj_p, EP_EDGES);
    adj_k<<<(EV_EDGES + 255) / 256, 256, 0, stream>>>(v_ei, cnt_v, adj_v, EV_EDGES);
    dinv_k<<<(NP_TOT + 255) / 256, 256, 0, stream>>>(cnt_p, dinv_p, NP_TOT);
    dinv_k<<<(NV_TOT + 255) / 256, 256, 0, stream>>>(cnt_v, dinv_v, NV_TOT);
    c_k<<<(EP_EDGES + 255) / 256, 256, 0, stream>>>(p_ei, dinv_p, c_p, EP_EDGES);
    w01_k<<<1, 128, 0, stream>>>(pW0, pb0, pW1, W01, b01);
    w_frag<<<(128 * 128 + 255) / 256, 256, 0, stream>>>(vW1, W1vh, W1vl, 128, 128);
    w_frag<<<(128 * 128 + 255) / 256, 256, 0, stream>>>(vW2, W2vh, W2vl, 128, 128);
    w_frag<<<(512 * 256 + 255) / 256, 256, 0, stream>>>(hW1, H1h, H1l, 512, 256);
    w_frag<<<(256 * 128 + 255) / 256, 256, 0, stream>>>(hW2, H2h, H2l, 256, 128);

    // ---- p encoder ----
    pfused<<<NP_TOT / 128, 512, 0, stream>>>(p_x, adj_p, cnt_p, dinv_p, c_p,
                                             W01, b01, pb1, p_gz, 500);
    small_gemm<<<dim3(16, 1), 256, 0, stream>>>(p_gz, nullptr, pW2, pb2, p_g, 128, 128);

    // ---- v encoder + head, one block per batch ----
    vhead_k<<<NB, 512, 0, stream>>>(v_x, adj_v, cnt_v, dinv_v,
                                    vW0, vb0, W1vh, W1vl, vb1, W2vh, W2vl, vb2,
                                    p_g, H1h, H1l, hb1, H2h, H2l, hb2,
                                    hW3, hb3, (float*)d_out);
}

// Round 9
// 136.488 us; speedup vs baseline: 6.3752x; 1.2493x over previous
//
#include <hip/hip_runtime.h>
#include <hip/hip_bf16.h>

#define NP_TOT 128000
#define NV_TOT 12800
#define EP_EDGES 768000
#define EV_EDGES 51200
#define NB 256
#define MAXDEG 40

typedef short bf16x8 __attribute__((ext_vector_type(8)));
typedef float f32x4 __attribute__((ext_vector_type(4)));

static __device__ __forceinline__ unsigned short f2bf(float f) {
    unsigned u = __builtin_bit_cast(unsigned, f);
    unsigned r = u + 0x7FFFu + ((u >> 16) & 1u);   // RNE
    return (unsigned short)(r >> 16);
}
static __device__ __forceinline__ float bf2f(unsigned short h) {
    return __builtin_bit_cast(float, (unsigned)h << 16);
}

// ---------------- merged adjacency build (p and v edge sets) ----------------
__global__ void adj2_k(const int* __restrict__ p_ei, const int* __restrict__ v_ei,
                       int* __restrict__ cnt_p, int* __restrict__ adj_p,
                       int* __restrict__ cnt_v, int* __restrict__ adj_v) {
    int i = blockIdx.x * 256 + threadIdx.x;
    if (i < EP_EDGES) {
        int dst = p_ei[EP_EDGES + i];
        int slot = atomicAdd(&cnt_p[dst], 1);
        if (slot < MAXDEG) adj_p[(size_t)dst * MAXDEG + slot] = p_ei[i];
    } else {
        int e = i - EP_EDGES;
        int dst = v_ei[EV_EDGES + e];
        int slot = atomicAdd(&cnt_v[dst], 1);
        if (slot < MAXDEG) adj_v[(size_t)dst * MAXDEG + slot] = v_ei[e];
    }
}

// c[src] += dinv[dst] over p edges (pool-first layer-2 trick); dinv inline
__global__ void c_k(const int* __restrict__ ei, const int* __restrict__ cnt,
                    float* __restrict__ c, int NE) {
    int e = blockIdx.x * 256 + threadIdx.x;
    if (e >= NE) return;
    float dj = rsqrtf(1.0f + (float)cnt[ei[NE + e]]);
    atomicAdd(&c[ei[e]], dj);
}

// ---------------- merged prep: W01/b01 + all weight fragment conversions ----------------
static __device__ __forceinline__ void frag_elem(const float* __restrict__ W,
                                                 short* __restrict__ Fh,
                                                 short* __restrict__ Fl,
                                                 int K, int M, int e) {
    if (e >= K * M) return;
    int col = e % M, kk = e / M;
    int ks = kk >> 5, rem = kk & 31, fq = rem >> 3, j = rem & 7;
    float v = W[(size_t)kk * M + col];
    unsigned short h = f2bf(v);
    size_t dst = (((size_t)col * (K >> 5) + ks) * 4 + fq) * 8 + j;
    Fh[dst] = (short)h;
    Fl[dst] = (short)f2bf(v - bf2f(h));
}

__global__ __launch_bounds__(256) void prep_k(
    const float* __restrict__ pW0, const float* __restrict__ pb0,
    const float* __restrict__ pW1,
    float* __restrict__ W01, float* __restrict__ b01,
    const float* __restrict__ vW1, short* __restrict__ W1vh, short* __restrict__ W1vl,
    const float* __restrict__ vW2, short* __restrict__ W2vh, short* __restrict__ W2vl,
    const float* __restrict__ hW1, short* __restrict__ H1h, short* __restrict__ H1l,
    const float* __restrict__ hW2, short* __restrict__ H2h, short* __restrict__ H2l) {
    int bid = blockIdx.x, t = threadIdx.x;
    if (bid == 0) {
        if (t < 128) {
            int col = t;
            float acc[17];
            #pragma unroll
            for (int r = 0; r < 17; r++) acc[r] = 0.f;
            for (int i = 0; i < 128; i++) {
                float w1 = pW1[i * 128 + col];
                #pragma unroll
                for (int r = 0; r < 16; r++) acc[r] += pW0[r * 128 + i] * w1;
                acc[16] += pb0[i] * w1;
            }
            #pragma unroll
            for (int r = 0; r < 16; r++) W01[r * 128 + col] = acc[r];
            b01[col] = acc[16];
        }
    } else if (bid < 65) {
        frag_elem(vW1, W1vh, W1vl, 128, 128, (bid - 1) * 256 + t);
    } else if (bid < 129) {
        frag_elem(vW2, W2vh, W2vl, 128, 128, (bid - 65) * 256 + t);
    } else if (bid < 641) {
        frag_elem(hW1, H1h, H1l, 512, 256, (bid - 129) * 256 + t);
    } else {
        frag_elem(hW2, H2h, H2l, 256, 128, (bid - 641) * 256 + t);
    }
}

// ---------------- fully-fused p encoder (dinv inline from cnt) ----------------
__global__ __launch_bounds__(512) void pfused(const float* __restrict__ x,
                                              const int* __restrict__ adj,
                                              const int* __restrict__ cnt,
                                              const float* __restrict__ cw,
                                              const float* __restrict__ W01,
                                              const float* __restrict__ b01,
                                              const float* __restrict__ b1,
                                              float* __restrict__ pool, int npg) {
    __shared__ char lds[80 * 128 + 1024];
    float* sbeta = (float*)(lds + 80 * 128);
    float* spw   = sbeta + 128;

    const int t = threadIdx.x;
    int nb = gridDim.x;
    int bid = blockIdx.x;
    int swz = (nb & 7) ? bid : ((bid & 7) * (nb >> 3) + (bid >> 3));
    int row0 = swz * 128;

    {
        int ns = t >> 2, q = t & 3;
        int node = row0 + ns;
        int cn = cnt[node];
        float di = rsqrtf(1.0f + (float)cn);
        int d = cn > MAXDEG ? MAXDEG : cn;
        const int* ap = adj + (size_t)node * MAXDEG;
        int4 i0 = *(const int4*)ap;
        int4 i1 = *(const int4*)(ap + 4);
        int4 i2 = *(const int4*)(ap + 8);
        const float4* x4 = (const float4*)x;
        float4 xo = x4[(size_t)node * 4 + q];
        float ax = di * xo.x, ay = di * xo.y, az = di * xo.z, aw = di * xo.w;
        float tsum = 0.f;
        int idx[12] = {i0.x,i0.y,i0.z,i0.w,i1.x,i1.y,i1.z,i1.w,i2.x,i2.y,i2.z,i2.w};
        #pragma unroll
        for (int e = 0; e < 12; e++) {
            bool valid = e < d;
            int s = valid ? idx[e] : node;
            float dj = valid ? rsqrtf(1.0f + (float)cnt[s]) : 0.f;
            float4 v = x4[(size_t)s * 4 + q];
            ax += dj * v.x; ay += dj * v.y; az += dj * v.z; aw += dj * v.w;
            tsum += dj;
        }
        for (int e = 12; e < d; e++) {
            int s = ap[e];
            float dj = rsqrtf(1.0f + (float)cnt[s]);
            float4 v = x4[(size_t)s * 4 + q];
            ax += dj * v.x; ay += dj * v.y; az += dj * v.z; aw += dj * v.w;
            tsum += dj;
        }
        ax *= di; ay *= di; az *= di; aw *= di;
        unsigned short h0 = f2bf(ax), h1 = f2bf(ay), h2 = f2bf(az), h3 = f2bf(aw);
        unsigned short l0 = f2bf(ax - bf2f(h0)), l1 = f2bf(ay - bf2f(h1));
        unsigned short l2 = f2bf(az - bf2f(h2)), l3 = f2bf(aw - bf2f(h3));
        char* base = lds + ns * 80;
        *(unsigned*)(base + q * 8)     = (unsigned)h0 | ((unsigned)h1 << 16);
        *(unsigned*)(base + q * 8 + 4) = (unsigned)h2 | ((unsigned)h3 << 16);
        *(unsigned*)(base + 32 + q * 8)     = (unsigned)l0 | ((unsigned)l1 << 16);
        *(unsigned*)(base + 32 + q * 8 + 4) = (unsigned)l2 | ((unsigned)l3 << 16);
        if (q == 0) {
            sbeta[ns] = di * (di + tsum);
            spw[ns]   = di * (di + cw[node]) * (1.0f / npg);
        }
    }
    __syncthreads();

    const int lane = t & 63;
    const int wvi = t >> 6;
    const int fr = lane & 15;
    const int fq = lane >> 4;
    const int col = wvi * 16 + fr;

    bf16x8 B1, B2;
    {
        float wt[8];
        #pragma unroll
        for (int j = 0; j < 8; j++)
            wt[j] = W01[(size_t)((fq * 8 + j) & 15) * 128 + col];
        short b1a[8], b2a[8];
        #pragma unroll
        for (int j = 0; j < 8; j++) {
            int kk = fq * 8 + j;
            unsigned short h = f2bf(wt[j]);
            b1a[j] = (short)h;
            b2a[j] = (kk < 16) ? (short)f2bf(wt[j] - bf2f(h)) : (short)0;
        }
        B1 = (bf16x8){b1a[0],b1a[1],b1a[2],b1a[3],b1a[4],b1a[5],b1a[6],b1a[7]};
        B2 = (bf16x8){b2a[0],b2a[1],b2a[2],b2a[3],b2a[4],b2a[5],b2a[6],b2a[7]};
    }

    f32x4 acc[8];
    #pragma unroll
    for (int m = 0; m < 8; m++) acc[m] = (f32x4){0.f, 0.f, 0.f, 0.f};
    #pragma unroll
    for (int m = 0; m < 8; m++) {
        int r = m * 16 + fr;
        bf16x8 a = *(bf16x8*)(lds + r * 80 + fq * 16);
        acc[m] = __builtin_amdgcn_mfma_f32_16x16x32_bf16(a, B1, acc[m], 0, 0, 0);
        acc[m] = __builtin_amdgcn_mfma_f32_16x16x32_bf16(a, B2, acc[m], 0, 0, 0);
    }

    float b01c = b01[col];
    float b1c = b1[col];
    int b0 = row0 / npg;
    int bound = (b0 + 1) * npg;
    float sA = 0.f, sB = 0.f;
    #pragma unroll
    for (int m = 0; m < 8; m++) {
        #pragma unroll
        for (int j = 0; j < 4; j++) {
            int rl = m * 16 + fq * 4 + j;
            float v = acc[m][j] + sbeta[rl] * b01c + b1c;
            v = fmaxf(v, 0.f);
            float pv = spw[rl] * v;
            if (row0 + rl < bound) sA += pv; else sB += pv;
        }
    }
    sA += __shfl_xor(sA, 16); sA += __shfl_xor(sA, 32);
    sB += __shfl_xor(sB, 16); sB += __shfl_xor(sB, 32);
    if (fq == 0) {
        atomicAdd(&pool[b0 * 128 + col], sA);
        if (row0 + 127 >= bound) atomicAdd(&pool[(b0 + 1) * 128 + col], sB);
    }
}

// ---------------- mega-fused v encoder + head: one block per batch ----------------
#define LB 0            // fp32 work [64][136] pitch 544
#define LC 34816        // bf16 hi plane [64] pitch 512 (k0-255)
#define LD 67584        // bf16 lo plane
#define LE 100352       // small scratch
#define E_SDINV (LE)
#define E_SCNT  (LE + 256)
#define E_SADJ  (LE + 512)
#define E_SVG   (LE + 3584)
#define E_VGH   (LE + 4096)
#define E_VGL   (LE + 4352)
#define E_PGH   (LE + 4608)
#define E_PGL   (LE + 4864)
#define E_WSUM  (LE + 5120)
__global__ __launch_bounds__(512) void vhead_k(
    const float* __restrict__ v_x,
    const int* __restrict__ adj, const int* __restrict__ cnt,
    const float* __restrict__ W0, const float* __restrict__ b0,
    const short* __restrict__ W1h, const short* __restrict__ W1l,
    const float* __restrict__ b1,
    const short* __restrict__ W2h, const short* __restrict__ W2l,
    const float* __restrict__ b2,
    const float* __restrict__ p_gz,
    const float* __restrict__ pW2, const float* __restrict__ pb2,
    const short* __restrict__ H1h, const short* __restrict__ H1l,
    const float* __restrict__ hb1,
    const short* __restrict__ H2h, const short* __restrict__ H2l,
    const float* __restrict__ hb2,
    const float* __restrict__ w3, const float* __restrict__ b3,
    float* __restrict__ out) {
    __shared__ char lds[107520];
    const int t = threadIdx.x;
    const int b = blockIdx.x;
    const int lane = t & 63;
    const int wv = t >> 6;
    const int fr = lane & 15;
    const int fq = lane >> 4;
    float* Bf = (float*)(lds + LB);
    float* sdinv = (float*)(lds + E_SDINV);
    int*   scnt  = (int*)(lds + E_SCNT);
    int*   sadj  = (int*)(lds + E_SADJ);

    // ---- P0: stage W0 -> LC; node meta; p_g partials (fused small_gemm) ----
    *(float4*)(lds + LC + t * 16) = *((const float4*)W0 + t);
    if (t < 64) {
        bool ok = t < 50;
        int c = ok ? cnt[b * 50 + t] : 0;
        scnt[t]  = c;
        sdinv[t] = ok ? rsqrtf(1.0f + (float)c) : 0.f;
    }
    if (t < 150) {
        int node = t / 3, chunk = t % 3;
        int4 v = *(const int4*)&adj[((size_t)(b * 50 + node)) * MAXDEG + chunk * 4];
        int* d = &sadj[node * 12 + chunk * 4];
        d[0] = v.x - b * 50; d[1] = v.y - b * 50; d[2] = v.z - b * 50; d[3] = v.w - b * 50;
    }
    {
        int col = t & 127, q = t >> 7;
        const float* gz = p_gz + (size_t)b * 128;
        float s = 0.f;
        #pragma unroll
        for (int k = 0; k < 32; k++)
            s += gz[q * 32 + k] * pW2[(size_t)(q * 32 + k) * 128 + col];
        ((float*)(lds + E_WSUM))[q * 128 + col] = s;
    }
    __syncthreads();

    // ---- P1: finalize p_g frags; h0 = x@W0 + b0 -> Bf fp32 ----
    if (t < 128) {
        float* part = (float*)(lds + E_WSUM);
        float v = part[t] + part[128 + t] + part[256 + t] + part[384 + t] + pb2[t];
        unsigned short h = f2bf(v);
        ((short*)(lds + E_PGH))[t] = (short)h;
        ((short*)(lds + E_PGL))[t] = (short)f2bf(v - bf2f(h));
    }
    {
        int n = t >> 3, cg = t & 7;
        if (n < 50) {
            const float* sW0 = (const float*)(lds + LC);
            const float4* xr = (const float4*)(v_x + (size_t)(b * 50 + n) * 16);
            float4 x0 = xr[0], x1 = xr[1], x2 = xr[2], x3 = xr[3];
            float xv[16] = {x0.x,x0.y,x0.z,x0.w, x1.x,x1.y,x1.z,x1.w,
                            x2.x,x2.y,x2.z,x2.w, x3.x,x3.y,x3.z,x3.w};
            #pragma unroll
            for (int cc = 0; cc < 16; cc++) {
                int c = cg * 16 + cc;
                float a = b0[c];
                #pragma unroll
                for (int k = 0; k < 16; k++) a += xv[k] * sW0[k * 128 + c];
                Bf[n * 136 + c] = a;
            }
        }
    }
    __syncthreads();

    // ---- P2: h0 -> split k128..255; gather1 -> z1 at k0..127 ----
    {
        int r = t >> 3, f0 = (t & 7) * 16;
        #pragma unroll
        for (int w8 = 0; w8 < 8; w8++) {
            int f = f0 + 2 * w8;
            float v0 = Bf[r * 136 + f], v1 = Bf[r * 136 + f + 1];
            unsigned short h0 = f2bf(v0), h1 = f2bf(v1);
            unsigned short l0 = f2bf(v0 - bf2f(h0)), l1 = f2bf(v1 - bf2f(h1));
            int q = (256 + 2 * f) ^ ((r & 7) << 4);
            *(unsigned*)(lds + LC + r * 512 + q) = (unsigned)h0 | ((unsigned)h1 << 16);
            *(unsigned*)(lds + LD + r * 512 + q) = (unsigned)l0 | ((unsigned)l1 << 16);
        }
        int n = r;
        if (n < 50) {
            float di = sdinv[n];
            int d = scnt[n]; if (d > MAXDEG) d = MAXDEG;
            float acc[16];
            #pragma unroll
            for (int cc = 0; cc < 16; cc++) acc[cc] = di * Bf[n * 136 + f0 + cc];
            #pragma unroll
            for (int e = 0; e < 12; e++) {
                bool valid = e < d;
                int jl = valid ? sadj[n * 12 + e] : n;
                float dj = valid ? sdinv[jl] : 0.f;
                #pragma unroll
                for (int cc = 0; cc < 16; cc++) acc[cc] += dj * Bf[jl * 136 + f0 + cc];
            }
            for (int e = 12; e < d; e++) {
                int jl = adj[((size_t)(b * 50 + n)) * MAXDEG + e] - b * 50;
                float dj = sdinv[jl];
                #pragma unroll
                for (int cc = 0; cc < 16; cc++) acc[cc] += dj * Bf[jl * 136 + f0 + cc];
            }
            #pragma unroll
            for (int w8 = 0; w8 < 8; w8++) {
                float z0 = di * acc[2 * w8], z1 = di * acc[2 * w8 + 1];
                unsigned short h0 = f2bf(z0), h1 = f2bf(z1);
                unsigned short l0 = f2bf(z0 - bf2f(h0)), l1 = f2bf(z1 - bf2f(h1));
                int q = (2 * (f0 + 2 * w8)) ^ ((n & 7) << 4);
                *(unsigned*)(lds + LC + n * 512 + q) = (unsigned)h0 | ((unsigned)h1 << 16);
                *(unsigned*)(lds + LD + n * 512 + q) = (unsigned)l0 | ((unsigned)l1 << 16);
            }
        }
    }
    __syncthreads();

    // ---- P3: L1 MFMA: h1 = relu(z1@W1 + b1) -> Bf ----
    {
        const int col = wv * 16 + fr;
        bf16x8 bh[4], bl[4];
        #pragma unroll
        for (int ks = 0; ks < 4; ks++) {
            int base = ((col * 4 + ks) * 4 + fq) * 8;
            bh[ks] = *(const bf16x8*)&W1h[base];
            bl[ks] = *(const bf16x8*)&W1l[base];
        }
        f32x4 acc[4];
        #pragma unroll
        for (int m = 0; m < 4; m++) acc[m] = (f32x4){0.f,0.f,0.f,0.f};
        #pragma unroll
        for (int ks = 0; ks < 4; ks++) {
            int kb = ks * 64 + fq * 16;
            #pragma unroll
            for (int m = 0; m < 4; m++) {
                int r = m * 16 + fr;
                int off = r * 512 + (kb ^ ((r & 7) << 4));
                bf16x8 ah = *(bf16x8*)(lds + LC + off);
                bf16x8 al = *(bf16x8*)(lds + LD + off);
                acc[m] = __builtin_amdgcn_mfma_f32_16x16x32_bf16(ah, bh[ks], acc[m], 0, 0, 0);
                acc[m] = __builtin_amdgcn_mfma_f32_16x16x32_bf16(ah, bl[ks], acc[m], 0, 0, 0);
                acc[m] = __builtin_amdgcn_mfma_f32_16x16x32_bf16(al, bh[ks], acc[m], 0, 0, 0);
            }
        }
        float b1c = b1[col];
        #pragma unroll
        for (int m = 0; m < 4; m++)
            #pragma unroll
            for (int j = 0; j < 4; j++) {
                int row = m * 16 + fq * 4 + j;
                Bf[row * 136 + col] = fmaxf(acc[m][j] + b1c, 0.f);
            }
    }
    __syncthreads();

    // ---- P4: gather2 on h1 -> z2 at k0..127 ----
    {
        int n = t >> 3, f0 = (t & 7) * 16;
        if (n < 50) {
            float di = sdinv[n];
            int d = scnt[n]; if (d > MAXDEG) d = MAXDEG;
            float acc[16];
            #pragma unroll
            for (int cc = 0; cc < 16; cc++) acc[cc] = di * Bf[n * 136 + f0 + cc];
            #pragma unroll
            for (int e = 0; e < 12; e++) {
                bool valid = e < d;
                int jl = valid ? sadj[n * 12 + e] : n;
                float dj = valid ? sdinv[jl] : 0.f;
                #pragma unroll
                for (int cc = 0; cc < 16; cc++) acc[cc] += dj * Bf[jl * 136 + f0 + cc];
            }
            for (int e = 12; e < d; e++) {
                int jl = adj[((size_t)(b * 50 + n)) * MAXDEG + e] - b * 50;
                float dj = sdinv[jl];
                #pragma unroll
                for (int cc = 0; cc < 16; cc++) acc[cc] += dj * Bf[jl * 136 + f0 + cc];
            }
            #pragma unroll
            for (int w8 = 0; w8 < 8; w8++) {
                float z0 = di * acc[2 * w8], z1 = di * acc[2 * w8 + 1];
                unsigned short h0 = f2bf(z0), h1 = f2bf(z1);
                unsigned short l0 = f2bf(z0 - bf2f(h0)), l1 = f2bf(z1 - bf2f(h1));
                int q = (2 * (f0 + 2 * w8)) ^ ((n & 7) << 4);
                *(unsigned*)(lds + LC + n * 512 + q) = (unsigned)h0 | ((unsigned)h1 << 16);
                *(unsigned*)(lds + LD + n * 512 + q) = (unsigned)l0 | ((unsigned)l1 << 16);
            }
        }
    }
    __syncthreads();

    // ---- P5: L2 MFMA: h2 = z2@W2 + b2 (regs) ----
    float h2v[4][4];
    {
        const int col = wv * 16 + fr;
        bf16x8 bh[4], bl[4];
        #pragma unroll
        for (int ks = 0; ks < 4; ks++) {
            int base = ((col * 4 + ks) * 4 + fq) * 8;
            bh[ks] = *(const bf16x8*)&W2h[base];
            bl[ks] = *(const bf16x8*)&W2l[base];
        }
        f32x4 acc[4];
        #pragma unroll
        for (int m = 0; m < 4; m++) acc[m] = (f32x4){0.f,0.f,0.f,0.f};
        #pragma unroll
        for (int ks = 0; ks < 4; ks++) {
            int kb = ks * 64 + fq * 16;
            #pragma unroll
            for (int m = 0; m < 4; m++) {
                int r = m * 16 + fr;
                int off = r * 512 + (kb ^ ((r & 7) << 4));
                bf16x8 ah = *(bf16x8*)(lds + LC + off);
                bf16x8 al = *(bf16x8*)(lds + LD + off);
                acc[m] = __builtin_amdgcn_mfma_f32_16x16x32_bf16(ah, bh[ks], acc[m], 0, 0, 0);
                acc[m] = __builtin_amdgcn_mfma_f32_16x16x32_bf16(ah, bl[ks], acc[m], 0, 0, 0);
                acc[m] = __builtin_amdgcn_mfma_f32_16x16x32_bf16(al, bh[ks], acc[m], 0, 0, 0);
            }
        }
        float b2c = b2[col];
        #pragma unroll
        for (int m = 0; m < 4; m++)
            #pragma unroll
            for (int j = 0; j < 4; j++) h2v[m][j] = acc[m][j] + b2c;
    }
    __syncthreads();

    // ---- P6: h2 -> split k0..127; pool -> svg ----
    {
        const int col = wv * 16 + fr;
        float s = 0.f;
        #pragma unroll
        for (int m = 0; m < 4; m++)
            #pragma unroll
            for (int j = 0; j < 4; j++) {
                int row = m * 16 + fq * 4 + j;
                float v = h2v[m][j];
                unsigned short h = f2bf(v);
                unsigned short l = f2bf(v - bf2f(h));
                int q = (2 * col) ^ ((row & 7) << 4);
                *(short*)(lds + LC + row * 512 + q) = (short)h;
                *(short*)(lds + LD + row * 512 + q) = (short)l;
                if (row < 50) s += v;
            }
        s += __shfl_xor(s, 16); s += __shfl_xor(s, 32);
        if (fq == 0) ((float*)(lds + E_SVG))[col] = s * (1.0f / 50.0f);
    }
    __syncthreads();

    // ---- P7: vg -> frags ----
    if (t < 128) {
        float v = ((float*)(lds + E_SVG))[t];
        unsigned short h = f2bf(v);
        ((short*)(lds + E_VGH))[t] = (short)h;
        ((short*)(lds + E_VGL))[t] = (short)f2bf(v - bf2f(h));
    }
    __syncthreads();

    // ---- P8: T1 = leaky([h2|h0|vg|pg]@hW1 + hb1) ----
    f32x4 accT[4][2];
    #pragma unroll
    for (int m = 0; m < 4; m++)
        #pragma unroll
        for (int nf = 0; nf < 2; nf++) accT[m][nf] = (f32x4){0.f,0.f,0.f,0.f};
    {
        #pragma unroll
        for (int ks = 0; ks < 16; ks++) {
            bf16x8 bh[2], bl[2];
            #pragma unroll
            for (int nf = 0; nf < 2; nf++) {
                int col2 = wv * 32 + nf * 16 + fr;
                int base = ((col2 * 16 + ks) * 4 + fq) * 8;
                bh[nf] = *(const bf16x8*)&H1h[base];
                bl[nf] = *(const bf16x8*)&H1l[base];
            }
            if (ks < 8) {
                int kb = ks * 64 + fq * 16;
                #pragma unroll
                for (int m = 0; m < 4; m++) {
                    int r = m * 16 + fr;
                    int off = r * 512 + (kb ^ ((r & 7) << 4));
                    bf16x8 ah = *(bf16x8*)(lds + LC + off);
                    bf16x8 al = *(bf16x8*)(lds + LD + off);
                    #pragma unroll
                    for (int nf = 0; nf < 2; nf++) {
                        accT[m][nf] = __builtin_amdgcn_mfma_f32_16x16x32_bf16(ah, bh[nf], accT[m][nf], 0, 0, 0);
                        accT[m][nf] = __builtin_amdgcn_mfma_f32_16x16x32_bf16(ah, bl[nf], accT[m][nf], 0, 0, 0);
                        accT[m][nf] = __builtin_amdgcn_mfma_f32_16x16x32_bf16(al, bh[nf], accT[m][nf], 0, 0, 0);
                    }
                }
            } else {
                int boff = (ks < 12) ? (E_VGH + (ks - 8) * 64 + fq * 16)
                                     : (E_PGH + (ks - 12) * 64 + fq * 16);
                int loff = boff + 256;
                bf16x8 ah = *(bf16x8*)(lds + boff);
                bf16x8 al = *(bf16x8*)(lds + loff);
                #pragma unroll
                for (int m = 0; m < 4; m++)
                    #pragma unroll
                    for (int nf = 0; nf < 2; nf++) {
                        accT[m][nf] = __builtin_amdgcn_mfma_f32_16x16x32_bf16(ah, bh[nf], accT[m][nf], 0, 0, 0);
                        accT[m][nf] = __builtin_amdgcn_mfma_f32_16x16x32_bf16(ah, bl[nf], accT[m][nf], 0, 0, 0);
                        accT[m][nf] = __builtin_amdgcn_mfma_f32_16x16x32_bf16(al, bh[nf], accT[m][nf], 0, 0, 0);
                    }
            }
        }
    }
    __syncthreads();
    {
        #pragma unroll
        for (int nf = 0; nf < 2; nf++) {
            int col2 = wv * 32 + nf * 16 + fr;
            float hc = hb1[col2];
            #pragma unroll
            for (int m = 0; m < 4; m++)
                #pragma unroll
                for (int j = 0; j < 4; j++) {
                    int row = m * 16 + fq * 4 + j;
                    float v = accT[m][nf][j] + hc;
                    v = v > 0.f ? v : 0.01f * v;
                    unsigned short h = f2bf(v);
                    unsigned short l = f2bf(v - bf2f(h));
                    int q = (2 * col2) ^ ((row & 7) << 4);
                    *(short*)(lds + LC + row * 512 + q) = (short)h;
                    *(short*)(lds + LD + row * 512 + q) = (short)l;
                }
        }
    }
    __syncthreads();

    // ---- P9: T2 = leaky(T1@hW2 + hb2); logits ----
    {
        const int col3 = wv * 16 + fr;
        f32x4 acc[4];
        #pragma unroll
        for (int m = 0; m < 4; m++) acc[m] = (f32x4){0.f,0.f,0.f,0.f};
        #pragma unroll
        for (int ks = 0; ks < 8; ks++) {
            int base = ((col3 * 8 + ks) * 4 + fq) * 8;
            bf16x8 bh = *(const bf16x8*)&H2h[base];
            bf16x8 bl = *(const bf16x8*)&H2l[base];
            int kb = ks * 64 + fq * 16;
            #pragma unroll
            for (int m = 0; m < 4; m++) {
                int r = m * 16 + fr;
                int off = r * 512 + (kb ^ ((r & 7) << 4));
                bf16x8 ah = *(bf16x8*)(lds + LC + off);
                bf16x8 al = *(bf16x8*)(lds + LD + off);
                acc[m] = __builtin_amdgcn_mfma_f32_16x16x32_bf16(ah, bh, acc[m], 0, 0, 0);
                acc[m] = __builtin_amdgcn_mfma_f32_16x16x32_bf16(ah, bl, acc[m], 0, 0, 0);
                acc[m] = __builtin_amdgcn_mfma_f32_16x16x32_bf16(al, bh, acc[m], 0, 0, 0);
            }
        }
        float hc = hb2[col3], wc = w3[col3];
        float p[4][4];
        #pragma unroll
        for (int m = 0; m < 4; m++)
            #pragma unroll
            for (int j = 0; j < 4; j++) {
                float v = acc[m][j] + hc;
                v = v > 0.f ? v : 0.01f * v;
                p[m][j] = v * wc;
            }
        #pragma unroll
        for (int m = 0; m < 4; m++)
            #pragma unroll
            for (int j = 0; j < 4; j++) {
                p[m][j] += __shfl_xor(p[m][j], 1);
                p[m][j] += __shfl_xor(p[m][j], 2);
                p[m][j] += __shfl_xor(p[m][j], 4);
                p[m][j] += __shfl_xor(p[m][j], 8);
            }
        if (fr == 0) {
            float* wsum = (float*)(lds + E_WSUM);
            #pragma unroll
            for (int m = 0; m < 4; m++)
                #pragma unroll
                for (int j = 0; j < 4; j++)
                    wsum[wv * 64 + m * 16 + fq * 4 + j] = p[m][j];
        }
    }
    __syncthreads();
    if (t < 50) {
        float* wsum = (float*)(lds + E_WSUM);
        float s = 0.f;
        #pragma unroll
        for (int w8 = 0; w8 < 8; w8++) s += wsum[w8 * 64 + t];
        out[b * 50 + t] = s + b3[0];
    }
}

extern "C" void kernel_launch(void* const* d_in, const int* in_sizes, int n_in,
                              void* d_out, int out_size, void* d_ws, size_t ws_size,
                              hipStream_t stream) {
    const float* p_x = (const float*)d_in[0];
    const float* v_x = (const float*)d_in[1];
    const int* p_ei = (const int*)d_in[2];
    const int* v_ei = (const int*)d_in[3];
    const float* pW0 = (const float*)d_in[6];  const float* pb0 = (const float*)d_in[7];
    const float* pW1 = (const float*)d_in[8];  const float* pb1 = (const float*)d_in[9];
    const float* pW2 = (const float*)d_in[10]; const float* pb2 = (const float*)d_in[11];
    const float* vW0 = (const float*)d_in[12]; const float* vb0 = (const float*)d_in[13];
    const float* vW1 = (const float*)d_in[14]; const float* vb1 = (const float*)d_in[15];
    const float* vW2 = (const float*)d_in[16]; const float* vb2 = (const float*)d_in[17];
    const float* hW1 = (const float*)d_in[18]; const float* hb1 = (const float*)d_in[19];
    const float* hW2 = (const float*)d_in[20]; const float* hb2 = (const float*)d_in[21];
    const float* hW3 = (const float*)d_in[22]; const float* hb3 = (const float*)d_in[23];

    char* w = (char*)d_ws;
    size_t off = 0;
    auto alloc = [&](size_t bytes) { char* p = w + off; off += (bytes + 255) & ~size_t(255); return p; };
    // zeroed group (contiguous, one memset): cnt_p | cnt_v | c_p | p_gz
    int*   cnt_p  = (int*)alloc((size_t)NP_TOT * 4);       // 512000
    int*   cnt_v  = (int*)alloc((size_t)NV_TOT * 4);       // 51200
    float* c_p    = (float*)alloc((size_t)NP_TOT * 4);     // 512000
    float* p_gz   = (float*)alloc((size_t)NB * 128 * 4);   // 131072
    size_t zero_bytes = (size_t)NP_TOT * 4 + (size_t)NV_TOT * 4
                      + (size_t)NP_TOT * 4 + (size_t)NB * 128 * 4;
    float* W01    = (float*)alloc((size_t)16 * 128 * 4);
    float* b01    = (float*)alloc((size_t)128 * 4);
    short* W1vh   = (short*)alloc((size_t)128 * 128 * 2);
    short* W1vl   = (short*)alloc((size_t)128 * 128 * 2);
    short* W2vh   = (short*)alloc((size_t)128 * 128 * 2);
    short* W2vl   = (short*)alloc((size_t)128 * 128 * 2);
    short* H1h    = (short*)alloc((size_t)512 * 256 * 2);
    short* H1l    = (short*)alloc((size_t)512 * 256 * 2);
    short* H2h    = (short*)alloc((size_t)256 * 128 * 2);
    short* H2l    = (short*)alloc((size_t)256 * 128 * 2);
    int*   adj_p  = (int*)alloc((size_t)NP_TOT * MAXDEG * 4);
    int*   adj_v  = (int*)alloc((size_t)NV_TOT * MAXDEG * 4);

    hipMemsetAsync(cnt_p, 0, zero_bytes, stream);
    adj2_k<<<(EP_EDGES + EV_EDGES) / 256, 256, 0, stream>>>(p_ei, v_ei, cnt_p, adj_p,
                                                            cnt_v, adj_v);
    c_k<<<(EP_EDGES + 255) / 256, 256, 0, stream>>>(p_ei, cnt_p, c_p, EP_EDGES);
    prep_k<<<769, 256, 0, stream>>>(pW0, pb0, pW1, W01, b01,
                                    vW1, W1vh, W1vl, vW2, W2vh, W2vl,
                                    hW1, H1h, H1l, hW2, H2h, H2l);
    pfused<<<NP_TOT / 128, 512, 0, stream>>>(p_x, adj_p, cnt_p, c_p,
                                             W01, b01, pb1, p_gz, 500);
    vhead_k<<<NB, 512, 0, stream>>>(v_x, adj_v, cnt_v,
                                    vW0, vb0, W1vh, W1vl, vb1, W2vh, W2vl, vb2,
                                    p_gz, pW2, pb2, H1h, H1l, hb1, H2h, H2l, hb2,
                                    hW3, hb3, (float*)d_out);
}